// Round 12
// baseline (1777.293 us; speedup 1.0000x reference)
//
#include <hip/hip_runtime.h>
#include <hip/hip_bf16.h>
#include <math.h>

// Problem constants
#define T_STEPS 64
#define NN      2048
#define KN      32
#define IND     256
#define H1D     128
#define C1D     384   // HEADS*H1
#define H2D     128
#define GD      256
#define PD      60
#define GRU_NB  8     // cooperating blocks for the GRU

typedef __attribute__((ext_vector_type(8))) short bf16x8v;  // 8 bf16 = 4 VGPR
typedef __attribute__((ext_vector_type(4))) float f32x4v;

// bit-reversed 4-bit order (involution): loading rows in this order makes
// lane l end up owning slot l&15 after the 16-slot butterfly reduce.
#define BITREV4_INIT {0,8,4,12,2,10,6,14,1,9,5,13,3,11,7,15}

__device__ __forceinline__ float bcast_lane(float v, int lane_imm) {
    return __uint_as_float(__builtin_amdgcn_readlane(__float_as_uint(v), lane_imm));
}

__device__ __forceinline__ void bf16_split(float v, __hip_bfloat16* hi, __hip_bfloat16* lo) {
    __hip_bfloat16 h = __float2bfloat16(v);
    *hi = h;
    *lo = __float2bfloat16(v - __bfloat162float(h));
}

// Butterfly stages 2..4 on 8 stage-1-combined partials (16 slots total).
// Input: comb[i] = stage-1 combine of slots (BR4[i], BR4[i]+1).
// Output: lane l holds full 64-lane sum of slot (l & 15).
__device__ __forceinline__ float xpose_reduce8(float part[8], int lane) {
#pragma unroll
    for (int i = 0; i < 4; ++i) {
        float send = (lane & 2) ? part[i] : part[i + 4];
        float keep = (lane & 2) ? part[i + 4] : part[i];
        part[i] = keep + __shfl_xor(send, 2);
    }
#pragma unroll
    for (int i = 0; i < 2; ++i) {
        float send = (lane & 4) ? part[i] : part[i + 2];
        float keep = (lane & 4) ? part[i + 2] : part[i];
        part[i] = keep + __shfl_xor(send, 4);
    }
    {
        float send = (lane & 8) ? part[0] : part[1];
        float keep = (lane & 8) ? part[1] : part[0];
        part[0] = keep + __shfl_xor(send, 8);
    }
    float r = part[0] + __shfl_xor(part[0], 16);
    return r + __shfl_xor(r, 32);
}

// ---------------------------------------------------------------------------
// K1: row norms of h[t]  (one wave per node, single float4 load)
// ---------------------------------------------------------------------------
__global__ __launch_bounds__(256) void norms_kernel(const float* __restrict__ h,
                                                    float* __restrict__ norms,
                                                    int t_base) {
    int gw   = (int)((blockIdx.x * blockDim.x + threadIdx.x) >> 6);
    int lane = threadIdx.x & 63;
    int n    = gw & (NN - 1);
    int tloc = gw >> 11;
    const float4* row = (const float4*)(h + ((size_t)(t_base + tloc) * NN + n) * IND);
    float4 v = row[lane];
    float s = v.x * v.x + v.y * v.y + v.z * v.z + v.w * v.w;
#pragma unroll
    for (int off = 32; off > 0; off >>= 1) s += __shfl_xor(s, off);
    if (lane == 0) norms[(size_t)tloc * NN + n] = sqrtf(s);
}

// ---------------------------------------------------------------------------
// K2: input attention. 4 waves per (t,n): wave = (d-half, k-half).
// 16 rows/wave in VGPRs (32 regs) -> 6 waves/SIMD occupancy.
// ---------------------------------------------------------------------------
__global__ __launch_bounds__(256, 6) void input_attn_kernel(const float* __restrict__ h,
                                                            const int* __restrict__ neigh,
                                                            const float* __restrict__ norms,
                                                            __hip_bfloat16* __restrict__ ihHi,
                                                            __hip_bfloat16* __restrict__ ihLo,
                                                            int t_base) {
    const int BR[16] = BITREV4_INIT;
    __shared__ float hd_s[2][2][16];   // [half_d][half_k][slot]
    __shared__ float acc_s[2][128];    // [half_d][d]
    int wave = threadIdx.x >> 6;
    int hd   = wave >> 1;
    int hk   = wave & 1;
    int lane = threadIdx.x & 63;
    int gw   = blockIdx.x;
    int n    = gw & (NN - 1);
    int tloc = gw >> 11;
    const float* hT  = h + (size_t)(t_base + tloc) * NN * IND;
    const float* nrm = norms + (size_t)tloc * NN;

    const float* dst = hT + (size_t)n * IND + hd * 128;
    float d0 = dst[lane], d1 = dst[lane + 64];

    int   jreg = neigh[n * KN + hk * 16 + (lane & 15)];
    float nj   = nrm[jreg];
    float ndst = nrm[n];

    float r0[16], r1[16], comb[8];
#pragma unroll
    for (int i = 0; i < 8; ++i) {
        int sja = __builtin_amdgcn_readlane(jreg, BR[i]);
        int sjb = __builtin_amdgcn_readlane(jreg, BR[i + 8]);
        const float* sa = hT + (size_t)sja * IND + hd * 128;
        const float* sb = hT + (size_t)sjb * IND + hd * 128;
        r0[i]     = sa[lane]; r1[i]     = sa[lane + 64];
        r0[i + 8] = sb[lane]; r1[i + 8] = sb[lane + 64];
        float pa = r0[i] * d0 + r1[i] * d1;
        float pb = r0[i + 8] * d0 + r1[i + 8] * d1;
        float send = (lane & 1) ? pa : pb;
        float keep = (lane & 1) ? pb : pa;
        comb[i] = keep + __shfl_xor(send, 1);
    }
#pragma unroll
    for (int i = 0; i < 16; ++i) asm volatile("" : "+v"(r0[i]), "+v"(r1[i]));
    float hdot = xpose_reduce8(comb, lane);   // my d-half dot of slot (lane&15)
    if (lane < 16) hd_s[hd][hk][lane] = hdot;
    __syncthreads();
    float dot = hdot + hd_s[hd ^ 1][hk][lane & 15];

    float r  = dot / (nj * ndst);
    float r2 = r * r;
    float e  = r2 * r2;

    float a0 = 0.f, a1 = 0.f;
#pragma unroll
    for (int i = 0; i < 16; ++i) {
        float ek = bcast_lane(e, BR[i]);
        a0 += ek * r0[i];
        a1 += ek * r1[i];
    }
    if (hk == 0) { acc_s[hd][lane] = a0; acc_s[hd][lane + 64] = a1; }
    __syncthreads();
    if (hk == 1) {
        float t0 = a0 + acc_s[hd][lane];
        float t1 = a1 + acc_s[hd][lane + 64];
        size_t base = (size_t)gw * IND + hd * 128;
        __hip_bfloat16 hi, lo;
        bf16_split(t0, &hi, &lo);
        ihHi[base + lane] = hi;       ihLo[base + lane] = lo;
        bf16_split(t1, &hi, &lo);
        ihHi[base + lane + 64] = hi;  ihLo[base + lane + 64] = lo;
    }
}

// ---------------------------------------------------------------------------
// MFMA GEMM, bf16x3 error-compensated split (fp32-grade accuracy).
// A: [M][K] bf16 pairs. BT: [N][K] bf16 pairs. C: fp32.
// ---------------------------------------------------------------------------
__global__ __launch_bounds__(256) void gemm_bf16x3(const __hip_bfloat16* __restrict__ Ahi,
                                                   const __hip_bfloat16* __restrict__ Alo,
                                                   const __hip_bfloat16* __restrict__ BThi,
                                                   const __hip_bfloat16* __restrict__ BTlo,
                                                   float* __restrict__ C,
                                                   int M, int N, int K) {
    int lane = threadIdx.x & 63;
    int w    = threadIdx.x >> 6;
    int m0   = blockIdx.y * 64 + w * 16;
    int n0   = blockIdx.x * 64;
    int r    = lane & 15;        // row (A) / col (B) within fragment
    int g    = lane >> 4;        // k-group: k = g*8 .. g*8+7

    const __hip_bfloat16* arow_hi = Ahi + (size_t)(m0 + r) * K + g * 8;
    const __hip_bfloat16* arow_lo = Alo + (size_t)(m0 + r) * K + g * 8;

    f32x4v acc[4] = {};
    for (int k0 = 0; k0 < K; k0 += 32) {
        bf16x8v ah = *(const bf16x8v*)(arow_hi + k0);
        bf16x8v al = *(const bf16x8v*)(arow_lo + k0);
#pragma unroll
        for (int nt = 0; nt < 4; ++nt) {
            size_t boff = (size_t)(n0 + nt * 16 + r) * K + g * 8 + k0;
            bf16x8v bh = *(const bf16x8v*)(BThi + boff);
            bf16x8v bl = *(const bf16x8v*)(BTlo + boff);
            acc[nt] = __builtin_amdgcn_mfma_f32_16x16x32_bf16(ah, bh, acc[nt], 0, 0, 0);
            acc[nt] = __builtin_amdgcn_mfma_f32_16x16x32_bf16(ah, bl, acc[nt], 0, 0, 0);
            acc[nt] = __builtin_amdgcn_mfma_f32_16x16x32_bf16(al, bh, acc[nt], 0, 0, 0);
        }
    }
#pragma unroll
    for (int nt = 0; nt < 4; ++nt)
#pragma unroll
        for (int q = 0; q < 4; ++q)
            C[(size_t)(m0 + g * 4 + q) * N + n0 + nt * 16 + r] = acc[nt][q];
}

// ---------------------------------------------------------------------------
// K4: 3-head GAT + relu. One block (384 thr = 3 heads x 2 k-halves) per (t,n).
// 16 rows/wave; softmax combined across k-halves through LDS.
// ---------------------------------------------------------------------------
__global__ __launch_bounds__(384, 6) void gat_heads_kernel(const float* __restrict__ z1,
                                                           const int* __restrict__ neigh,
                                                           __hip_bfloat16* __restrict__ cHi,
                                                           __hip_bfloat16* __restrict__ cLo) {
    const int BR[16] = BITREV4_INIT;
    __shared__ float dots_s[3][2][16];
    __shared__ float accs[3][128];
    int n    = blockIdx.x & (NN - 1);
    const float* ztbl = z1 + (size_t)(blockIdx.x >> 11) * NN * C1D;
    int wave = threadIdx.x >> 6;
    int head = wave >> 1;        // 0..2
    int kh   = wave & 1;
    int lane = threadIdx.x & 63;

    const float* dst = ztbl + (size_t)n * C1D + head * H1D;
    float d0 = dst[lane], d1 = dst[lane + 64];
    int jreg = neigh[n * KN + kh * 16 + (lane & 15)];

    float r0[16], r1[16], comb[8];
#pragma unroll
    for (int i = 0; i < 8; ++i) {
        int sja = __builtin_amdgcn_readlane(jreg, BR[i]);
        int sjb = __builtin_amdgcn_readlane(jreg, BR[i + 8]);
        const float* sa = ztbl + (size_t)sja * C1D + head * H1D;
        const float* sb = ztbl + (size_t)sjb * C1D + head * H1D;
        r0[i]     = sa[lane]; r1[i]     = sa[lane + 64];
        r0[i + 8] = sb[lane]; r1[i + 8] = sb[lane + 64];
        float pa = r0[i] * d0 + r1[i] * d1;
        float pb = r0[i + 8] * d0 + r1[i + 8] * d1;
        float send = (lane & 1) ? pa : pb;
        float keep = (lane & 1) ? pb : pa;
        comb[i] = keep + __shfl_xor(send, 1);
    }
#pragma unroll
    for (int i = 0; i < 16; ++i) asm volatile("" : "+v"(r0[i]), "+v"(r1[i]));
    float dot = xpose_reduce8(comb, lane);   // my k-half dot of slot (lane&15)

    if (lane < 16) dots_s[head][kh][lane] = dot;
    __syncthreads();
    float dOth = dots_s[head][kh ^ 1][lane & 15];

    float mx = fmaxf(dot, dOth);
#pragma unroll
    for (int off = 8; off > 0; off >>= 1) mx = fmaxf(mx, __shfl_xor(mx, off));
    float eMine = __expf(dot - mx);
    float eOth  = __expf(dOth - mx);
    float ss = eMine + eOth;
#pragma unroll
    for (int off = 8; off > 0; off >>= 1) ss += __shfl_xor(ss, off);
    float p = eMine / ss;

    float a0 = 0.f, a1 = 0.f;
#pragma unroll
    for (int i = 0; i < 16; ++i) {
        float pk = bcast_lane(p, BR[i]);
        a0 += pk * r0[i];
        a1 += pk * r1[i];
    }
    if (kh == 0) { accs[head][lane] = a0; accs[head][lane + 64] = a1; }
    __syncthreads();
    if (kh == 1) {
        float t0 = fmaxf(a0 + accs[head][lane], 0.f);
        float t1 = fmaxf(a1 + accs[head][lane + 64], 0.f);
        size_t base = (size_t)blockIdx.x * C1D + (size_t)head * H1D;
        __hip_bfloat16 hi, lo;
        bf16_split(t0, &hi, &lo);
        cHi[base + lane] = hi;       cLo[base + lane] = lo;
        bf16_split(t1, &hi, &lo);
        cHi[base + lane + 64] = hi;  cLo[base + lane + 64] = lo;
    }
}

// ---------------------------------------------------------------------------
// K7: final GAT on z2 (d=128) + relu -> c2. Block = 2 nodes x 2 k-halves.
// ---------------------------------------------------------------------------
__global__ __launch_bounds__(256, 6) void gat_final_kernel(const float* __restrict__ z2,
                                                           const int* __restrict__ neigh,
                                                           float* __restrict__ c2) {
    const int BR[16] = BITREV4_INIT;
    __shared__ float dots_s[2][2][16];   // [nodeloc][kh][slot]
    __shared__ float accs[2][128];
    int wave    = threadIdx.x >> 6;
    int nodeloc = wave >> 1;
    int kh      = wave & 1;
    int lane    = threadIdx.x & 63;
    int gw   = (int)((blockIdx.x << 1) | nodeloc);
    int n    = gw & (NN - 1);
    const float* ztbl = z2 + (size_t)(gw >> 11) * NN * H2D;

    const float* dst = ztbl + (size_t)n * H2D;
    float d0 = dst[lane], d1 = dst[lane + 64];
    int jreg = neigh[n * KN + kh * 16 + (lane & 15)];

    float r0[16], r1[16], comb[8];
#pragma unroll
    for (int i = 0; i < 8; ++i) {
        int sja = __builtin_amdgcn_readlane(jreg, BR[i]);
        int sjb = __builtin_amdgcn_readlane(jreg, BR[i + 8]);
        const float* sa = ztbl + (size_t)sja * H2D;
        const float* sb = ztbl + (size_t)sjb * H2D;
        r0[i]     = sa[lane]; r1[i]     = sa[lane + 64];
        r0[i + 8] = sb[lane]; r1[i + 8] = sb[lane + 64];
        float pa = r0[i] * d0 + r1[i] * d1;
        float pb = r0[i + 8] * d0 + r1[i + 8] * d1;
        float send = (lane & 1) ? pa : pb;
        float keep = (lane & 1) ? pb : pa;
        comb[i] = keep + __shfl_xor(send, 1);
    }
#pragma unroll
    for (int i = 0; i < 16; ++i) asm volatile("" : "+v"(r0[i]), "+v"(r1[i]));
    float dot = xpose_reduce8(comb, lane);

    if (lane < 16) dots_s[nodeloc][kh][lane] = dot;
    __syncthreads();
    float dOth = dots_s[nodeloc][kh ^ 1][lane & 15];

    float mx = fmaxf(dot, dOth);
#pragma unroll
    for (int off = 8; off > 0; off >>= 1) mx = fmaxf(mx, __shfl_xor(mx, off));
    float eMine = __expf(dot - mx);
    float eOth  = __expf(dOth - mx);
    float ss = eMine + eOth;
#pragma unroll
    for (int off = 8; off > 0; off >>= 1) ss += __shfl_xor(ss, off);
    float p = eMine / ss;

    float a0 = 0.f, a1 = 0.f;
#pragma unroll
    for (int i = 0; i < 16; ++i) {
        float pk = bcast_lane(p, BR[i]);
        a0 += pk * r0[i];
        a1 += pk * r1[i];
    }
    if (kh == 0) { accs[nodeloc][lane] = a0; accs[nodeloc][lane + 64] = a1; }
    __syncthreads();
    if (kh == 1) {
        c2[(size_t)gw * H2D + lane]      = fmaxf(a0 + accs[nodeloc][lane], 0.f);
        c2[(size_t)gw * H2D + lane + 64] = fmaxf(a1 + accs[nodeloc][lane + 64], 0.f);
    }
}

// ---------------------------------------------------------------------------
// K8: pooled[t][j] = max_n c2[t][n][j]  — two stage for grid parallelism
// ---------------------------------------------------------------------------
__global__ __launch_bounds__(128) void pool_part_kernel(const float* __restrict__ c2,
                                                        float* __restrict__ ppart) {
    int j = threadIdx.x;
    int tloc  = blockIdx.x >> 4;
    int slice = blockIdx.x & 15;
    const float* base = c2 + ((size_t)tloc * NN + slice * 128) * H2D;
    float mx = 0.f;
    for (int q = 0; q < 128; ++q) mx = fmaxf(mx, base[(size_t)q * H2D + j]);
    ppart[(size_t)blockIdx.x * H2D + j] = mx;
}
__global__ __launch_bounds__(128) void pool_reduce_kernel(const float* __restrict__ ppart,
                                                          float* __restrict__ pooled,
                                                          int t_base) {
    int j = threadIdx.x;
    const float* base = ppart + (size_t)blockIdx.x * 16 * H2D;
    float mx = 0.f;
#pragma unroll
    for (int q = 0; q < 16; ++q) mx = fmaxf(mx, base[(size_t)q * H2D + j]);
    pooled[(t_base + blockIdx.x) * H2D + j] = mx;
}

// ---------------------------------------------------------------------------
// prep: weights -> transposed bf16 hi/lo pairs; zero GRU counters.
// ---------------------------------------------------------------------------
__global__ void prep_kernel(const float* __restrict__ fc1, const float* __restrict__ fc2,
                            __hip_bfloat16* __restrict__ W1Thi, __hip_bfloat16* __restrict__ W1Tlo,
                            __hip_bfloat16* __restrict__ f2Thi, __hip_bfloat16* __restrict__ f2Tlo,
                            unsigned int* __restrict__ cnt) {
    int i = blockIdx.x * 256 + threadIdx.x;
    if (i < 384 * 256) {
        int cf = i / 256, d = i % 256;
        int hd = cf >> 7, j = cf & 127;
        float v = fc1[(size_t)hd * 256 * 128 + (size_t)d * 128 + j];
        __hip_bfloat16 hi, lo;
        bf16_split(v, &hi, &lo);
        W1Thi[i] = hi; W1Tlo[i] = lo;
    }
    if (i < 128 * 384) {
        int n = i / 384, k = i % 384;
        float v = fc2[(size_t)k * 128 + n];
        __hip_bfloat16 hi, lo;
        bf16_split(v, &hi, &lo);
        f2Thi[i] = hi; f2Tlo[i] = lo;
    }
    if (i < T_STEPS) cnt[i] = 0u;
}

// ---------------------------------------------------------------------------
// gi_all[t][o] = Wih[o,:] . pooled[t,:] + bih[o]   (parallel over t)
// ---------------------------------------------------------------------------
__global__ __launch_bounds__(256) void gi_all_kernel(const float* __restrict__ Wih,
                                                     const float* __restrict__ bih,
                                                     const float* __restrict__ pooled,
                                                     float* __restrict__ gi_all) {
    __shared__ float p_s[H2D];
    int t  = blockIdx.x / 3;
    int ob = (blockIdx.x % 3) * 256;
    if (threadIdx.x < H2D) p_s[threadIdx.x] = pooled[t * H2D + threadIdx.x];
    __syncthreads();
    int o = ob + threadIdx.x;
    float acc = bih[o];
    const float* wr = Wih + (size_t)o * H2D;
#pragma unroll 4
    for (int d = 0; d < H2D; ++d) acc += wr[d] * p_s[d];
    gi_all[t * 768 + o] = acc;
}

// ---------------------------------------------------------------------------
// GRU: 8 cooperating blocks, Whh register-resident.
// ---------------------------------------------------------------------------
__global__ __launch_bounds__(768) void gru_reg_kernel(const float* __restrict__ Whh,
                                                      const float* __restrict__ bhh,
                                                      const float* __restrict__ gi_all,
                                                      const float* __restrict__ hx0,
                                                      float* hx_all,
                                                      unsigned int* cnt) {
    __shared__ float4 hx_pad[72];                 // padded: idx (g,i) -> g*9+i
    __shared__ __align__(16) float hx_lin[GD];    // linear copy for hx_old
    __shared__ float gh_s[96];
    int b   = blockIdx.x;
    int tid = threadIdx.x;
    int row_local = tid >> 3;      // 0..95
    int sub       = tid & 7;       // 0..7
    int chunk     = row_local >> 5;
    int r_in      = row_local & 31;
    int grow      = chunk * GD + b * 32 + r_in;

    float4 wreg[8];
    const float4* wrow = (const float4*)(Whh + (size_t)grow * GD + sub * 32);
#pragma unroll
    for (int i = 0; i < 8; ++i) wreg[i] = wrow[i];
    float bias = (sub == 0) ? bhh[grow] : 0.f;

    for (int t = 0; t < T_STEPS; ++t) {
        if (t > 0) {
            if (tid == 0) {
                while (__hip_atomic_load(&cnt[t - 1], __ATOMIC_ACQUIRE,
                                         __HIP_MEMORY_SCOPE_AGENT) < GRU_NB)
                    __builtin_amdgcn_s_sleep(1);
            }
            __syncthreads();
        }
        const float* hsrc = (t == 0) ? hx0 : (hx_all + (size_t)(t - 1) * GD);
        if (tid < 64) {
            float4 v;
            v.x = __hip_atomic_load(hsrc + tid * 4 + 0, __ATOMIC_RELAXED, __HIP_MEMORY_SCOPE_AGENT);
            v.y = __hip_atomic_load(hsrc + tid * 4 + 1, __ATOMIC_RELAXED, __HIP_MEMORY_SCOPE_AGENT);
            v.z = __hip_atomic_load(hsrc + tid * 4 + 2, __ATOMIC_RELAXED, __HIP_MEMORY_SCOPE_AGENT);
            v.w = __hip_atomic_load(hsrc + tid * 4 + 3, __ATOMIC_RELAXED, __HIP_MEMORY_SCOPE_AGENT);
            hx_pad[(tid >> 3) * 9 + (tid & 7)] = v;
            ((float4*)hx_lin)[tid] = v;
        }
        __syncthreads();

        float acc = 0.f;
#pragma unroll
        for (int i = 0; i < 8; ++i) {
            float4 hv = hx_pad[sub * 9 + i];
            float4 wv = wreg[i];
            acc += wv.x * hv.x + wv.y * hv.y + wv.z * hv.z + wv.w * hv.w;
        }
        acc += __shfl_xor(acc, 1);
        acc += __shfl_xor(acc, 2);
        acc += __shfl_xor(acc, 4);
        if (sub == 0) gh_s[row_local] = acc + bias;
        __syncthreads();

        if (tid < 32) {
            int u = b * 32 + tid;
            float gi_r = gi_all[t * 768 + u];
            float gi_z = gi_all[t * 768 + 256 + u];
            float gi_n = gi_all[t * 768 + 512 + u];
            float r  = 1.f / (1.f + expf(-(gi_r + gh_s[tid])));
            float zg = 1.f / (1.f + expf(-(gi_z + gh_s[32 + tid])));
            float nn = tanhf(gi_n + r * gh_s[64 + tid]);
            float hnew = (1.f - zg) * nn + zg * hx_lin[u];
            __hip_atomic_store(&hx_all[(size_t)t * GD + u], hnew,
                               __ATOMIC_RELAXED, __HIP_MEMORY_SCOPE_AGENT);
        }
        __syncthreads();
        if (tid == 0)
            __hip_atomic_fetch_add(&cnt[t], 1u, __ATOMIC_RELEASE,
                                   __HIP_MEMORY_SCOPE_AGENT);
    }
}

// ---------------------------------------------------------------------------
// res heads + SIR scan. One block per t.
// ---------------------------------------------------------------------------
__global__ __launch_bounds__(128) void res_sir_kernel(const float* __restrict__ hx_all,
                                                      const float* __restrict__ It,
                                                      const float* __restrict__ Rt,
                                                      const float* __restrict__ r1W,
                                                      const float* __restrict__ r1b,
                                                      const float* __restrict__ r2W,
                                                      const float* __restrict__ r2b,
                                                      const float* __restrict__ I,
                                                      const float* __restrict__ R,
                                                      const float* __restrict__ S,
                                                      const float* __restrict__ Npop,
                                                      float* __restrict__ out) {
    __shared__ float nhx[258];
    __shared__ float ab_s[2];
    int t = blockIdx.x, tid = threadIdx.x;
    for (int i = tid; i < GD; i += 128) nhx[i] = hx_all[t * GD + i];
    if (tid == 0) { nhx[256] = It[t]; nhx[257] = Rt[t]; }
    __syncthreads();
    if (tid < 120) {
        float acc = r1b[tid];
        const float* wr = r1W + tid * 258;
        for (int d = 0; d < 258; ++d) acc += wr[d] * nhx[d];
        int idx = t * 60 + (tid >> 1);
        if (tid & 1) out[3840 + idx] = acc;
        else         out[idx] = acc;
    }
    if (tid == 120 || tid == 121) {
        int q = tid - 120;
        float acc = r2b[q];
        const float* wr = r2W + q * 258;
        for (int d = 0; d < 258; ++d) acc += wr[d] * nhx[d];
        ab_s[q] = acc;
    }
    __syncthreads();
    if (tid == 0) {
        float a_s = 1.f / (1.f + expf(-ab_s[0]));
        float b_s = 1.f / (1.f + expf(-ab_s[1]));
        float Np = Npop[0];
        float lI = I[t], lR = R[t], lS = S[t];
        for (int p = 0; p < PD; ++p) {
            float dI = a_s * lI * (lS / Np) - b_s * lI;
            float dR = b_s * lI;
            lI += dI;
            lR += dR;
            lS = Np - lI - lR;
            out[7680  + t * 60 + p] = dI;
            out[11520 + t * 60 + p] = dR;
        }
    }
}

// ---------------------------------------------------------------------------
extern "C" void kernel_launch(void* const* d_in, const int* in_sizes, int n_in,
                              void* d_out, int out_size, void* d_ws, size_t ws_size,
                              hipStream_t stream) {
    const float* h    = (const float*)d_in[0];
    const int*   ng   = (const int*)  d_in[1];
    const float* Npop = (const float*)d_in[2];
    const float* I_   = (const float*)d_in[3];
    const float* R_   = (const float*)d_in[4];
    const float* S_   = (const float*)d_in[5];
    const float* It   = (const float*)d_in[6];
    const float* Rt   = (const float*)d_in[7];
    const float* fc1  = (const float*)d_in[8];
    const float* fc2  = (const float*)d_in[9];
    const float* gWih = (const float*)d_in[10];
    const float* gWhh = (const float*)d_in[11];
    const float* gbih = (const float*)d_in[12];
    const float* gbhh = (const float*)d_in[13];
    const float* r1W  = (const float*)d_in[14];
    const float* r1b  = (const float*)d_in[15];
    const float* r2W  = (const float*)d_in[16];
    const float* r2b  = (const float*)d_in[17];
    const float* hx0  = (const float*)d_in[18];
    float* out = (float*)d_out;

    // ---- workspace carve-up (all region sizes 16B-aligned) ----
    char* w = (char*)d_ws;
    float* pooled = (float*)w; w += (size_t)T_STEPS * H2D * 4;      // 32 KB
    float* hx_all = (float*)w; w += (size_t)T_STEPS * GD * 4;       // 64 KB
    float* gi_all = (float*)w; w += (size_t)T_STEPS * 768 * 4;      // 192 KB
    float* ppart  = (float*)w; w += (size_t)T_STEPS * 16 * H2D * 4; // 512 KB
    __hip_bfloat16* W1Thi = (__hip_bfloat16*)w; w += (size_t)384 * 256 * 2; // 192 KB
    __hip_bfloat16* W1Tlo = (__hip_bfloat16*)w; w += (size_t)384 * 256 * 2;
    __hip_bfloat16* f2Thi = (__hip_bfloat16*)w; w += (size_t)128 * 384 * 2; // 96 KB
    __hip_bfloat16* f2Tlo = (__hip_bfloat16*)w; w += (size_t)128 * 384 * 2;
    unsigned int* cnt = (unsigned int*)w; w += 256;                 // 64 ctr + pad
    size_t fixed = (size_t)(w - (char*)d_ws);

    // per-Tc bytes: norms 8KB + pairA 2MB (ihHi/ihLo; later z2+c2) +
    //               z1 3MB + pairC 3MB (cHi/cLo)
    const size_t perTc = 8192 + 2097152 + 3145728 + 3145728;
    int Tc = 16;
    while (Tc > 1) {
        if (fixed + (size_t)Tc * perTc <= ws_size) break;
        Tc >>= 1;
    }
    float* norms = (float*)w;             w += (size_t)Tc * NN * 4;
    char*  pairA = w;                     w += (size_t)Tc * NN * 256 * 2 * 2;
    float* z1    = (float*)w;             w += (size_t)Tc * NN * C1D * 4;
    __hip_bfloat16* cHi = (__hip_bfloat16*)w; w += (size_t)Tc * NN * C1D * 2;
    __hip_bfloat16* cLo = (__hip_bfloat16*)w;

    __hip_bfloat16* ihHi = (__hip_bfloat16*)pairA;
    __hip_bfloat16* ihLo = ihHi + (size_t)Tc * NN * 256;
    // z2 + c2 overlay pairA after GEMM1 consumed ihHi/ihLo
    float* z2 = (float*)pairA;
    float* c2 = z2 + (size_t)Tc * NN * H2D;

    prep_kernel<<<(384 * 256 + 255) / 256, 256, 0, stream>>>(fc1, fc2, W1Thi, W1Tlo,
                                                             f2Thi, f2Tlo, cnt);

    for (int t0 = 0; t0 < T_STEPS; t0 += Tc) {
        int M = Tc * NN;
        norms_kernel      <<<Tc * NN / 4, 256, 0, stream>>>(h, norms, t0);
        input_attn_kernel <<<Tc * NN,     256, 0, stream>>>(h, ng, norms, ihHi, ihLo, t0);
        // z1 = ih @ W1  (M x 256) @ (256 x 384), bf16x3 MFMA
        gemm_bf16x3<<<dim3(384 / 64, M / 64), 256, 0, stream>>>(ihHi, ihLo, W1Thi, W1Tlo,
                                                                z1, M, 384, 256);
        gat_heads_kernel  <<<Tc * NN, 384, 0, stream>>>(z1, ng, cHi, cLo);
        // z2 = c @ fc2  (M x 384) @ (384 x 128), bf16x3 MFMA
        gemm_bf16x3<<<dim3(128 / 64, M / 64), 256, 0, stream>>>(cHi, cLo, f2Thi, f2Tlo,
                                                                z2, M, 128, 384);
        gat_final_kernel  <<<Tc * NN / 2, 256, 0, stream>>>(z2, ng, c2);
        pool_part_kernel  <<<Tc * 16, 128, 0, stream>>>(c2, ppart);
        pool_reduce_kernel<<<Tc, 128, 0, stream>>>(ppart, pooled, t0);
    }

    gi_all_kernel<<<T_STEPS * 3, 256, 0, stream>>>(gWih, gbih, pooled, gi_all);
    gru_reg_kernel<<<GRU_NB, 768, 0, stream>>>(gWhh, gbhh, gi_all, hx0, hx_all, cnt);
    res_sir_kernel<<<T_STEPS, 128, 0, stream>>>(hx_all, It, Rt, r1W, r1b, r2W, r2b,
                                                I_, R_, S_, Npop, out);
}

// Round 13
// 1566.429 us; speedup vs baseline: 1.1346x; 1.1346x over previous
//
#include <hip/hip_runtime.h>
#include <hip/hip_bf16.h>
#include <math.h>

// Problem constants
#define T_STEPS 64
#define NN      2048
#define KN      32
#define IND     256
#define H1D     128
#define C1D     384   // HEADS*H1
#define H2D     128
#define GD      256
#define PD      60
#define GRU_NB  8     // cooperating blocks for the GRU

typedef __attribute__((ext_vector_type(8))) short bf16x8v;  // 8 bf16 = 4 VGPR
typedef __attribute__((ext_vector_type(4))) float f32x4v;

// bit-reversed 5-bit order (involution)
#define BITREV5_INIT {0,16,8,24,4,20,12,28,2,18,10,26,6,22,14,30, \
                      1,17,9,25,5,21,13,29,3,19,11,27,7,23,15,31}

__device__ __forceinline__ float bcast_lane(float v, int lane_imm) {
    return __uint_as_float(__builtin_amdgcn_readlane(__float_as_uint(v), lane_imm));
}

__device__ __forceinline__ void bf16_split(float v, __hip_bfloat16* hi, __hip_bfloat16* lo) {
    __hip_bfloat16 h = __float2bfloat16(v);
    *hi = h;
    *lo = __float2bfloat16(v - __bfloat162float(h));
}

// Butterfly stages 2..6 on 16 stage-1-combined partials.
__device__ __forceinline__ float xpose_reduce16(float part[16], int lane) {
#pragma unroll
    for (int i = 0; i < 8; ++i) {
        float send = (lane & 2) ? part[i] : part[i + 8];
        float keep = (lane & 2) ? part[i + 8] : part[i];
        part[i] = keep + __shfl_xor(send, 2);
    }
#pragma unroll
    for (int i = 0; i < 4; ++i) {
        float send = (lane & 4) ? part[i] : part[i + 4];
        float keep = (lane & 4) ? part[i + 4] : part[i];
        part[i] = keep + __shfl_xor(send, 4);
    }
#pragma unroll
    for (int i = 0; i < 2; ++i) {
        float send = (lane & 8) ? part[i] : part[i + 2];
        float keep = (lane & 8) ? part[i + 2] : part[i];
        part[i] = keep + __shfl_xor(send, 8);
    }
    {
        float send = (lane & 16) ? part[0] : part[1];
        float keep = (lane & 16) ? part[1] : part[0];
        part[0] = keep + __shfl_xor(send, 16);
    }
    return part[0] + __shfl_xor(part[0], 32);
}

// ---------------------------------------------------------------------------
// K1: row norms of h[t]  (one wave per node, single float4 load)
// ---------------------------------------------------------------------------
__global__ __launch_bounds__(256) void norms_kernel(const float* __restrict__ h,
                                                    float* __restrict__ norms,
                                                    int t_base) {
    int gw   = (int)((blockIdx.x * blockDim.x + threadIdx.x) >> 6);
    int lane = threadIdx.x & 63;
    int n    = gw & (NN - 1);
    int tloc = gw >> 11;
    const float4* row = (const float4*)(h + ((size_t)(t_base + tloc) * NN + n) * IND);
    float4 v = row[lane];
    float s = v.x * v.x + v.y * v.y + v.z * v.z + v.w * v.w;
#pragma unroll
    for (int off = 32; off > 0; off >>= 1) s += __shfl_xor(s, off);
    if (lane == 0) norms[(size_t)tloc * NN + n] = sqrtf(s);
}

// ---------------------------------------------------------------------------
// K2: input attention. 2 waves per (t,n); rows in VGPRs (keep-alive),
// scalar SGPR row bases. Output: bf16 hi/lo pair (feeds MFMA GEMM).
// ---------------------------------------------------------------------------
__global__ __launch_bounds__(256, 4) void input_attn_kernel(const float* __restrict__ h,
                                                            const int* __restrict__ neigh,
                                                            const float* __restrict__ norms,
                                                            __hip_bfloat16* __restrict__ ihHi,
                                                            __hip_bfloat16* __restrict__ ihLo,
                                                            int t_base) {
    const int BR[32] = BITREV5_INIT;
    __shared__ float hd_s[2][2][32];
    int wave    = threadIdx.x >> 6;   // 0..3
    int nodeloc = wave >> 1;          // 0..1
    int half    = wave & 1;           // which 128-dim half
    int lane    = threadIdx.x & 63;
    int gw   = (int)((blockIdx.x << 1) | nodeloc);
    int n    = gw & (NN - 1);
    int tloc = gw >> 11;
    const float* hT  = h + (size_t)(t_base + tloc) * NN * IND;
    const float* nrm = norms + (size_t)tloc * NN;

    const float* dst = hT + (size_t)n * IND + half * 128;
    float d0 = dst[lane], d1 = dst[lane + 64];

    int   jreg = neigh[n * KN + (lane & 31)];
    float nj   = nrm[jreg];
    float ndst = nrm[n];

    float r0[32], r1[32], comb[16];
#pragma unroll
    for (int i = 0; i < 16; ++i) {
        int sja = __builtin_amdgcn_readlane(jreg, BR[i]);
        int sjb = __builtin_amdgcn_readlane(jreg, BR[i + 16]);
        const float* sa = hT + (size_t)sja * IND + half * 128;
        const float* sb = hT + (size_t)sjb * IND + half * 128;
        r0[i]      = sa[lane]; r1[i]      = sa[lane + 64];
        r0[i + 16] = sb[lane]; r1[i + 16] = sb[lane + 64];
        float pa = r0[i] * d0 + r1[i] * d1;
        float pb = r0[i + 16] * d0 + r1[i + 16] * d1;
        float send = (lane & 1) ? pa : pb;
        float keep = (lane & 1) ? pb : pa;
        comb[i] = keep + __shfl_xor(send, 1);
    }
#pragma unroll
    for (int i = 0; i < 32; ++i) asm volatile("" : "+v"(r0[i]), "+v"(r1[i]));
    float hdot = xpose_reduce16(comb, lane);   // half-dot of neighbor (lane&31)
    if (lane < 32) hd_s[nodeloc][half][lane] = hdot;
    __syncthreads();
    float dot = hdot + hd_s[nodeloc][half ^ 1][lane & 31];

    float r  = dot / (nj * ndst);
    float r2 = r * r;
    float e  = r2 * r2;

    float a0 = 0.f, a1 = 0.f;
#pragma unroll
    for (int i = 0; i < 32; ++i) {
        float ek = bcast_lane(e, BR[i]);
        a0 += ek * r0[i];
        a1 += ek * r1[i];
    }
    size_t base = (size_t)gw * IND + half * 128;
    __hip_bfloat16 hi, lo;
    bf16_split(a0, &hi, &lo);
    ihHi[base + lane] = hi;       ihLo[base + lane] = lo;
    bf16_split(a1, &hi, &lo);
    ihHi[base + lane + 64] = hi;  ihLo[base + lane + 64] = lo;
}

// ---------------------------------------------------------------------------
// MFMA GEMM, bf16x3 error-compensated split, LDS-staged (coalesced loads).
// A: [M][K] bf16 pairs. BT: [N][K] bf16 pairs. C: fp32.
// BM=BN=64, BK=32, 256 thr = 4 waves; wave w owns rows [w*16, w*16+16).
// LDS rows padded to 40 bf16 (80 B) -> 2-way bank aliasing (free).
// ---------------------------------------------------------------------------
__global__ __launch_bounds__(256) void gemm_bf16x3(const __hip_bfloat16* __restrict__ Ahi,
                                                   const __hip_bfloat16* __restrict__ Alo,
                                                   const __hip_bfloat16* __restrict__ BThi,
                                                   const __hip_bfloat16* __restrict__ BTlo,
                                                   float* __restrict__ C,
                                                   int M, int N, int K) {
    __shared__ short Ah[64][40], Al[64][40], Bh[64][40], Bl[64][40];
    int tid  = threadIdx.x;
    int lane = tid & 63;
    int w    = tid >> 6;
    int mb   = blockIdx.y * 64;
    int n0   = blockIdx.x * 64;
    int r    = lane & 15;        // row within fragment
    int g    = lane >> 4;        // k-group: k = g*8 .. g*8+7
    int lrow = tid >> 2;         // loader row 0..63
    int lseg = tid & 3;          // loader 16B segment 0..3

    const size_t aoff = (size_t)(mb + lrow) * K + lseg * 8;
    const size_t boff = (size_t)(n0 + lrow) * K + lseg * 8;

    f32x4v acc[4] = {};
    for (int k0 = 0; k0 < K; k0 += 32) {
        __syncthreads();
        *(bf16x8v*)&Ah[lrow][lseg * 8] = *(const bf16x8v*)(Ahi + aoff + k0);
        *(bf16x8v*)&Al[lrow][lseg * 8] = *(const bf16x8v*)(Alo + aoff + k0);
        *(bf16x8v*)&Bh[lrow][lseg * 8] = *(const bf16x8v*)(BThi + boff + k0);
        *(bf16x8v*)&Bl[lrow][lseg * 8] = *(const bf16x8v*)(BTlo + boff + k0);
        __syncthreads();
        bf16x8v ah = *(const bf16x8v*)&Ah[w * 16 + r][g * 8];
        bf16x8v al = *(const bf16x8v*)&Al[w * 16 + r][g * 8];
#pragma unroll
        for (int nt = 0; nt < 4; ++nt) {
            bf16x8v bh = *(const bf16x8v*)&Bh[nt * 16 + r][g * 8];
            bf16x8v bl = *(const bf16x8v*)&Bl[nt * 16 + r][g * 8];
            acc[nt] = __builtin_amdgcn_mfma_f32_16x16x32_bf16(ah, bh, acc[nt], 0, 0, 0);
            acc[nt] = __builtin_amdgcn_mfma_f32_16x16x32_bf16(ah, bl, acc[nt], 0, 0, 0);
            acc[nt] = __builtin_amdgcn_mfma_f32_16x16x32_bf16(al, bh, acc[nt], 0, 0, 0);
        }
    }
    // C/D layout: col = lane&15, row = (lane>>4)*4 + reg   [m89-verified]
#pragma unroll
    for (int nt = 0; nt < 4; ++nt)
#pragma unroll
        for (int q = 0; q < 4; ++q)
            C[(size_t)(mb + w * 16 + g * 4 + q) * N + n0 + nt * 16 + r] = acc[nt][q];
}

// ---------------------------------------------------------------------------
// K4: 3-head GAT + relu. One block (192 thr, wave=head) per (t,n).
// Output: bf16 hi/lo pair (feeds GEMM2).
// ---------------------------------------------------------------------------
__global__ __launch_bounds__(192, 4) void gat_heads_kernel(const float* __restrict__ z1,
                                                           const int* __restrict__ neigh,
                                                           __hip_bfloat16* __restrict__ cHi,
                                                           __hip_bfloat16* __restrict__ cLo) {
    const int BR[32] = BITREV5_INIT;
    int n    = blockIdx.x & (NN - 1);
    const float* ztbl = z1 + (size_t)(blockIdx.x >> 11) * NN * C1D;
    int head = threadIdx.x >> 6;
    int lane = threadIdx.x & 63;

    const float* dst = ztbl + (size_t)n * C1D + head * H1D;
    float d0 = dst[lane], d1 = dst[lane + 64];
    int jreg = neigh[n * KN + (lane & 31)];

    float r0[32], r1[32], comb[16];
#pragma unroll
    for (int i = 0; i < 16; ++i) {
        int sja = __builtin_amdgcn_readlane(jreg, BR[i]);
        int sjb = __builtin_amdgcn_readlane(jreg, BR[i + 16]);
        const float* sa = ztbl + (size_t)sja * C1D + head * H1D;
        const float* sb = ztbl + (size_t)sjb * C1D + head * H1D;
        r0[i]      = sa[lane]; r1[i]      = sa[lane + 64];
        r0[i + 16] = sb[lane]; r1[i + 16] = sb[lane + 64];
        float pa = r0[i] * d0 + r1[i] * d1;
        float pb = r0[i + 16] * d0 + r1[i + 16] * d1;
        float send = (lane & 1) ? pa : pb;
        float keep = (lane & 1) ? pb : pa;
        comb[i] = keep + __shfl_xor(send, 1);
    }
#pragma unroll
    for (int i = 0; i < 32; ++i) asm volatile("" : "+v"(r0[i]), "+v"(r1[i]));
    float dot = xpose_reduce16(comb, lane);

    float m = dot;
#pragma unroll
    for (int off = 16; off > 0; off >>= 1) m = fmaxf(m, __shfl_xor(m, off));
    float p = __expf(dot - m);
    float s = p;
#pragma unroll
    for (int off = 16; off > 0; off >>= 1) s += __shfl_xor(s, off);
    p /= s;

    float a0 = 0.f, a1 = 0.f;
#pragma unroll
    for (int i = 0; i < 32; ++i) {
        float pk = bcast_lane(p, BR[i]);
        a0 += pk * r0[i];
        a1 += pk * r1[i];
    }
    size_t base = (size_t)blockIdx.x * C1D + (size_t)head * H1D;
    __hip_bfloat16 hi, lo;
    bf16_split(fmaxf(a0, 0.f), &hi, &lo);
    cHi[base + lane] = hi;       cLo[base + lane] = lo;
    bf16_split(fmaxf(a1, 0.f), &hi, &lo);
    cHi[base + lane + 64] = hi;  cLo[base + lane + 64] = lo;
}

// ---------------------------------------------------------------------------
// K7: final GAT on z2 (d=128) + relu + FUSED partial max-pool.
// One wave per (t,n); 4 nodes (same t) per block -> one 128-float partial.
// ---------------------------------------------------------------------------
__global__ __launch_bounds__(256, 4) void gat_final_kernel(const float* __restrict__ z2,
                                                           const int* __restrict__ neigh,
                                                           float* __restrict__ ppart) {
    const int BR[32] = BITREV5_INIT;
    __shared__ float red_s[4][128];
    int wave = threadIdx.x >> 6;
    int gw   = (int)((blockIdx.x << 2) | wave);
    int n    = gw & (NN - 1);
    const float* ztbl = z2 + (size_t)(gw >> 11) * NN * H2D;
    int lane = threadIdx.x & 63;

    const float* dst = ztbl + (size_t)n * H2D;
    float d0 = dst[lane], d1 = dst[lane + 64];
    int jreg = neigh[n * KN + (lane & 31)];

    float r0[32], r1[32], comb[16];
#pragma unroll
    for (int i = 0; i < 16; ++i) {
        int sja = __builtin_amdgcn_readlane(jreg, BR[i]);
        int sjb = __builtin_amdgcn_readlane(jreg, BR[i + 16]);
        const float* sa = ztbl + (size_t)sja * H2D;
        const float* sb = ztbl + (size_t)sjb * H2D;
        r0[i]      = sa[lane]; r1[i]      = sa[lane + 64];
        r0[i + 16] = sb[lane]; r1[i + 16] = sb[lane + 64];
        float pa = r0[i] * d0 + r1[i] * d1;
        float pb = r0[i + 16] * d0 + r1[i + 16] * d1;
        float send = (lane & 1) ? pa : pb;
        float keep = (lane & 1) ? pb : pa;
        comb[i] = keep + __shfl_xor(send, 1);
    }
#pragma unroll
    for (int i = 0; i < 32; ++i) asm volatile("" : "+v"(r0[i]), "+v"(r1[i]));
    float dot = xpose_reduce16(comb, lane);

    float m = dot;
#pragma unroll
    for (int off = 16; off > 0; off >>= 1) m = fmaxf(m, __shfl_xor(m, off));
    float p = __expf(dot - m);
    float s = p;
#pragma unroll
    for (int off = 16; off > 0; off >>= 1) s += __shfl_xor(s, off);
    p /= s;

    float a0 = 0.f, a1 = 0.f;
#pragma unroll
    for (int i = 0; i < 32; ++i) {
        float pk = bcast_lane(p, BR[i]);
        a0 += pk * r0[i];
        a1 += pk * r1[i];
    }
    red_s[wave][lane]      = fmaxf(a0, 0.f);
    red_s[wave][lane + 64] = fmaxf(a1, 0.f);
    __syncthreads();
    int tid = threadIdx.x;
    if (tid < 128) {
        float mx = fmaxf(fmaxf(red_s[0][tid], red_s[1][tid]),
                         fmaxf(red_s[2][tid], red_s[3][tid]));
        ppart[(size_t)blockIdx.x * H2D + tid] = mx;
    }
}

// ---------------------------------------------------------------------------
// K8: pooled[t][j] = max over NN/4 = 512 block-partials
// ---------------------------------------------------------------------------
__global__ __launch_bounds__(128) void pool_reduce_kernel(const float* __restrict__ ppart,
                                                          float* __restrict__ pooled,
                                                          int t_base) {
    int j = threadIdx.x;
    const float* base = ppart + (size_t)blockIdx.x * 512 * H2D;
    float mx = 0.f;
#pragma unroll 8
    for (int q = 0; q < 512; ++q) mx = fmaxf(mx, base[(size_t)q * H2D + j]);
    pooled[(t_base + blockIdx.x) * H2D + j] = mx;
}

// ---------------------------------------------------------------------------
// prep: weights -> transposed bf16 hi/lo pairs; zero GRU counters.
// ---------------------------------------------------------------------------
__global__ void prep_kernel(const float* __restrict__ fc1, const float* __restrict__ fc2,
                            __hip_bfloat16* __restrict__ W1Thi, __hip_bfloat16* __restrict__ W1Tlo,
                            __hip_bfloat16* __restrict__ f2Thi, __hip_bfloat16* __restrict__ f2Tlo,
                            unsigned int* __restrict__ cnt) {
    int i = blockIdx.x * 256 + threadIdx.x;
    if (i < 384 * 256) {
        int cf = i / 256, d = i % 256;
        int hd = cf >> 7, j = cf & 127;
        float v = fc1[(size_t)hd * 256 * 128 + (size_t)d * 128 + j];
        __hip_bfloat16 hi, lo;
        bf16_split(v, &hi, &lo);
        W1Thi[i] = hi; W1Tlo[i] = lo;
    }
    if (i < 128 * 384) {
        int n = i / 384, k = i % 384;
        float v = fc2[(size_t)k * 128 + n];
        __hip_bfloat16 hi, lo;
        bf16_split(v, &hi, &lo);
        f2Thi[i] = hi; f2Tlo[i] = lo;
    }
    if (i < T_STEPS) cnt[i] = 0u;
}

// ---------------------------------------------------------------------------
// gi_all[t][o] = Wih[o,:] . pooled[t,:] + bih[o]   (parallel over t)
// ---------------------------------------------------------------------------
__global__ __launch_bounds__(256) void gi_all_kernel(const float* __restrict__ Wih,
                                                     const float* __restrict__ bih,
                                                     const float* __restrict__ pooled,
                                                     float* __restrict__ gi_all) {
    __shared__ float p_s[H2D];
    int t  = blockIdx.x / 3;
    int ob = (blockIdx.x % 3) * 256;
    if (threadIdx.x < H2D) p_s[threadIdx.x] = pooled[t * H2D + threadIdx.x];
    __syncthreads();
    int o = ob + threadIdx.x;
    float acc = bih[o];
    const float* wr = Wih + (size_t)o * H2D;
#pragma unroll 4
    for (int d = 0; d < H2D; ++d) acc += wr[d] * p_s[d];
    gi_all[t * 768 + o] = acc;
}

// ---------------------------------------------------------------------------
// GRU: 8 cooperating blocks, Whh register-resident.
// ---------------------------------------------------------------------------
__global__ __launch_bounds__(768) void gru_reg_kernel(const float* __restrict__ Whh,
                                                      const float* __restrict__ bhh,
                                                      const float* __restrict__ gi_all,
                                                      const float* __restrict__ hx0,
                                                      float* hx_all,
                                                      unsigned int* cnt) {
    __shared__ float4 hx_pad[72];                 // padded: idx (g,i) -> g*9+i
    __shared__ __align__(16) float hx_lin[GD];    // linear copy for hx_old
    __shared__ float gh_s[96];
    int b   = blockIdx.x;
    int tid = threadIdx.x;
    int row_local = tid >> 3;      // 0..95
    int sub       = tid & 7;       // 0..7
    int chunk     = row_local >> 5;
    int r_in      = row_local & 31;
    int grow      = chunk * GD + b * 32 + r_in;

    float4 wreg[8];
    const float4* wrow = (const float4*)(Whh + (size_t)grow * GD + sub * 32);
#pragma unroll
    for (int i = 0; i < 8; ++i) wreg[i] = wrow[i];
    float bias = (sub == 0) ? bhh[grow] : 0.f;

    for (int t = 0; t < T_STEPS; ++t) {
        if (t > 0) {
            if (tid == 0) {
                while (__hip_atomic_load(&cnt[t - 1], __ATOMIC_ACQUIRE,
                                         __HIP_MEMORY_SCOPE_AGENT) < GRU_NB)
                    __builtin_amdgcn_s_sleep(1);
            }
            __syncthreads();
        }
        const float* hsrc = (t == 0) ? hx0 : (hx_all + (size_t)(t - 1) * GD);
        if (tid < 64) {
            float4 v;
            v.x = __hip_atomic_load(hsrc + tid * 4 + 0, __ATOMIC_RELAXED, __HIP_MEMORY_SCOPE_AGENT);
            v.y = __hip_atomic_load(hsrc + tid * 4 + 1, __ATOMIC_RELAXED, __HIP_MEMORY_SCOPE_AGENT);
            v.z = __hip_atomic_load(hsrc + tid * 4 + 2, __ATOMIC_RELAXED, __HIP_MEMORY_SCOPE_AGENT);
            v.w = __hip_atomic_load(hsrc + tid * 4 + 3, __ATOMIC_RELAXED, __HIP_MEMORY_SCOPE_AGENT);
            hx_pad[(tid >> 3) * 9 + (tid & 7)] = v;
            ((float4*)hx_lin)[tid] = v;
        }
        __syncthreads();

        float acc = 0.f;
#pragma unroll
        for (int i = 0; i < 8; ++i) {
            float4 hv = hx_pad[sub * 9 + i];
            float4 wv = wreg[i];
            acc += wv.x * hv.x + wv.y * hv.y + wv.z * hv.z + wv.w * hv.w;
        }
        acc += __shfl_xor(acc, 1);
        acc += __shfl_xor(acc, 2);
        acc += __shfl_xor(acc, 4);
        if (sub == 0) gh_s[row_local] = acc + bias;
        __syncthreads();

        if (tid < 32) {
            int u = b * 32 + tid;
            float gi_r = gi_all[t * 768 + u];
            float gi_z = gi_all[t * 768 + 256 + u];
            float gi_n = gi_all[t * 768 + 512 + u];
            float r  = 1.f / (1.f + expf(-(gi_r + gh_s[tid])));
            float zg = 1.f / (1.f + expf(-(gi_z + gh_s[32 + tid])));
            float nn = tanhf(gi_n + r * gh_s[64 + tid]);
            float hnew = (1.f - zg) * nn + zg * hx_lin[u];
            __hip_atomic_store(&hx_all[(size_t)t * GD + u], hnew,
                               __ATOMIC_RELAXED, __HIP_MEMORY_SCOPE_AGENT);
        }
        __syncthreads();
        if (tid == 0)
            __hip_atomic_fetch_add(&cnt[t], 1u, __ATOMIC_RELEASE,
                                   __HIP_MEMORY_SCOPE_AGENT);
    }
}

// ---------------------------------------------------------------------------
// res heads + SIR scan. One block per t.
// ---------------------------------------------------------------------------
__global__ __launch_bounds__(128) void res_sir_kernel(const float* __restrict__ hx_all,
                                                      const float* __restrict__ It,
                                                      const float* __restrict__ Rt,
                                                      const float* __restrict__ r1W,
                                                      const float* __restrict__ r1b,
                                                      const float* __restrict__ r2W,
                                                      const float* __restrict__ r2b,
                                                      const float* __restrict__ I,
                                                      const float* __restrict__ R,
                                                      const float* __restrict__ S,
                                                      const float* __restrict__ Npop,
                                                      float* __restrict__ out) {
    __shared__ float nhx[258];
    __shared__ float ab_s[2];
    int t = blockIdx.x, tid = threadIdx.x;
    for (int i = tid; i < GD; i += 128) nhx[i] = hx_all[t * GD + i];
    if (tid == 0) { nhx[256] = It[t]; nhx[257] = Rt[t]; }
    __syncthreads();
    if (tid < 120) {
        float acc = r1b[tid];
        const float* wr = r1W + tid * 258;
        for (int d = 0; d < 258; ++d) acc += wr[d] * nhx[d];
        int idx = t * 60 + (tid >> 1);
        if (tid & 1) out[3840 + idx] = acc;
        else         out[idx] = acc;
    }
    if (tid == 120 || tid == 121) {
        int q = tid - 120;
        float acc = r2b[q];
        const float* wr = r2W + q * 258;
        for (int d = 0; d < 258; ++d) acc += wr[d] * nhx[d];
        ab_s[q] = acc;
    }
    __syncthreads();
    if (tid == 0) {
        float a_s = 1.f / (1.f + expf(-ab_s[0]));
        float b_s = 1.f / (1.f + expf(-ab_s[1]));
        float Np = Npop[0];
        float lI = I[t], lR = R[t], lS = S[t];
        for (int p = 0; p < PD; ++p) {
            float dI = a_s * lI * (lS / Np) - b_s * lI;
            float dR = b_s * lI;
            lI += dI;
            lR += dR;
            lS = Np - lI - lR;
            out[7680  + t * 60 + p] = dI;
            out[11520 + t * 60 + p] = dR;
        }
    }
}

// ---------------------------------------------------------------------------
extern "C" void kernel_launch(void* const* d_in, const int* in_sizes, int n_in,
                              void* d_out, int out_size, void* d_ws, size_t ws_size,
                              hipStream_t stream) {
    const float* h    = (const float*)d_in[0];
    const int*   ng   = (const int*)  d_in[1];
    const float* Npop = (const float*)d_in[2];
    const float* I_   = (const float*)d_in[3];
    const float* R_   = (const float*)d_in[4];
    const float* S_   = (const float*)d_in[5];
    const float* It   = (const float*)d_in[6];
    const float* Rt   = (const float*)d_in[7];
    const float* fc1  = (const float*)d_in[8];
    const float* fc2  = (const float*)d_in[9];
    const float* gWih = (const float*)d_in[10];
    const float* gWhh = (const float*)d_in[11];
    const float* gbih = (const float*)d_in[12];
    const float* gbhh = (const float*)d_in[13];
    const float* r1W  = (const float*)d_in[14];
    const float* r1b  = (const float*)d_in[15];
    const float* r2W  = (const float*)d_in[16];
    const float* r2b  = (const float*)d_in[17];
    const float* hx0  = (const float*)d_in[18];
    float* out = (float*)d_out;

    // ---- workspace carve-up (all region sizes 16B-aligned) ----
    char* w = (char*)d_ws;
    float* pooled = (float*)w; w += (size_t)T_STEPS * H2D * 4;      // 32 KB
    float* hx_all = (float*)w; w += (size_t)T_STEPS * GD * 4;       // 64 KB
    float* gi_all = (float*)w; w += (size_t)T_STEPS * 768 * 4;      // 192 KB
    float* ppart  = (float*)w; w += (size_t)16 * 512 * H2D * 4;     // 4 MB (Tc<=16)
    __hip_bfloat16* W1Thi = (__hip_bfloat16*)w; w += (size_t)384 * 256 * 2; // 192 KB
    __hip_bfloat16* W1Tlo = (__hip_bfloat16*)w; w += (size_t)384 * 256 * 2;
    __hip_bfloat16* f2Thi = (__hip_bfloat16*)w; w += (size_t)128 * 384 * 2; // 96 KB
    __hip_bfloat16* f2Tlo = (__hip_bfloat16*)w; w += (size_t)128 * 384 * 2;
    unsigned int* cnt = (unsigned int*)w; w += 256;                 // 64 ctr + pad
    size_t fixed = (size_t)(w - (char*)d_ws);

    // per-Tc bytes: norms 8KB + pairA 2MB (ihHi/ihLo; later z2) +
    //               z1 3MB + pairC 3MB (cHi/cLo)
    const size_t perTc = 8192 + 2097152 + 3145728 + 3145728;
    int Tc = 16;
    while (Tc > 1) {
        if (fixed + (size_t)Tc * perTc <= ws_size) break;
        Tc >>= 1;
    }
    float* norms = (float*)w;             w += (size_t)Tc * NN * 4;
    char*  pairA = w;                     w += (size_t)Tc * NN * 256 * 2 * 2;
    float* z1    = (float*)w;             w += (size_t)Tc * NN * C1D * 4;
    __hip_bfloat16* cHi = (__hip_bfloat16*)w; w += (size_t)Tc * NN * C1D * 2;
    __hip_bfloat16* cLo = (__hip_bfloat16*)w;

    __hip_bfloat16* ihHi = (__hip_bfloat16*)pairA;
    __hip_bfloat16* ihLo = ihHi + (size_t)Tc * NN * 256;
    // z2 overlays pairA after GEMM1 consumed ihHi/ihLo
    float* z2 = (float*)pairA;

    prep_kernel<<<(384 * 256 + 255) / 256, 256, 0, stream>>>(fc1, fc2, W1Thi, W1Tlo,
                                                             f2Thi, f2Tlo, cnt);

    for (int t0 = 0; t0 < T_STEPS; t0 += Tc) {
        int M = Tc * NN;
        norms_kernel      <<<Tc * NN / 4, 256, 0, stream>>>(h, norms, t0);
        input_attn_kernel <<<Tc * NN / 2, 256, 0, stream>>>(h, ng, norms, ihHi, ihLo, t0);
        // z1 = ih @ W1  (M x 256) @ (256 x 384), bf16x3 MFMA, LDS-staged
        gemm_bf16x3<<<dim3(384 / 64, M / 64), 256, 0, stream>>>(ihHi, ihLo, W1Thi, W1Tlo,
                                                                z1, M, 384, 256);
        gat_heads_kernel  <<<Tc * NN, 192, 0, stream>>>(z1, ng, cHi, cLo);
        // z2 = c @ fc2  (M x 384) @ (384 x 128), bf16x3 MFMA, LDS-staged
        gemm_bf16x3<<<dim3(128 / 64, M / 64), 256, 0, stream>>>(cHi, cLo, f2Thi, f2Tlo,
                                                                z2, M, 128, 384);
        gat_final_kernel  <<<Tc * NN / 4, 256, 0, stream>>>(z2, ng, ppart);
        pool_reduce_kernel<<<Tc, 128, 0, stream>>>(ppart, pooled, t0);
    }

    gi_all_kernel<<<T_STEPS * 3, 256, 0, stream>>>(gWih, gbih, pooled, gi_all);
    gru_reg_kernel<<<GRU_NB, 768, 0, stream>>>(gWhh, gbhh, gi_all, hx0, hx_all, cnt);
    res_sir_kernel<<<T_STEPS, 128, 0, stream>>>(hx_all, It, Rt, r1W, r1b, r2W, r2b,
                                                I_, R_, S_, Npop, out);
}

// Round 14
// 1542.300 us; speedup vs baseline: 1.1524x; 1.0156x over previous
//
#include <hip/hip_runtime.h>
#include <hip/hip_bf16.h>
#include <math.h>

// Problem constants
#define T_STEPS 64
#define NN      2048
#define KN      32
#define IND     256
#define H1D     128
#define C1D     384   // HEADS*H1
#define H2D     128
#define GD      256
#define PD      60
#define GRU_NB  8     // cooperating blocks for the GRU

typedef __attribute__((ext_vector_type(8))) short bf16x8v;  // 8 bf16 = 4 VGPR
typedef __attribute__((ext_vector_type(4))) float f32x4v;

// bit-reversed 5-bit order (involution)
#define BITREV5_INIT {0,16,8,24,4,20,12,28,2,18,10,26,6,22,14,30, \
                      1,17,9,25,5,21,13,29,3,19,11,27,7,23,15,31}

__device__ __forceinline__ float bcast_lane(float v, int lane_imm) {
    return __uint_as_float(__builtin_amdgcn_readlane(__float_as_uint(v), lane_imm));
}

__device__ __forceinline__ void bf16_split(float v, __hip_bfloat16* hi, __hip_bfloat16* lo) {
    __hip_bfloat16 h = __float2bfloat16(v);
    *hi = h;
    *lo = __float2bfloat16(v - __bfloat162float(h));
}

// Butterfly stages 2..6 on 16 stage-1-combined partials.
__device__ __forceinline__ float xpose_reduce16(float part[16], int lane) {
#pragma unroll
    for (int i = 0; i < 8; ++i) {
        float send = (lane & 2) ? part[i] : part[i + 8];
        float keep = (lane & 2) ? part[i + 8] : part[i];
        part[i] = keep + __shfl_xor(send, 2);
    }
#pragma unroll
    for (int i = 0; i < 4; ++i) {
        float send = (lane & 4) ? part[i] : part[i + 4];
        float keep = (lane & 4) ? part[i + 4] : part[i];
        part[i] = keep + __shfl_xor(send, 4);
    }
#pragma unroll
    for (int i = 0; i < 2; ++i) {
        float send = (lane & 8) ? part[i] : part[i + 2];
        float keep = (lane & 8) ? part[i + 2] : part[i];
        part[i] = keep + __shfl_xor(send, 8);
    }
    {
        float send = (lane & 16) ? part[0] : part[1];
        float keep = (lane & 16) ? part[1] : part[0];
        part[0] = keep + __shfl_xor(send, 16);
    }
    return part[0] + __shfl_xor(part[0], 32);
}

// ---------------------------------------------------------------------------
// K1: row norms of h[t]  (one wave per node, single float4 load)
// ---------------------------------------------------------------------------
__global__ __launch_bounds__(256) void norms_kernel(const float* __restrict__ h,
                                                    float* __restrict__ norms,
                                                    int t_base) {
    int gw   = (int)((blockIdx.x * blockDim.x + threadIdx.x) >> 6);
    int lane = threadIdx.x & 63;
    int n    = gw & (NN - 1);
    int tloc = gw >> 11;
    const float4* row = (const float4*)(h + ((size_t)(t_base + tloc) * NN + n) * IND);
    float4 v = row[lane];
    float s = v.x * v.x + v.y * v.y + v.z * v.z + v.w * v.w;
#pragma unroll
    for (int off = 32; off > 0; off >>= 1) s += __shfl_xor(s, off);
    if (lane == 0) norms[(size_t)tloc * NN + n] = sqrtf(s);
}

// ---------------------------------------------------------------------------
// K2: input attention. 2 waves per (t,n); rows in VGPRs (keep-alive),
// scalar SGPR row bases. Output: bf16 hi/lo pair (feeds MFMA GEMM).
// min-waves/EU = 5 (VGPR cap 102; body needs ~95-100) for latency hiding.
// ---------------------------------------------------------------------------
__global__ __launch_bounds__(256, 5) void input_attn_kernel(const float* __restrict__ h,
                                                            const int* __restrict__ neigh,
                                                            const float* __restrict__ norms,
                                                            __hip_bfloat16* __restrict__ ihHi,
                                                            __hip_bfloat16* __restrict__ ihLo,
                                                            int t_base) {
    const int BR[32] = BITREV5_INIT;
    __shared__ float hd_s[2][2][32];
    int wave    = threadIdx.x >> 6;   // 0..3
    int nodeloc = wave >> 1;          // 0..1
    int half    = wave & 1;           // which 128-dim half
    int lane    = threadIdx.x & 63;
    int gw   = (int)((blockIdx.x << 1) | nodeloc);
    int n    = gw & (NN - 1);
    int tloc = gw >> 11;
    const float* hT  = h + (size_t)(t_base + tloc) * NN * IND;
    const float* nrm = norms + (size_t)tloc * NN;

    const float* dst = hT + (size_t)n * IND + half * 128;
    float d0 = dst[lane], d1 = dst[lane + 64];

    int   jreg = neigh[n * KN + (lane & 31)];
    float nj   = nrm[jreg];
    float ndst = nrm[n];

    float r0[32], r1[32], comb[16];
#pragma unroll
    for (int i = 0; i < 16; ++i) {
        int sja = __builtin_amdgcn_readlane(jreg, BR[i]);
        int sjb = __builtin_amdgcn_readlane(jreg, BR[i + 16]);
        const float* sa = hT + (size_t)sja * IND + half * 128;
        const float* sb = hT + (size_t)sjb * IND + half * 128;
        r0[i]      = sa[lane]; r1[i]      = sa[lane + 64];
        r0[i + 16] = sb[lane]; r1[i + 16] = sb[lane + 64];
        float pa = r0[i] * d0 + r1[i] * d1;
        float pb = r0[i + 16] * d0 + r1[i + 16] * d1;
        float send = (lane & 1) ? pa : pb;
        float keep = (lane & 1) ? pb : pa;
        comb[i] = keep + __shfl_xor(send, 1);
    }
#pragma unroll
    for (int i = 0; i < 32; ++i) asm volatile("" : "+v"(r0[i]), "+v"(r1[i]));
    float hdot = xpose_reduce16(comb, lane);   // half-dot of neighbor (lane&31)
    if (lane < 32) hd_s[nodeloc][half][lane] = hdot;
    __syncthreads();
    float dot = hdot + hd_s[nodeloc][half ^ 1][lane & 31];

    float r  = dot / (nj * ndst);
    float r2 = r * r;
    float e  = r2 * r2;

    float a0 = 0.f, a1 = 0.f;
#pragma unroll
    for (int i = 0; i < 32; ++i) {
        float ek = bcast_lane(e, BR[i]);
        a0 += ek * r0[i];
        a1 += ek * r1[i];
    }
    size_t base = (size_t)gw * IND + half * 128;
    __hip_bfloat16 hi, lo;
    bf16_split(a0, &hi, &lo);
    ihHi[base + lane] = hi;       ihLo[base + lane] = lo;
    bf16_split(a1, &hi, &lo);
    ihHi[base + lane + 64] = hi;  ihLo[base + lane + 64] = lo;
}

// ---------------------------------------------------------------------------
// MFMA GEMM, bf16x3 error-compensated split, LDS-staged (coalesced loads).
// A: [M][K] bf16 pairs. BT: [N][K] bf16 pairs. C: fp32.
// BM=BN=64, BK=32, 256 thr = 4 waves; wave w owns rows [w*16, w*16+16).
// LDS rows padded to 40 bf16 (80 B) -> 2-way bank aliasing (free).
// ---------------------------------------------------------------------------
__global__ __launch_bounds__(256) void gemm_bf16x3(const __hip_bfloat16* __restrict__ Ahi,
                                                   const __hip_bfloat16* __restrict__ Alo,
                                                   const __hip_bfloat16* __restrict__ BThi,
                                                   const __hip_bfloat16* __restrict__ BTlo,
                                                   float* __restrict__ C,
                                                   int M, int N, int K) {
    __shared__ short Ah[64][40], Al[64][40], Bh[64][40], Bl[64][40];
    int tid  = threadIdx.x;
    int lane = tid & 63;
    int w    = tid >> 6;
    int mb   = blockIdx.y * 64;
    int n0   = blockIdx.x * 64;
    int r    = lane & 15;        // row within fragment
    int g    = lane >> 4;        // k-group: k = g*8 .. g*8+7
    int lrow = tid >> 2;         // loader row 0..63
    int lseg = tid & 3;          // loader 16B segment 0..3

    const size_t aoff = (size_t)(mb + lrow) * K + lseg * 8;
    const size_t boff = (size_t)(n0 + lrow) * K + lseg * 8;

    f32x4v acc[4] = {};
    for (int k0 = 0; k0 < K; k0 += 32) {
        __syncthreads();
        *(bf16x8v*)&Ah[lrow][lseg * 8] = *(const bf16x8v*)(Ahi + aoff + k0);
        *(bf16x8v*)&Al[lrow][lseg * 8] = *(const bf16x8v*)(Alo + aoff + k0);
        *(bf16x8v*)&Bh[lrow][lseg * 8] = *(const bf16x8v*)(BThi + boff + k0);
        *(bf16x8v*)&Bl[lrow][lseg * 8] = *(const bf16x8v*)(BTlo + boff + k0);
        __syncthreads();
        bf16x8v ah = *(const bf16x8v*)&Ah[w * 16 + r][g * 8];
        bf16x8v al = *(const bf16x8v*)&Al[w * 16 + r][g * 8];
#pragma unroll
        for (int nt = 0; nt < 4; ++nt) {
            bf16x8v bh = *(const bf16x8v*)&Bh[nt * 16 + r][g * 8];
            bf16x8v bl = *(const bf16x8v*)&Bl[nt * 16 + r][g * 8];
            acc[nt] = __builtin_amdgcn_mfma_f32_16x16x32_bf16(ah, bh, acc[nt], 0, 0, 0);
            acc[nt] = __builtin_amdgcn_mfma_f32_16x16x32_bf16(ah, bl, acc[nt], 0, 0, 0);
            acc[nt] = __builtin_amdgcn_mfma_f32_16x16x32_bf16(al, bh, acc[nt], 0, 0, 0);
        }
    }
    // C/D layout: col = lane&15, row = (lane>>4)*4 + reg   [m89-verified]
#pragma unroll
    for (int nt = 0; nt < 4; ++nt)
#pragma unroll
        for (int q = 0; q < 4; ++q)
            C[(size_t)(mb + w * 16 + g * 4 + q) * N + n0 + nt * 16 + r] = acc[nt][q];
}

// ---------------------------------------------------------------------------
// K4: 3-head GAT + relu. One block (192 thr, wave=head) per (t,n).
// Output: bf16 hi/lo pair (feeds GEMM2). min-waves/EU = 5.
// ---------------------------------------------------------------------------
__global__ __launch_bounds__(192, 5) void gat_heads_kernel(const float* __restrict__ z1,
                                                           const int* __restrict__ neigh,
                                                           __hip_bfloat16* __restrict__ cHi,
                                                           __hip_bfloat16* __restrict__ cLo) {
    const int BR[32] = BITREV5_INIT;
    int n    = blockIdx.x & (NN - 1);
    const float* ztbl = z1 + (size_t)(blockIdx.x >> 11) * NN * C1D;
    int head = threadIdx.x >> 6;
    int lane = threadIdx.x & 63;

    const float* dst = ztbl + (size_t)n * C1D + head * H1D;
    float d0 = dst[lane], d1 = dst[lane + 64];
    int jreg = neigh[n * KN + (lane & 31)];

    float r0[32], r1[32], comb[16];
#pragma unroll
    for (int i = 0; i < 16; ++i) {
        int sja = __builtin_amdgcn_readlane(jreg, BR[i]);
        int sjb = __builtin_amdgcn_readlane(jreg, BR[i + 16]);
        const float* sa = ztbl + (size_t)sja * C1D + head * H1D;
        const float* sb = ztbl + (size_t)sjb * C1D + head * H1D;
        r0[i]      = sa[lane]; r1[i]      = sa[lane + 64];
        r0[i + 16] = sb[lane]; r1[i + 16] = sb[lane + 64];
        float pa = r0[i] * d0 + r1[i] * d1;
        float pb = r0[i + 16] * d0 + r1[i + 16] * d1;
        float send = (lane & 1) ? pa : pb;
        float keep = (lane & 1) ? pb : pa;
        comb[i] = keep + __shfl_xor(send, 1);
    }
#pragma unroll
    for (int i = 0; i < 32; ++i) asm volatile("" : "+v"(r0[i]), "+v"(r1[i]));
    float dot = xpose_reduce16(comb, lane);

    float m = dot;
#pragma unroll
    for (int off = 16; off > 0; off >>= 1) m = fmaxf(m, __shfl_xor(m, off));
    float p = __expf(dot - m);
    float s = p;
#pragma unroll
    for (int off = 16; off > 0; off >>= 1) s += __shfl_xor(s, off);
    p /= s;

    float a0 = 0.f, a1 = 0.f;
#pragma unroll
    for (int i = 0; i < 32; ++i) {
        float pk = bcast_lane(p, BR[i]);
        a0 += pk * r0[i];
        a1 += pk * r1[i];
    }
    size_t base = (size_t)blockIdx.x * C1D + (size_t)head * H1D;
    __hip_bfloat16 hi, lo;
    bf16_split(fmaxf(a0, 0.f), &hi, &lo);
    cHi[base + lane] = hi;       cLo[base + lane] = lo;
    bf16_split(fmaxf(a1, 0.f), &hi, &lo);
    cHi[base + lane + 64] = hi;  cLo[base + lane + 64] = lo;
}

// ---------------------------------------------------------------------------
// K7: final GAT on z2 (d=128) + relu + FUSED partial max-pool.
// One wave per (t,n); 4 nodes (same t) per block -> one 128-float partial.
// min-waves/EU = 5.
// ---------------------------------------------------------------------------
__global__ __launch_bounds__(256, 5) void gat_final_kernel(const float* __restrict__ z2,
                                                           const int* __restrict__ neigh,
                                                           float* __restrict__ ppart) {
    const int BR[32] = BITREV5_INIT;
    __shared__ float red_s[4][128];
    int wave = threadIdx.x >> 6;
    int gw   = (int)((blockIdx.x << 2) | wave);
    int n    = gw & (NN - 1);
    const float* ztbl = z2 + (size_t)(gw >> 11) * NN * H2D;
    int lane = threadIdx.x & 63;

    const float* dst = ztbl + (size_t)n * H2D;
    float d0 = dst[lane], d1 = dst[lane + 64];
    int jreg = neigh[n * KN + (lane & 31)];

    float r0[32], r1[32], comb[16];
#pragma unroll
    for (int i = 0; i < 16; ++i) {
        int sja = __builtin_amdgcn_readlane(jreg, BR[i]);
        int sjb = __builtin_amdgcn_readlane(jreg, BR[i + 16]);
        const float* sa = ztbl + (size_t)sja * H2D;
        const float* sb = ztbl + (size_t)sjb * H2D;
        r0[i]      = sa[lane]; r1[i]      = sa[lane + 64];
        r0[i + 16] = sb[lane]; r1[i + 16] = sb[lane + 64];
        float pa = r0[i] * d0 + r1[i] * d1;
        float pb = r0[i + 16] * d0 + r1[i + 16] * d1;
        float send = (lane & 1) ? pa : pb;
        float keep = (lane & 1) ? pb : pa;
        comb[i] = keep + __shfl_xor(send, 1);
    }
#pragma unroll
    for (int i = 0; i < 32; ++i) asm volatile("" : "+v"(r0[i]), "+v"(r1[i]));
    float dot = xpose_reduce16(comb, lane);

    float m = dot;
#pragma unroll
    for (int off = 16; off > 0; off >>= 1) m = fmaxf(m, __shfl_xor(m, off));
    float p = __expf(dot - m);
    float s = p;
#pragma unroll
    for (int off = 16; off > 0; off >>= 1) s += __shfl_xor(s, off);
    p /= s;

    float a0 = 0.f, a1 = 0.f;
#pragma unroll
    for (int i = 0; i < 32; ++i) {
        float pk = bcast_lane(p, BR[i]);
        a0 += pk * r0[i];
        a1 += pk * r1[i];
    }
    red_s[wave][lane]      = fmaxf(a0, 0.f);
    red_s[wave][lane + 64] = fmaxf(a1, 0.f);
    __syncthreads();
    int tid = threadIdx.x;
    if (tid < 128) {
        float mx = fmaxf(fmaxf(red_s[0][tid], red_s[1][tid]),
                         fmaxf(red_s[2][tid], red_s[3][tid]));
        ppart[(size_t)blockIdx.x * H2D + tid] = mx;
    }
}

// ---------------------------------------------------------------------------
// K8: pooled[t][j] = max over NN/4 = 512 block-partials
// ---------------------------------------------------------------------------
__global__ __launch_bounds__(128) void pool_reduce_kernel(const float* __restrict__ ppart,
                                                          float* __restrict__ pooled,
                                                          int t_base) {
    int j = threadIdx.x;
    const float* base = ppart + (size_t)blockIdx.x * 512 * H2D;
    float mx = 0.f;
#pragma unroll 8
    for (int q = 0; q < 512; ++q) mx = fmaxf(mx, base[(size_t)q * H2D + j]);
    pooled[(t_base + blockIdx.x) * H2D + j] = mx;
}

// ---------------------------------------------------------------------------
// prep: weights -> transposed bf16 hi/lo pairs; zero GRU counters.
// ---------------------------------------------------------------------------
__global__ void prep_kernel(const float* __restrict__ fc1, const float* __restrict__ fc2,
                            __hip_bfloat16* __restrict__ W1Thi, __hip_bfloat16* __restrict__ W1Tlo,
                            __hip_bfloat16* __restrict__ f2Thi, __hip_bfloat16* __restrict__ f2Tlo,
                            unsigned int* __restrict__ cnt) {
    int i = blockIdx.x * 256 + threadIdx.x;
    if (i < 384 * 256) {
        int cf = i / 256, d = i % 256;
        int hd = cf >> 7, j = cf & 127;
        float v = fc1[(size_t)hd * 256 * 128 + (size_t)d * 128 + j];
        __hip_bfloat16 hi, lo;
        bf16_split(v, &hi, &lo);
        W1Thi[i] = hi; W1Tlo[i] = lo;
    }
    if (i < 128 * 384) {
        int n = i / 384, k = i % 384;
        float v = fc2[(size_t)k * 128 + n];
        __hip_bfloat16 hi, lo;
        bf16_split(v, &hi, &lo);
        f2Thi[i] = hi; f2Tlo[i] = lo;
    }
    if (i < T_STEPS) cnt[i] = 0u;
}

// ---------------------------------------------------------------------------
// gi_all[t][o] = Wih[o,:] . pooled[t,:] + bih[o]   (parallel over t)
// ---------------------------------------------------------------------------
__global__ __launch_bounds__(256) void gi_all_kernel(const float* __restrict__ Wih,
                                                     const float* __restrict__ bih,
                                                     const float* __restrict__ pooled,
                                                     float* __restrict__ gi_all) {
    __shared__ float p_s[H2D];
    int t  = blockIdx.x / 3;
    int ob = (blockIdx.x % 3) * 256;
    if (threadIdx.x < H2D) p_s[threadIdx.x] = pooled[t * H2D + threadIdx.x];
    __syncthreads();
    int o = ob + threadIdx.x;
    float acc = bih[o];
    const float* wr = Wih + (size_t)o * H2D;
#pragma unroll 4
    for (int d = 0; d < H2D; ++d) acc += wr[d] * p_s[d];
    gi_all[t * 768 + o] = acc;
}

// ---------------------------------------------------------------------------
// GRU: 8 cooperating blocks, Whh register-resident.
// ---------------------------------------------------------------------------
__global__ __launch_bounds__(768) void gru_reg_kernel(const float* __restrict__ Whh,
                                                      const float* __restrict__ bhh,
                                                      const float* __restrict__ gi_all,
                                                      const float* __restrict__ hx0,
                                                      float* hx_all,
                                                      unsigned int* cnt) {
    __shared__ float4 hx_pad[72];                 // padded: idx (g,i) -> g*9+i
    __shared__ __align__(16) float hx_lin[GD];    // linear copy for hx_old
    __shared__ float gh_s[96];
    int b   = blockIdx.x;
    int tid = threadIdx.x;
    int row_local = tid >> 3;      // 0..95
    int sub       = tid & 7;       // 0..7
    int chunk     = row_local >> 5;
    int r_in      = row_local & 31;
    int grow      = chunk * GD + b * 32 + r_in;

    float4 wreg[8];
    const float4* wrow = (const float4*)(Whh + (size_t)grow * GD + sub * 32);
#pragma unroll
    for (int i = 0; i < 8; ++i) wreg[i] = wrow[i];
    float bias = (sub == 0) ? bhh[grow] : 0.f;

    for (int t = 0; t < T_STEPS; ++t) {
        if (t > 0) {
            if (tid == 0) {
                while (__hip_atomic_load(&cnt[t - 1], __ATOMIC_ACQUIRE,
                                         __HIP_MEMORY_SCOPE_AGENT) < GRU_NB)
                    __builtin_amdgcn_s_sleep(1);
            }
            __syncthreads();
        }
        const float* hsrc = (t == 0) ? hx0 : (hx_all + (size_t)(t - 1) * GD);
        if (tid < 64) {
            float4 v;
            v.x = __hip_atomic_load(hsrc + tid * 4 + 0, __ATOMIC_RELAXED, __HIP_MEMORY_SCOPE_AGENT);
            v.y = __hip_atomic_load(hsrc + tid * 4 + 1, __ATOMIC_RELAXED, __HIP_MEMORY_SCOPE_AGENT);
            v.z = __hip_atomic_load(hsrc + tid * 4 + 2, __ATOMIC_RELAXED, __HIP_MEMORY_SCOPE_AGENT);
            v.w = __hip_atomic_load(hsrc + tid * 4 + 3, __ATOMIC_RELAXED, __HIP_MEMORY_SCOPE_AGENT);
            hx_pad[(tid >> 3) * 9 + (tid & 7)] = v;
            ((float4*)hx_lin)[tid] = v;
        }
        __syncthreads();

        float acc = 0.f;
#pragma unroll
        for (int i = 0; i < 8; ++i) {
            float4 hv = hx_pad[sub * 9 + i];
            float4 wv = wreg[i];
            acc += wv.x * hv.x + wv.y * hv.y + wv.z * hv.z + wv.w * hv.w;
        }
        acc += __shfl_xor(acc, 1);
        acc += __shfl_xor(acc, 2);
        acc += __shfl_xor(acc, 4);
        if (sub == 0) gh_s[row_local] = acc + bias;
        __syncthreads();

        if (tid < 32) {
            int u = b * 32 + tid;
            float gi_r = gi_all[t * 768 + u];
            float gi_z = gi_all[t * 768 + 256 + u];
            float gi_n = gi_all[t * 768 + 512 + u];
            float r  = 1.f / (1.f + expf(-(gi_r + gh_s[tid])));
            float zg = 1.f / (1.f + expf(-(gi_z + gh_s[32 + tid])));
            float nn = tanhf(gi_n + r * gh_s[64 + tid]);
            float hnew = (1.f - zg) * nn + zg * hx_lin[u];
            __hip_atomic_store(&hx_all[(size_t)t * GD + u], hnew,
                               __ATOMIC_RELAXED, __HIP_MEMORY_SCOPE_AGENT);
        }
        __syncthreads();
        if (tid == 0)
            __hip_atomic_fetch_add(&cnt[t], 1u, __ATOMIC_RELEASE,
                                   __HIP_MEMORY_SCOPE_AGENT);
    }
}

// ---------------------------------------------------------------------------
// res heads + SIR scan. One block per t.
// ---------------------------------------------------------------------------
__global__ __launch_bounds__(128) void res_sir_kernel(const float* __restrict__ hx_all,
                                                      const float* __restrict__ It,
                                                      const float* __restrict__ Rt,
                                                      const float* __restrict__ r1W,
                                                      const float* __restrict__ r1b,
                                                      const float* __restrict__ r2W,
                                                      const float* __restrict__ r2b,
                                                      const float* __restrict__ I,
                                                      const float* __restrict__ R,
                                                      const float* __restrict__ S,
                                                      const float* __restrict__ Npop,
                                                      float* __restrict__ out) {
    __shared__ float nhx[258];
    __shared__ float ab_s[2];
    int t = blockIdx.x, tid = threadIdx.x;
    for (int i = tid; i < GD; i += 128) nhx[i] = hx_all[t * GD + i];
    if (tid == 0) { nhx[256] = It[t]; nhx[257] = Rt[t]; }
    __syncthreads();
    if (tid < 120) {
        float acc = r1b[tid];
        const float* wr = r1W + tid * 258;
        for (int d = 0; d < 258; ++d) acc += wr[d] * nhx[d];
        int idx = t * 60 + (tid >> 1);
        if (tid & 1) out[3840 + idx] = acc;
        else         out[idx] = acc;
    }
    if (tid == 120 || tid == 121) {
        int q = tid - 120;
        float acc = r2b[q];
        const float* wr = r2W + q * 258;
        for (int d = 0; d < 258; ++d) acc += wr[d] * nhx[d];
        ab_s[q] = acc;
    }
    __syncthreads();
    if (tid == 0) {
        float a_s = 1.f / (1.f + expf(-ab_s[0]));
        float b_s = 1.f / (1.f + expf(-ab_s[1]));
        float Np = Npop[0];
        float lI = I[t], lR = R[t], lS = S[t];
        for (int p = 0; p < PD; ++p) {
            float dI = a_s * lI * (lS / Np) - b_s * lI;
            float dR = b_s * lI;
            lI += dI;
            lR += dR;
            lS = Np - lI - lR;
            out[7680  + t * 60 + p] = dI;
            out[11520 + t * 60 + p] = dR;
        }
    }
}

// ---------------------------------------------------------------------------
extern "C" void kernel_launch(void* const* d_in, const int* in_sizes, int n_in,
                              void* d_out, int out_size, void* d_ws, size_t ws_size,
                              hipStream_t stream) {
    const float* h    = (const float*)d_in[0];
    const int*   ng   = (const int*)  d_in[1];
    const float* Npop = (const float*)d_in[2];
    const float* I_   = (const float*)d_in[3];
    const float* R_   = (const float*)d_in[4];
    const float* S_   = (const float*)d_in[5];
    const float* It   = (const float*)d_in[6];
    const float* Rt   = (const float*)d_in[7];
    const float* fc1  = (const float*)d_in[8];
    const float* fc2  = (const float*)d_in[9];
    const float* gWih = (const float*)d_in[10];
    const float* gWhh = (const float*)d_in[11];
    const float* gbih = (const float*)d_in[12];
    const float* gbhh = (const float*)d_in[13];
    const float* r1W  = (const float*)d_in[14];
    const float* r1b  = (const float*)d_in[15];
    const float* r2W  = (const float*)d_in[16];
    const float* r2b  = (const float*)d_in[17];
    const float* hx0  = (const float*)d_in[18];
    float* out = (float*)d_out;

    // ---- workspace carve-up (all region sizes 16B-aligned) ----
    char* w = (char*)d_ws;
    float* pooled = (float*)w; w += (size_t)T_STEPS * H2D * 4;      // 32 KB
    float* hx_all = (float*)w; w += (size_t)T_STEPS * GD * 4;       // 64 KB
    float* gi_all = (float*)w; w += (size_t)T_STEPS * 768 * 4;      // 192 KB
    float* ppart  = (float*)w; w += (size_t)16 * 512 * H2D * 4;     // 4 MB (Tc<=16)
    __hip_bfloat16* W1Thi = (__hip_bfloat16*)w; w += (size_t)384 * 256 * 2; // 192 KB
    __hip_bfloat16* W1Tlo = (__hip_bfloat16*)w; w += (size_t)384 * 256 * 2;
    __hip_bfloat16* f2Thi = (__hip_bfloat16*)w; w += (size_t)128 * 384 * 2; // 96 KB
    __hip_bfloat16* f2Tlo = (__hip_bfloat16*)w; w += (size_t)128 * 384 * 2;
    unsigned int* cnt = (unsigned int*)w; w += 256;                 // 64 ctr + pad
    size_t fixed = (size_t)(w - (char*)d_ws);

    // per-Tc bytes: norms 8KB + pairA 2MB (ihHi/ihLo; later z2) +
    //               z1 3MB + pairC 3MB (cHi/cLo)
    const size_t perTc = 8192 + 2097152 + 3145728 + 3145728;
    int Tc = 16;
    while (Tc > 1) {
        if (fixed + (size_t)Tc * perTc <= ws_size) break;
        Tc >>= 1;
    }
    float* norms = (float*)w;             w += (size_t)Tc * NN * 4;
    char*  pairA = w;                     w += (size_t)Tc * NN * 256 * 2 * 2;
    float* z1    = (float*)w;             w += (size_t)Tc * NN * C1D * 4;
    __hip_bfloat16* cHi = (__hip_bfloat16*)w; w += (size_t)Tc * NN * C1D * 2;
    __hip_bfloat16* cLo = (__hip_bfloat16*)w;

    __hip_bfloat16* ihHi = (__hip_bfloat16*)pairA;
    __hip_bfloat16* ihLo = ihHi + (size_t)Tc * NN * 256;
    // z2 overlays pairA after GEMM1 consumed ihHi/ihLo
    float* z2 = (float*)pairA;

    prep_kernel<<<(384 * 256 + 255) / 256, 256, 0, stream>>>(fc1, fc2, W1Thi, W1Tlo,
                                                             f2Thi, f2Tlo, cnt);

    for (int t0 = 0; t0 < T_STEPS; t0 += Tc) {
        int M = Tc * NN;
        norms_kernel      <<<Tc * NN / 4, 256, 0, stream>>>(h, norms, t0);
        input_attn_kernel <<<Tc * NN / 2, 256, 0, stream>>>(h, ng, norms, ihHi, ihLo, t0);
        // z1 = ih @ W1  (M x 256) @ (256 x 384), bf16x3 MFMA, LDS-staged
        gemm_bf16x3<<<dim3(384 / 64, M / 64), 256, 0, stream>>>(ihHi, ihLo, W1Thi, W1Tlo,
                                                                z1, M, 384, 256);
        gat_heads_kernel  <<<Tc * NN, 192, 0, stream>>>(z1, ng, cHi, cLo);
        // z2 = c @ fc2  (M x 384) @ (384 x 128), bf16x3 MFMA, LDS-staged
        gemm_bf16x3<<<dim3(128 / 64, M / 64), 256, 0, stream>>>(cHi, cLo, f2Thi, f2Tlo,
                                                                z2, M, 128, 384);
        gat_final_kernel  <<<Tc * NN / 4, 256, 0, stream>>>(z2, ng, ppart);
        pool_reduce_kernel<<<Tc, 128, 0, stream>>>(ppart, pooled, t0);
    }

    gi_all_kernel<<<T_STEPS * 3, 256, 0, stream>>>(gWih, gbih, pooled, gi_all);
    gru_reg_kernel<<<GRU_NB, 768, 0, stream>>>(gWhh, gbhh, gi_all, hx0, hx_all, cnt);
    res_sir_kernel<<<T_STEPS, 128, 0, stream>>>(hx_all, It, Rt, r1W, r1b, r2W, r2b,
                                                I_, R_, S_, Npop, out);
}

// Round 15
// 1528.146 us; speedup vs baseline: 1.1630x; 1.0093x over previous
//
#include <hip/hip_runtime.h>
#include <hip/hip_bf16.h>
#include <math.h>

// Problem constants
#define T_STEPS 64
#define NN      2048
#define KN      32
#define IND     256
#define H1D     128
#define C1D     384   // HEADS*H1
#define H2D     128
#define GD      256
#define PD      60
#define GRU_NB  8     // cooperating blocks for the GRU

typedef __attribute__((ext_vector_type(8))) short bf16x8v;  // 8 bf16 = 4 VGPR
typedef __attribute__((ext_vector_type(4))) float f32x4v;

// bit-reversed 5-bit order (involution)
#define BITREV5_INIT {0,16,8,24,4,20,12,28,2,18,10,26,6,22,14,30, \
                      1,17,9,25,5,21,13,29,3,19,11,27,7,23,15,31}

__device__ __forceinline__ float bcast_lane(float v, int lane_imm) {
    return __uint_as_float(__builtin_amdgcn_readlane(__float_as_uint(v), lane_imm));
}

__device__ __forceinline__ void bf16_split(float v, __hip_bfloat16* hi, __hip_bfloat16* lo) {
    __hip_bfloat16 h = __float2bfloat16(v);
    *hi = h;
    *lo = __float2bfloat16(v - __bfloat162float(h));
}

// Butterfly stages 2..6 on 16 stage-1-combined partials.
__device__ __forceinline__ float xpose_reduce16(float part[16], int lane) {
#pragma unroll
    for (int i = 0; i < 8; ++i) {
        float send = (lane & 2) ? part[i] : part[i + 8];
        float keep = (lane & 2) ? part[i + 8] : part[i];
        part[i] = keep + __shfl_xor(send, 2);
    }
#pragma unroll
    for (int i = 0; i < 4; ++i) {
        float send = (lane & 4) ? part[i] : part[i + 4];
        float keep = (lane & 4) ? part[i + 4] : part[i];
        part[i] = keep + __shfl_xor(send, 4);
    }
#pragma unroll
    for (int i = 0; i < 2; ++i) {
        float send = (lane & 8) ? part[i] : part[i + 2];
        float keep = (lane & 8) ? part[i + 2] : part[i];
        part[i] = keep + __shfl_xor(send, 8);
    }
    {
        float send = (lane & 16) ? part[0] : part[1];
        float keep = (lane & 16) ? part[1] : part[0];
        part[0] = keep + __shfl_xor(send, 16);
    }
    return part[0] + __shfl_xor(part[0], 32);
}

// ---------------------------------------------------------------------------
// K1: row norms of h[t]  (one wave per node, single float4 load)
// ---------------------------------------------------------------------------
__global__ __launch_bounds__(256) void norms_kernel(const float* __restrict__ h,
                                                    float* __restrict__ norms,
                                                    int t_base) {
    int gw   = (int)((blockIdx.x * blockDim.x + threadIdx.x) >> 6);
    int lane = threadIdx.x & 63;
    int n    = gw & (NN - 1);
    int tloc = gw >> 11;
    const float4* row = (const float4*)(h + ((size_t)(t_base + tloc) * NN + n) * IND);
    float4 v = row[lane];
    float s = v.x * v.x + v.y * v.y + v.z * v.z + v.w * v.w;
#pragma unroll
    for (int off = 32; off > 0; off >>= 1) s += __shfl_xor(s, off);
    if (lane == 0) norms[(size_t)tloc * NN + n] = sqrtf(s);
}

// ---------------------------------------------------------------------------
// K2: input attention. 2 waves per (t,n); rows in VGPRs (keep-alive),
// scalar SGPR row bases. Output: bf16 hi/lo pair (feeds MFMA GEMM).
// ---------------------------------------------------------------------------
__global__ __launch_bounds__(256, 5) void input_attn_kernel(const float* __restrict__ h,
                                                            const int* __restrict__ neigh,
                                                            const float* __restrict__ norms,
                                                            __hip_bfloat16* __restrict__ ihHi,
                                                            __hip_bfloat16* __restrict__ ihLo,
                                                            int t_base) {
    const int BR[32] = BITREV5_INIT;
    __shared__ float hd_s[2][2][32];
    int wave    = threadIdx.x >> 6;   // 0..3
    int nodeloc = wave >> 1;          // 0..1
    int half    = wave & 1;           // which 128-dim half
    int lane    = threadIdx.x & 63;
    int gw   = (int)((blockIdx.x << 1) | nodeloc);
    int n    = gw & (NN - 1);
    int tloc = gw >> 11;
    const float* hT  = h + (size_t)(t_base + tloc) * NN * IND;
    const float* nrm = norms + (size_t)tloc * NN;

    const float* dst = hT + (size_t)n * IND + half * 128;
    float d0 = dst[lane], d1 = dst[lane + 64];

    int   jreg = neigh[n * KN + (lane & 31)];
    float nj   = nrm[jreg];
    float ndst = nrm[n];

    float r0[32], r1[32], comb[16];
#pragma unroll
    for (int i = 0; i < 16; ++i) {
        int sja = __builtin_amdgcn_readlane(jreg, BR[i]);
        int sjb = __builtin_amdgcn_readlane(jreg, BR[i + 16]);
        const float* sa = hT + (size_t)sja * IND + half * 128;
        const float* sb = hT + (size_t)sjb * IND + half * 128;
        r0[i]      = sa[lane]; r1[i]      = sa[lane + 64];
        r0[i + 16] = sb[lane]; r1[i + 16] = sb[lane + 64];
        float pa = r0[i] * d0 + r1[i] * d1;
        float pb = r0[i + 16] * d0 + r1[i + 16] * d1;
        float send = (lane & 1) ? pa : pb;
        float keep = (lane & 1) ? pb : pa;
        comb[i] = keep + __shfl_xor(send, 1);
    }
#pragma unroll
    for (int i = 0; i < 32; ++i) asm volatile("" : "+v"(r0[i]), "+v"(r1[i]));
    float hdot = xpose_reduce16(comb, lane);   // half-dot of neighbor (lane&31)
    if (lane < 32) hd_s[nodeloc][half][lane] = hdot;
    __syncthreads();
    float dot = hdot + hd_s[nodeloc][half ^ 1][lane & 31];

    float r  = dot / (nj * ndst);
    float r2 = r * r;
    float e  = r2 * r2;

    float a0 = 0.f, a1 = 0.f;
#pragma unroll
    for (int i = 0; i < 32; ++i) {
        float ek = bcast_lane(e, BR[i]);
        a0 += ek * r0[i];
        a1 += ek * r1[i];
    }
    size_t base = (size_t)gw * IND + half * 128;
    __hip_bfloat16 hi, lo;
    bf16_split(a0, &hi, &lo);
    ihHi[base + lane] = hi;       ihLo[base + lane] = lo;
    bf16_split(a1, &hi, &lo);
    ihHi[base + lane + 64] = hi;  ihLo[base + lane + 64] = lo;
}

// ---------------------------------------------------------------------------
// MFMA GEMM, bf16x3 error-compensated split, LDS-staged (coalesced loads).
// ---------------------------------------------------------------------------
__global__ __launch_bounds__(256) void gemm_bf16x3(const __hip_bfloat16* __restrict__ Ahi,
                                                   const __hip_bfloat16* __restrict__ Alo,
                                                   const __hip_bfloat16* __restrict__ BThi,
                                                   const __hip_bfloat16* __restrict__ BTlo,
                                                   float* __restrict__ C,
                                                   int M, int N, int K) {
    __shared__ short Ah[64][40], Al[64][40], Bh[64][40], Bl[64][40];
    int tid  = threadIdx.x;
    int lane = tid & 63;
    int w    = tid >> 6;
    int mb   = blockIdx.y * 64;
    int n0   = blockIdx.x * 64;
    int r    = lane & 15;        // row within fragment
    int g    = lane >> 4;        // k-group: k = g*8 .. g*8+7
    int lrow = tid >> 2;         // loader row 0..63
    int lseg = tid & 3;          // loader 16B segment 0..3

    const size_t aoff = (size_t)(mb + lrow) * K + lseg * 8;
    const size_t boff = (size_t)(n0 + lrow) * K + lseg * 8;

    f32x4v acc[4] = {};
    for (int k0 = 0; k0 < K; k0 += 32) {
        __syncthreads();
        *(bf16x8v*)&Ah[lrow][lseg * 8] = *(const bf16x8v*)(Ahi + aoff + k0);
        *(bf16x8v*)&Al[lrow][lseg * 8] = *(const bf16x8v*)(Alo + aoff + k0);
        *(bf16x8v*)&Bh[lrow][lseg * 8] = *(const bf16x8v*)(BThi + boff + k0);
        *(bf16x8v*)&Bl[lrow][lseg * 8] = *(const bf16x8v*)(BTlo + boff + k0);
        __syncthreads();
        bf16x8v ah = *(const bf16x8v*)&Ah[w * 16 + r][g * 8];
        bf16x8v al = *(const bf16x8v*)&Al[w * 16 + r][g * 8];
#pragma unroll
        for (int nt = 0; nt < 4; ++nt) {
            bf16x8v bh = *(const bf16x8v*)&Bh[nt * 16 + r][g * 8];
            bf16x8v bl = *(const bf16x8v*)&Bl[nt * 16 + r][g * 8];
            acc[nt] = __builtin_amdgcn_mfma_f32_16x16x32_bf16(ah, bh, acc[nt], 0, 0, 0);
            acc[nt] = __builtin_amdgcn_mfma_f32_16x16x32_bf16(ah, bl, acc[nt], 0, 0, 0);
            acc[nt] = __builtin_amdgcn_mfma_f32_16x16x32_bf16(al, bh, acc[nt], 0, 0, 0);
        }
    }
#pragma unroll
    for (int nt = 0; nt < 4; ++nt)
#pragma unroll
        for (int q = 0; q < 4; ++q)
            C[(size_t)(mb + w * 16 + g * 4 + q) * N + n0 + nt * 16 + r] = acc[nt][q];
}

// ---------------------------------------------------------------------------
// K4: 3-head GAT + relu. One block (192 thr, wave=head) per (t,n).
// ---------------------------------------------------------------------------
__global__ __launch_bounds__(192, 5) void gat_heads_kernel(const float* __restrict__ z1,
                                                           const int* __restrict__ neigh,
                                                           __hip_bfloat16* __restrict__ cHi,
                                                           __hip_bfloat16* __restrict__ cLo) {
    const int BR[32] = BITREV5_INIT;
    int n    = blockIdx.x & (NN - 1);
    const float* ztbl = z1 + (size_t)(blockIdx.x >> 11) * NN * C1D;
    int head = threadIdx.x >> 6;
    int lane = threadIdx.x & 63;

    const float* dst = ztbl + (size_t)n * C1D + head * H1D;
    float d0 = dst[lane], d1 = dst[lane + 64];
    int jreg = neigh[n * KN + (lane & 31)];

    float r0[32], r1[32], comb[16];
#pragma unroll
    for (int i = 0; i < 16; ++i) {
        int sja = __builtin_amdgcn_readlane(jreg, BR[i]);
        int sjb = __builtin_amdgcn_readlane(jreg, BR[i + 16]);
        const float* sa = ztbl + (size_t)sja * C1D + head * H1D;
        const float* sb = ztbl + (size_t)sjb * C1D + head * H1D;
        r0[i]      = sa[lane]; r1[i]      = sa[lane + 64];
        r0[i + 16] = sb[lane]; r1[i + 16] = sb[lane + 64];
        float pa = r0[i] * d0 + r1[i] * d1;
        float pb = r0[i + 16] * d0 + r1[i + 16] * d1;
        float send = (lane & 1) ? pa : pb;
        float keep = (lane & 1) ? pb : pa;
        comb[i] = keep + __shfl_xor(send, 1);
    }
#pragma unroll
    for (int i = 0; i < 32; ++i) asm volatile("" : "+v"(r0[i]), "+v"(r1[i]));
    float dot = xpose_reduce16(comb, lane);

    float m = dot;
#pragma unroll
    for (int off = 16; off > 0; off >>= 1) m = fmaxf(m, __shfl_xor(m, off));
    float p = __expf(dot - m);
    float s = p;
#pragma unroll
    for (int off = 16; off > 0; off >>= 1) s += __shfl_xor(s, off);
    p /= s;

    float a0 = 0.f, a1 = 0.f;
#pragma unroll
    for (int i = 0; i < 32; ++i) {
        float pk = bcast_lane(p, BR[i]);
        a0 += pk * r0[i];
        a1 += pk * r1[i];
    }
    size_t base = (size_t)blockIdx.x * C1D + (size_t)head * H1D;
    __hip_bfloat16 hi, lo;
    bf16_split(fmaxf(a0, 0.f), &hi, &lo);
    cHi[base + lane] = hi;       cLo[base + lane] = lo;
    bf16_split(fmaxf(a1, 0.f), &hi, &lo);
    cHi[base + lane + 64] = hi;  cLo[base + lane + 64] = lo;
}

// ---------------------------------------------------------------------------
// K7: final GAT on z2 (d=128) + relu + FUSED partial max-pool.
// ---------------------------------------------------------------------------
__global__ __launch_bounds__(256, 5) void gat_final_kernel(const float* __restrict__ z2,
                                                           const int* __restrict__ neigh,
                                                           float* __restrict__ ppart) {
    const int BR[32] = BITREV5_INIT;
    __shared__ float red_s[4][128];
    int wave = threadIdx.x >> 6;
    int gw   = (int)((blockIdx.x << 2) | wave);
    int n    = gw & (NN - 1);
    const float* ztbl = z2 + (size_t)(gw >> 11) * NN * H2D;
    int lane = threadIdx.x & 63;

    const float* dst = ztbl + (size_t)n * H2D;
    float d0 = dst[lane], d1 = dst[lane + 64];
    int jreg = neigh[n * KN + (lane & 31)];

    float r0[32], r1[32], comb[16];
#pragma unroll
    for (int i = 0; i < 16; ++i) {
        int sja = __builtin_amdgcn_readlane(jreg, BR[i]);
        int sjb = __builtin_amdgcn_readlane(jreg, BR[i + 16]);
        const float* sa = ztbl + (size_t)sja * H2D;
        const float* sb = ztbl + (size_t)sjb * H2D;
        r0[i]      = sa[lane]; r1[i]      = sa[lane + 64];
        r0[i + 16] = sb[lane]; r1[i + 16] = sb[lane + 64];
        float pa = r0[i] * d0 + r1[i] * d1;
        float pb = r0[i + 16] * d0 + r1[i + 16] * d1;
        float send = (lane & 1) ? pa : pb;
        float keep = (lane & 1) ? pb : pa;
        comb[i] = keep + __shfl_xor(send, 1);
    }
#pragma unroll
    for (int i = 0; i < 32; ++i) asm volatile("" : "+v"(r0[i]), "+v"(r1[i]));
    float dot = xpose_reduce16(comb, lane);

    float m = dot;
#pragma unroll
    for (int off = 16; off > 0; off >>= 1) m = fmaxf(m, __shfl_xor(m, off));
    float p = __expf(dot - m);
    float s = p;
#pragma unroll
    for (int off = 16; off > 0; off >>= 1) s += __shfl_xor(s, off);
    p /= s;

    float a0 = 0.f, a1 = 0.f;
#pragma unroll
    for (int i = 0; i < 32; ++i) {
        float pk = bcast_lane(p, BR[i]);
        a0 += pk * r0[i];
        a1 += pk * r1[i];
    }
    red_s[wave][lane]      = fmaxf(a0, 0.f);
    red_s[wave][lane + 64] = fmaxf(a1, 0.f);
    __syncthreads();
    int tid = threadIdx.x;
    if (tid < 128) {
        float mx = fmaxf(fmaxf(red_s[0][tid], red_s[1][tid]),
                         fmaxf(red_s[2][tid], red_s[3][tid]));
        ppart[(size_t)blockIdx.x * H2D + tid] = mx;
    }
}

// ---------------------------------------------------------------------------
// K8: pooled[t][j] = max over NN/4 = 512 block-partials
// ---------------------------------------------------------------------------
__global__ __launch_bounds__(128) void pool_reduce_kernel(const float* __restrict__ ppart,
                                                          float* __restrict__ pooled,
                                                          int t_base) {
    int j = threadIdx.x;
    const float* base = ppart + (size_t)blockIdx.x * 512 * H2D;
    float mx = 0.f;
#pragma unroll 8
    for (int q = 0; q < 512; ++q) mx = fmaxf(mx, base[(size_t)q * H2D + j]);
    pooled[(t_base + blockIdx.x) * H2D + j] = mx;
}

// ---------------------------------------------------------------------------
// prep: weights -> transposed bf16 hi/lo pairs; zero GRU step flags.
// ---------------------------------------------------------------------------
__global__ void prep_kernel(const float* __restrict__ fc1, const float* __restrict__ fc2,
                            __hip_bfloat16* __restrict__ W1Thi, __hip_bfloat16* __restrict__ W1Tlo,
                            __hip_bfloat16* __restrict__ f2Thi, __hip_bfloat16* __restrict__ f2Tlo,
                            unsigned int* __restrict__ flags) {
    int i = blockIdx.x * 256 + threadIdx.x;
    if (i < 384 * 256) {
        int cf = i / 256, d = i % 256;
        int hd = cf >> 7, j = cf & 127;
        float v = fc1[(size_t)hd * 256 * 128 + (size_t)d * 128 + j];
        __hip_bfloat16 hi, lo;
        bf16_split(v, &hi, &lo);
        W1Thi[i] = hi; W1Tlo[i] = lo;
    }
    if (i < 128 * 384) {
        int n = i / 384, k = i % 384;
        float v = fc2[(size_t)k * 128 + n];
        __hip_bfloat16 hi, lo;
        bf16_split(v, &hi, &lo);
        f2Thi[i] = hi; f2Tlo[i] = lo;
    }
    if (i < T_STEPS * GRU_NB) flags[i] = 0u;
}

// ---------------------------------------------------------------------------
// gi_all[t][o] = Wih[o,:] . pooled[t,:] + bih[o]   (parallel over t)
// ---------------------------------------------------------------------------
__global__ __launch_bounds__(256) void gi_all_kernel(const float* __restrict__ Wih,
                                                     const float* __restrict__ bih,
                                                     const float* __restrict__ pooled,
                                                     float* __restrict__ gi_all) {
    __shared__ float p_s[H2D];
    int t  = blockIdx.x / 3;
    int ob = (blockIdx.x % 3) * 256;
    if (threadIdx.x < H2D) p_s[threadIdx.x] = pooled[t * H2D + threadIdx.x];
    __syncthreads();
    int o = ob + threadIdx.x;
    float acc = bih[o];
    const float* wr = Wih + (size_t)o * H2D;
#pragma unroll 4
    for (int d = 0; d < H2D; ++d) acc += wr[d] * p_s[d];
    gi_all[t * 768 + o] = acc;
}

// ---------------------------------------------------------------------------
// GRU: 8 cooperating blocks, Whh register-resident.
// Sync via PER-BLOCK flags (no shared-counter RMW serialization):
// writer does release-store flags[t*8+b]=1; waiters' lanes 0..7 poll all 8
// flags of step t-1 in parallel. gi loads hoisted above the poll so their
// latency hides under the spin.
// ---------------------------------------------------------------------------
__global__ __launch_bounds__(768) void gru_reg_kernel(const float* __restrict__ Whh,
                                                      const float* __restrict__ bhh,
                                                      const float* __restrict__ gi_all,
                                                      const float* __restrict__ hx0,
                                                      float* hx_all,
                                                      unsigned int* flags) {
    __shared__ float4 hx_pad[72];                 // padded: idx (g,i) -> g*9+i
    __shared__ __align__(16) float hx_lin[GD];    // linear copy for hx_old
    __shared__ float gh_s[96];
    int b   = blockIdx.x;
    int tid = threadIdx.x;
    int row_local = tid >> 3;      // 0..95
    int sub       = tid & 7;       // 0..7
    int chunk     = row_local >> 5;
    int r_in      = row_local & 31;
    int grow      = chunk * GD + b * 32 + r_in;

    float4 wreg[8];
    const float4* wrow = (const float4*)(Whh + (size_t)grow * GD + sub * 32);
#pragma unroll
    for (int i = 0; i < 8; ++i) wreg[i] = wrow[i];
    float bias = (sub == 0) ? bhh[grow] : 0.f;
    int u = b * 32 + tid;          // hidden unit owned by tid<32

    for (int t = 0; t < T_STEPS; ++t) {
        // prefetch gi for this step (independent of hx) before the wait
        float gi_r = 0.f, gi_z = 0.f, gi_n = 0.f;
        if (tid < 32) {
            gi_r = gi_all[t * 768 + u];
            gi_z = gi_all[t * 768 + 256 + u];
            gi_n = gi_all[t * 768 + 512 + u];
        }
        if (t > 0) {
            if (tid < GRU_NB) {
                while (__hip_atomic_load(&flags[(t - 1) * GRU_NB + tid],
                                         __ATOMIC_ACQUIRE,
                                         __HIP_MEMORY_SCOPE_AGENT) == 0u)
                    __builtin_amdgcn_s_sleep(1);
            }
            __syncthreads();
        }
        const float* hsrc = (t == 0) ? hx0 : (hx_all + (size_t)(t - 1) * GD);
        if (tid < 64) {
            float4 v;
            v.x = __hip_atomic_load(hsrc + tid * 4 + 0, __ATOMIC_RELAXED, __HIP_MEMORY_SCOPE_AGENT);
            v.y = __hip_atomic_load(hsrc + tid * 4 + 1, __ATOMIC_RELAXED, __HIP_MEMORY_SCOPE_AGENT);
            v.z = __hip_atomic_load(hsrc + tid * 4 + 2, __ATOMIC_RELAXED, __HIP_MEMORY_SCOPE_AGENT);
            v.w = __hip_atomic_load(hsrc + tid * 4 + 3, __ATOMIC_RELAXED, __HIP_MEMORY_SCOPE_AGENT);
            hx_pad[(tid >> 3) * 9 + (tid & 7)] = v;
            ((float4*)hx_lin)[tid] = v;
        }
        __syncthreads();

        float acc = 0.f;
#pragma unroll
        for (int i = 0; i < 8; ++i) {
            float4 hv = hx_pad[sub * 9 + i];
            float4 wv = wreg[i];
            acc += wv.x * hv.x + wv.y * hv.y + wv.z * hv.z + wv.w * hv.w;
        }
        acc += __shfl_xor(acc, 1);
        acc += __shfl_xor(acc, 2);
        acc += __shfl_xor(acc, 4);
        if (sub == 0) gh_s[row_local] = acc + bias;
        __syncthreads();

        if (tid < 32) {
            float r  = 1.f / (1.f + expf(-(gi_r + gh_s[tid])));
            float zg = 1.f / (1.f + expf(-(gi_z + gh_s[32 + tid])));
            float nn = tanhf(gi_n + r * gh_s[64 + tid]);
            float hnew = (1.f - zg) * nn + zg * hx_lin[u];
            __hip_atomic_store(&hx_all[(size_t)t * GD + u], hnew,
                               __ATOMIC_RELAXED, __HIP_MEMORY_SCOPE_AGENT);
        }
        __syncthreads();
        if (tid == 0)
            __hip_atomic_store(&flags[t * GRU_NB + b], 1u,
                               __ATOMIC_RELEASE, __HIP_MEMORY_SCOPE_AGENT);
    }
}

// ---------------------------------------------------------------------------
// res heads + SIR scan. One block per t.
// ---------------------------------------------------------------------------
__global__ __launch_bounds__(128) void res_sir_kernel(const float* __restrict__ hx_all,
                                                      const float* __restrict__ It,
                                                      const float* __restrict__ Rt,
                                                      const float* __restrict__ r1W,
                                                      const float* __restrict__ r1b,
                                                      const float* __restrict__ r2W,
                                                      const float* __restrict__ r2b,
                                                      const float* __restrict__ I,
                                                      const float* __restrict__ R,
                                                      const float* __restrict__ S,
                                                      const float* __restrict__ Npop,
                                                      float* __restrict__ out) {
    __shared__ float nhx[258];
    __shared__ float ab_s[2];
    int t = blockIdx.x, tid = threadIdx.x;
    for (int i = tid; i < GD; i += 128) nhx[i] = hx_all[t * GD + i];
    if (tid == 0) { nhx[256] = It[t]; nhx[257] = Rt[t]; }
    __syncthreads();
    if (tid < 120) {
        float acc = r1b[tid];
        const float* wr = r1W + tid * 258;
        for (int d = 0; d < 258; ++d) acc += wr[d] * nhx[d];
        int idx = t * 60 + (tid >> 1);
        if (tid & 1) out[3840 + idx] = acc;
        else         out[idx] = acc;
    }
    if (tid == 120 || tid == 121) {
        int q = tid - 120;
        float acc = r2b[q];
        const float* wr = r2W + q * 258;
        for (int d = 0; d < 258; ++d) acc += wr[d] * nhx[d];
        ab_s[q] = acc;
    }
    __syncthreads();
    if (tid == 0) {
        float a_s = 1.f / (1.f + expf(-ab_s[0]));
        float b_s = 1.f / (1.f + expf(-ab_s[1]));
        float Np = Npop[0];
        float lI = I[t], lR = R[t], lS = S[t];
        for (int p = 0; p < PD; ++p) {
            float dI = a_s * lI * (lS / Np) - b_s * lI;
            float dR = b_s * lI;
            lI += dI;
            lR += dR;
            lS = Np - lI - lR;
            out[7680  + t * 60 + p] = dI;
            out[11520 + t * 60 + p] = dR;
        }
    }
}

// ---------------------------------------------------------------------------
extern "C" void kernel_launch(void* const* d_in, const int* in_sizes, int n_in,
                              void* d_out, int out_size, void* d_ws, size_t ws_size,
                              hipStream_t stream) {
    const float* h    = (const float*)d_in[0];
    const int*   ng   = (const int*)  d_in[1];
    const float* Npop = (const float*)d_in[2];
    const float* I_   = (const float*)d_in[3];
    const float* R_   = (const float*)d_in[4];
    const float* S_   = (const float*)d_in[5];
    const float* It   = (const float*)d_in[6];
    const float* Rt   = (const float*)d_in[7];
    const float* fc1  = (const float*)d_in[8];
    const float* fc2  = (const float*)d_in[9];
    const float* gWih = (const float*)d_in[10];
    const float* gWhh = (const float*)d_in[11];
    const float* gbih = (const float*)d_in[12];
    const float* gbhh = (const float*)d_in[13];
    const float* r1W  = (const float*)d_in[14];
    const float* r1b  = (const float*)d_in[15];
    const float* r2W  = (const float*)d_in[16];
    const float* r2b  = (const float*)d_in[17];
    const float* hx0  = (const float*)d_in[18];
    float* out = (float*)d_out;

    // ---- workspace carve-up (all region sizes 16B-aligned) ----
    char* w = (char*)d_ws;
    float* pooled = (float*)w; w += (size_t)T_STEPS * H2D * 4;      // 32 KB
    float* hx_all = (float*)w; w += (size_t)T_STEPS * GD * 4;       // 64 KB
    float* gi_all = (float*)w; w += (size_t)T_STEPS * 768 * 4;      // 192 KB
    float* ppart  = (float*)w; w += (size_t)16 * 512 * H2D * 4;     // 4 MB (Tc<=16)
    __hip_bfloat16* W1Thi = (__hip_bfloat16*)w; w += (size_t)384 * 256 * 2; // 192 KB
    __hip_bfloat16* W1Tlo = (__hip_bfloat16*)w; w += (size_t)384 * 256 * 2;
    __hip_bfloat16* f2Thi = (__hip_bfloat16*)w; w += (size_t)128 * 384 * 2; // 96 KB
    __hip_bfloat16* f2Tlo = (__hip_bfloat16*)w; w += (size_t)128 * 384 * 2;
    unsigned int* flags = (unsigned int*)w; w += (size_t)T_STEPS * GRU_NB * 4; // 2 KB
    size_t fixed = (size_t)(w - (char*)d_ws);

    // per-Tc bytes: norms 8KB + pairA 2MB (ihHi/ihLo; later z2) +
    //               z1 3MB + pairC 3MB (cHi/cLo)
    const size_t perTc = 8192 + 2097152 + 3145728 + 3145728;
    int Tc = 16;
    while (Tc > 1) {
        if (fixed + (size_t)Tc * perTc <= ws_size) break;
        Tc >>= 1;
    }
    float* norms = (float*)w;             w += (size_t)Tc * NN * 4;
    char*  pairA = w;                     w += (size_t)Tc * NN * 256 * 2 * 2;
    float* z1    = (float*)w;             w += (size_t)Tc * NN * C1D * 4;
    __hip_bfloat16* cHi = (__hip_bfloat16*)w; w += (size_t)Tc * NN * C1D * 2;
    __hip_bfloat16* cLo = (__hip_bfloat16*)w;

    __hip_bfloat16* ihHi = (__hip_bfloat16*)pairA;
    __hip_bfloat16* ihLo = ihHi + (size_t)Tc * NN * 256;
    // z2 overlays pairA after GEMM1 consumed ihHi/ihLo
    float* z2 = (float*)pairA;

    prep_kernel<<<(384 * 256 + 255) / 256, 256, 0, stream>>>(fc1, fc2, W1Thi, W1Tlo,
                                                             f2Thi, f2Tlo, flags);

    for (int t0 = 0; t0 < T_STEPS; t0 += Tc) {
        int M = Tc * NN;
        norms_kernel      <<<Tc * NN / 4, 256, 0, stream>>>(h, norms, t0);
        input_attn_kernel <<<Tc * NN / 2, 256, 0, stream>>>(h, ng, norms, ihHi, ihLo, t0);
        // z1 = ih @ W1  (M x 256) @ (256 x 384), bf16x3 MFMA, LDS-staged
        gemm_bf16x3<<<dim3(384 / 64, M / 64), 256, 0, stream>>>(ihHi, ihLo, W1Thi, W1Tlo,
                                                                z1, M, 384, 256);
        gat_heads_kernel  <<<Tc * NN, 192, 0, stream>>>(z1, ng, cHi, cLo);
        // z2 = c @ fc2  (M x 384) @ (384 x 128), bf16x3 MFMA, LDS-staged
        gemm_bf16x3<<<dim3(128 / 64, M / 64), 256, 0, stream>>>(cHi, cLo, f2Thi, f2Tlo,
                                                                z2, M, 128, 384);
        gat_final_kernel  <<<Tc * NN / 4, 256, 0, stream>>>(z2, ng, ppart);
        pool_reduce_kernel<<<Tc, 128, 0, stream>>>(ppart, pooled, t0);
    }

    gi_all_kernel<<<T_STEPS * 3, 256, 0, stream>>>(gWih, gbih, pooled, gi_all);
    gru_reg_kernel<<<GRU_NB, 768, 0, stream>>>(gWhh, gbhh, gi_all, hx0, hx_all, flags);
    res_sir_kernel<<<T_STEPS, 128, 0, stream>>>(hx_all, It, Rt, r1W, r1b, r2W, r2b,
                                                I_, R_, S_, Npop, out);
}

// Round 16
// 1441.954 us; speedup vs baseline: 1.2326x; 1.0598x over previous
//
#include <hip/hip_runtime.h>
#include <hip/hip_bf16.h>
#include <math.h>

// Problem constants
#define T_STEPS 64
#define NN      2048
#define KN      32
#define IND     256
#define H1D     128
#define C1D     384   // HEADS*H1
#define H2D     128
#define GD      256
#define PD      60
#define GRU_NB  8     // cooperating blocks for the GRU

typedef __attribute__((ext_vector_type(8))) short bf16x8v;  // 8 bf16 = 4 VGPR
typedef __attribute__((ext_vector_type(4))) float f32x4v;

// bit-reversed 5-bit order (involution)
#define BITREV5_INIT {0,16,8,24,4,20,12,28,2,18,10,26,6,22,14,30, \
                      1,17,9,25,5,21,13,29,3,19,11,27,7,23,15,31}

__device__ __forceinline__ float bcast_lane(float v, int lane_imm) {
    return __uint_as_float(__builtin_amdgcn_readlane(__float_as_uint(v), lane_imm));
}

__device__ __forceinline__ void bf16_split(float v, __hip_bfloat16* hi, __hip_bfloat16* lo) {
    __hip_bfloat16 h = __float2bfloat16(v);
    *hi = h;
    *lo = __float2bfloat16(v - __bfloat162float(h));
}

// Butterfly stages 2..6 on 16 stage-1-combined partials.
__device__ __forceinline__ float xpose_reduce16(float part[16], int lane) {
#pragma unroll
    for (int i = 0; i < 8; ++i) {
        float send = (lane & 2) ? part[i] : part[i + 8];
        float keep = (lane & 2) ? part[i + 8] : part[i];
        part[i] = keep + __shfl_xor(send, 2);
    }
#pragma unroll
    for (int i = 0; i < 4; ++i) {
        float send = (lane & 4) ? part[i] : part[i + 4];
        float keep = (lane & 4) ? part[i + 4] : part[i];
        part[i] = keep + __shfl_xor(send, 4);
    }
#pragma unroll
    for (int i = 0; i < 2; ++i) {
        float send = (lane & 8) ? part[i] : part[i + 2];
        float keep = (lane & 8) ? part[i + 2] : part[i];
        part[i] = keep + __shfl_xor(send, 8);
    }
    {
        float send = (lane & 16) ? part[0] : part[1];
        float keep = (lane & 16) ? part[1] : part[0];
        part[0] = keep + __shfl_xor(send, 16);
    }
    return part[0] + __shfl_xor(part[0], 32);
}

// ---------------------------------------------------------------------------
// K1: row norms of h[t]  (one wave per node, single float4 load)
// ---------------------------------------------------------------------------
__global__ __launch_bounds__(256) void norms_kernel(const float* __restrict__ h,
                                                    float* __restrict__ norms,
                                                    int t_base) {
    int gw   = (int)((blockIdx.x * blockDim.x + threadIdx.x) >> 6);
    int lane = threadIdx.x & 63;
    int n    = gw & (NN - 1);
    int tloc = gw >> 11;
    const float4* row = (const float4*)(h + ((size_t)(t_base + tloc) * NN + n) * IND);
    float4 v = row[lane];
    float s = v.x * v.x + v.y * v.y + v.z * v.z + v.w * v.w;
#pragma unroll
    for (int off = 32; off > 0; off >>= 1) s += __shfl_xor(s, off);
    if (lane == 0) norms[(size_t)tloc * NN + n] = sqrtf(s);
}

// ---------------------------------------------------------------------------
// K2: input attention. 2 waves per (t,n); rows in VGPRs (keep-alive),
// scalar SGPR row bases. Output: bf16 hi/lo pair (feeds MFMA GEMM).
// ---------------------------------------------------------------------------
__global__ __launch_bounds__(256, 5) void input_attn_kernel(const float* __restrict__ h,
                                                            const int* __restrict__ neigh,
                                                            const float* __restrict__ norms,
                                                            __hip_bfloat16* __restrict__ ihHi,
                                                            __hip_bfloat16* __restrict__ ihLo,
                                                            int t_base) {
    const int BR[32] = BITREV5_INIT;
    __shared__ float hd_s[2][2][32];
    int wave    = threadIdx.x >> 6;   // 0..3
    int nodeloc = wave >> 1;          // 0..1
    int half    = wave & 1;           // which 128-dim half
    int lane    = threadIdx.x & 63;
    int gw   = (int)((blockIdx.x << 1) | nodeloc);
    int n    = gw & (NN - 1);
    int tloc = gw >> 11;
    const float* hT  = h + (size_t)(t_base + tloc) * NN * IND;
    const float* nrm = norms + (size_t)tloc * NN;

    const float* dst = hT + (size_t)n * IND + half * 128;
    float d0 = dst[lane], d1 = dst[lane + 64];

    int   jreg = neigh[n * KN + (lane & 31)];
    float nj   = nrm[jreg];
    float ndst = nrm[n];

    float r0[32], r1[32], comb[16];
#pragma unroll
    for (int i = 0; i < 16; ++i) {
        int sja = __builtin_amdgcn_readlane(jreg, BR[i]);
        int sjb = __builtin_amdgcn_readlane(jreg, BR[i + 16]);
        const float* sa = hT + (size_t)sja * IND + half * 128;
        const float* sb = hT + (size_t)sjb * IND + half * 128;
        r0[i]      = sa[lane]; r1[i]      = sa[lane + 64];
        r0[i + 16] = sb[lane]; r1[i + 16] = sb[lane + 64];
        float pa = r0[i] * d0 + r1[i] * d1;
        float pb = r0[i + 16] * d0 + r1[i + 16] * d1;
        float send = (lane & 1) ? pa : pb;
        float keep = (lane & 1) ? pb : pa;
        comb[i] = keep + __shfl_xor(send, 1);
    }
#pragma unroll
    for (int i = 0; i < 32; ++i) asm volatile("" : "+v"(r0[i]), "+v"(r1[i]));
    float hdot = xpose_reduce16(comb, lane);   // half-dot of neighbor (lane&31)
    if (lane < 32) hd_s[nodeloc][half][lane] = hdot;
    __syncthreads();
    float dot = hdot + hd_s[nodeloc][half ^ 1][lane & 31];

    float r  = dot / (nj * ndst);
    float r2 = r * r;
    float e  = r2 * r2;

    float a0 = 0.f, a1 = 0.f;
#pragma unroll
    for (int i = 0; i < 32; ++i) {
        float ek = bcast_lane(e, BR[i]);
        a0 += ek * r0[i];
        a1 += ek * r1[i];
    }
    size_t base = (size_t)gw * IND + half * 128;
    __hip_bfloat16 hi, lo;
    bf16_split(a0, &hi, &lo);
    ihHi[base + lane] = hi;       ihLo[base + lane] = lo;
    bf16_split(a1, &hi, &lo);
    ihHi[base + lane + 64] = hi;  ihLo[base + lane + 64] = lo;
}

// ---------------------------------------------------------------------------
// MFMA GEMM, bf16x3 error-compensated split, LDS-staged, 128x128 tile.
// A: [M][K] bf16 pairs. BT: [N][K] bf16 pairs. C: fp32.
// BM=BN=128, BK=32, 256 thr = 4 waves in 2x2; each wave owns 64x64
// (4x4 fragments of 16x16). LDS rows padded to 40 shorts (80 B -> 2-way
// bank aliasing, free per m136). Fragment mapping identical to verified
// 64^2 version (only row bases changed).
// ---------------------------------------------------------------------------
__global__ __launch_bounds__(256) void gemm_bf16x3(const __hip_bfloat16* __restrict__ Ahi,
                                                   const __hip_bfloat16* __restrict__ Alo,
                                                   const __hip_bfloat16* __restrict__ BThi,
                                                   const __hip_bfloat16* __restrict__ BTlo,
                                                   float* __restrict__ C,
                                                   int M, int N, int K) {
    __shared__ short Ah[128][40], Al[128][40], Bh[128][40], Bl[128][40];
    int tid  = threadIdx.x;
    int lane = tid & 63;
    int w    = tid >> 6;
    int wr   = (w >> 1) * 64;    // wave row base within tile
    int wc   = (w & 1) * 64;     // wave col base within tile
    int mb   = blockIdx.y * 128;
    int n0   = blockIdx.x * 128;
    int r    = lane & 15;        // row within fragment
    int g    = lane >> 4;        // k-group: k = g*8 .. g*8+7

    f32x4v acc[4][4] = {};
    for (int k0 = 0; k0 < K; k0 += 32) {
        __syncthreads();
        // stage 128x32 tiles of all four matrices (2 slots per thread each)
#pragma unroll
        for (int sl = 0; sl < 2; ++sl) {
            int s   = tid + sl * 256;     // 0..511
            int row = s >> 2;             // 0..127
            int seg = s & 3;              // 0..3 (8 bf16 each)
            size_t ga = (size_t)(mb + row) * K + k0 + seg * 8;
            size_t gb = (size_t)(n0 + row) * K + k0 + seg * 8;
            *(bf16x8v*)&Ah[row][seg * 8] = *(const bf16x8v*)(Ahi + ga);
            *(bf16x8v*)&Al[row][seg * 8] = *(const bf16x8v*)(Alo + ga);
            *(bf16x8v*)&Bh[row][seg * 8] = *(const bf16x8v*)(BThi + gb);
            *(bf16x8v*)&Bl[row][seg * 8] = *(const bf16x8v*)(BTlo + gb);
        }
        __syncthreads();
        bf16x8v ah[4], al[4];
#pragma unroll
        for (int m = 0; m < 4; ++m) {
            ah[m] = *(const bf16x8v*)&Ah[wr + m * 16 + r][g * 8];
            al[m] = *(const bf16x8v*)&Al[wr + m * 16 + r][g * 8];
        }
#pragma unroll
        for (int nt = 0; nt < 4; ++nt) {
            bf16x8v bh = *(const bf16x8v*)&Bh[wc + nt * 16 + r][g * 8];
            bf16x8v bl = *(const bf16x8v*)&Bl[wc + nt * 16 + r][g * 8];
#pragma unroll
            for (int m = 0; m < 4; ++m) {
                acc[m][nt] = __builtin_amdgcn_mfma_f32_16x16x32_bf16(ah[m], bh, acc[m][nt], 0, 0, 0);
                acc[m][nt] = __builtin_amdgcn_mfma_f32_16x16x32_bf16(ah[m], bl, acc[m][nt], 0, 0, 0);
                acc[m][nt] = __builtin_amdgcn_mfma_f32_16x16x32_bf16(al[m], bh, acc[m][nt], 0, 0, 0);
            }
        }
    }
    // C/D layout: col = lane&15, row = (lane>>4)*4 + reg   [m89-verified]
#pragma unroll
    for (int m = 0; m < 4; ++m)
#pragma unroll
        for (int nt = 0; nt < 4; ++nt)
#pragma unroll
            for (int q = 0; q < 4; ++q)
                C[(size_t)(mb + wr + m * 16 + g * 4 + q) * N + n0 + wc + nt * 16 + r] = acc[m][nt][q];
}

// ---------------------------------------------------------------------------
// K4: 3-head GAT + relu. One block (192 thr, wave=head) per (t,n).
// ---------------------------------------------------------------------------
__global__ __launch_bounds__(192, 5) void gat_heads_kernel(const float* __restrict__ z1,
                                                           const int* __restrict__ neigh,
                                                           __hip_bfloat16* __restrict__ cHi,
                                                           __hip_bfloat16* __restrict__ cLo) {
    const int BR[32] = BITREV5_INIT;
    int n    = blockIdx.x & (NN - 1);
    const float* ztbl = z1 + (size_t)(blockIdx.x >> 11) * NN * C1D;
    int head = threadIdx.x >> 6;
    int lane = threadIdx.x & 63;

    const float* dst = ztbl + (size_t)n * C1D + head * H1D;
    float d0 = dst[lane], d1 = dst[lane + 64];
    int jreg = neigh[n * KN + (lane & 31)];

    float r0[32], r1[32], comb[16];
#pragma unroll
    for (int i = 0; i < 16; ++i) {
        int sja = __builtin_amdgcn_readlane(jreg, BR[i]);
        int sjb = __builtin_amdgcn_readlane(jreg, BR[i + 16]);
        const float* sa = ztbl + (size_t)sja * C1D + head * H1D;
        const float* sb = ztbl + (size_t)sjb * C1D + head * H1D;
        r0[i]      = sa[lane]; r1[i]      = sa[lane + 64];
        r0[i + 16] = sb[lane]; r1[i + 16] = sb[lane + 64];
        float pa = r0[i] * d0 + r1[i] * d1;
        float pb = r0[i + 16] * d0 + r1[i + 16] * d1;
        float send = (lane & 1) ? pa : pb;
        float keep = (lane & 1) ? pb : pa;
        comb[i] = keep + __shfl_xor(send, 1);
    }
#pragma unroll
    for (int i = 0; i < 32; ++i) asm volatile("" : "+v"(r0[i]), "+v"(r1[i]));
    float dot = xpose_reduce16(comb, lane);

    float m = dot;
#pragma unroll
    for (int off = 16; off > 0; off >>= 1) m = fmaxf(m, __shfl_xor(m, off));
    float p = __expf(dot - m);
    float s = p;
#pragma unroll
    for (int off = 16; off > 0; off >>= 1) s += __shfl_xor(s, off);
    p /= s;

    float a0 = 0.f, a1 = 0.f;
#pragma unroll
    for (int i = 0; i < 32; ++i) {
        float pk = bcast_lane(p, BR[i]);
        a0 += pk * r0[i];
        a1 += pk * r1[i];
    }
    size_t base = (size_t)blockIdx.x * C1D + (size_t)head * H1D;
    __hip_bfloat16 hi, lo;
    bf16_split(fmaxf(a0, 0.f), &hi, &lo);
    cHi[base + lane] = hi;       cLo[base + lane] = lo;
    bf16_split(fmaxf(a1, 0.f), &hi, &lo);
    cHi[base + lane + 64] = hi;  cLo[base + lane + 64] = lo;
}

// ---------------------------------------------------------------------------
// K7: final GAT on z2 (d=128) + relu + FUSED partial max-pool.
// ---------------------------------------------------------------------------
__global__ __launch_bounds__(256, 5) void gat_final_kernel(const float* __restrict__ z2,
                                                           const int* __restrict__ neigh,
                                                           float* __restrict__ ppart) {
    const int BR[32] = BITREV5_INIT;
    __shared__ float red_s[4][128];
    int wave = threadIdx.x >> 6;
    int gw   = (int)((blockIdx.x << 2) | wave);
    int n    = gw & (NN - 1);
    const float* ztbl = z2 + (size_t)(gw >> 11) * NN * H2D;
    int lane = threadIdx.x & 63;

    const float* dst = ztbl + (size_t)n * H2D;
    float d0 = dst[lane], d1 = dst[lane + 64];
    int jreg = neigh[n * KN + (lane & 31)];

    float r0[32], r1[32], comb[16];
#pragma unroll
    for (int i = 0; i < 16; ++i) {
        int sja = __builtin_amdgcn_readlane(jreg, BR[i]);
        int sjb = __builtin_amdgcn_readlane(jreg, BR[i + 16]);
        const float* sa = ztbl + (size_t)sja * H2D;
        const float* sb = ztbl + (size_t)sjb * H2D;
        r0[i]      = sa[lane]; r1[i]      = sa[lane + 64];
        r0[i + 16] = sb[lane]; r1[i + 16] = sb[lane + 64];
        float pa = r0[i] * d0 + r1[i] * d1;
        float pb = r0[i + 16] * d0 + r1[i + 16] * d1;
        float send = (lane & 1) ? pa : pb;
        float keep = (lane & 1) ? pb : pa;
        comb[i] = keep + __shfl_xor(send, 1);
    }
#pragma unroll
    for (int i = 0; i < 32; ++i) asm volatile("" : "+v"(r0[i]), "+v"(r1[i]));
    float dot = xpose_reduce16(comb, lane);

    float m = dot;
#pragma unroll
    for (int off = 16; off > 0; off >>= 1) m = fmaxf(m, __shfl_xor(m, off));
    float p = __expf(dot - m);
    float s = p;
#pragma unroll
    for (int off = 16; off > 0; off >>= 1) s += __shfl_xor(s, off);
    p /= s;

    float a0 = 0.f, a1 = 0.f;
#pragma unroll
    for (int i = 0; i < 32; ++i) {
        float pk = bcast_lane(p, BR[i]);
        a0 += pk * r0[i];
        a1 += pk * r1[i];
    }
    red_s[wave][lane]      = fmaxf(a0, 0.f);
    red_s[wave][lane + 64] = fmaxf(a1, 0.f);
    __syncthreads();
    int tid = threadIdx.x;
    if (tid < 128) {
        float mx = fmaxf(fmaxf(red_s[0][tid], red_s[1][tid]),
                         fmaxf(red_s[2][tid], red_s[3][tid]));
        ppart[(size_t)blockIdx.x * H2D + tid] = mx;
    }
}

// ---------------------------------------------------------------------------
// K8: pooled[t][j] = max over NN/4 = 512 block-partials
// ---------------------------------------------------------------------------
__global__ __launch_bounds__(128) void pool_reduce_kernel(const float* __restrict__ ppart,
                                                          float* __restrict__ pooled,
                                                          int t_base) {
    int j = threadIdx.x;
    const float* base = ppart + (size_t)blockIdx.x * 512 * H2D;
    float mx = 0.f;
#pragma unroll 8
    for (int q = 0; q < 512; ++q) mx = fmaxf(mx, base[(size_t)q * H2D + j]);
    pooled[(t_base + blockIdx.x) * H2D + j] = mx;
}

// ---------------------------------------------------------------------------
// prep: weights -> transposed bf16 hi/lo pairs; zero GRU step flags.
// ---------------------------------------------------------------------------
__global__ void prep_kernel(const float* __restrict__ fc1, const float* __restrict__ fc2,
                            __hip_bfloat16* __restrict__ W1Thi, __hip_bfloat16* __restrict__ W1Tlo,
                            __hip_bfloat16* __restrict__ f2Thi, __hip_bfloat16* __restrict__ f2Tlo,
                            unsigned int* __restrict__ flags) {
    int i = blockIdx.x * 256 + threadIdx.x;
    if (i < 384 * 256) {
        int cf = i / 256, d = i % 256;
        int hd = cf >> 7, j = cf & 127;
        float v = fc1[(size_t)hd * 256 * 128 + (size_t)d * 128 + j];
        __hip_bfloat16 hi, lo;
        bf16_split(v, &hi, &lo);
        W1Thi[i] = hi; W1Tlo[i] = lo;
    }
    if (i < 128 * 384) {
        int n = i / 384, k = i % 384;
        float v = fc2[(size_t)k * 128 + n];
        __hip_bfloat16 hi, lo;
        bf16_split(v, &hi, &lo);
        f2Thi[i] = hi; f2Tlo[i] = lo;
    }
    if (i < T_STEPS * GRU_NB) flags[i] = 0u;
}

// ---------------------------------------------------------------------------
// gi_all[t][o] = Wih[o,:] . pooled[t,:] + bih[o]   (parallel over t)
// ---------------------------------------------------------------------------
__global__ __launch_bounds__(256) void gi_all_kernel(const float* __restrict__ Wih,
                                                     const float* __restrict__ bih,
                                                     const float* __restrict__ pooled,
                                                     float* __restrict__ gi_all) {
    __shared__ float p_s[H2D];
    int t  = blockIdx.x / 3;
    int ob = (blockIdx.x % 3) * 256;
    if (threadIdx.x < H2D) p_s[threadIdx.x] = pooled[t * H2D + threadIdx.x];
    __syncthreads();
    int o = ob + threadIdx.x;
    float acc = bih[o];
    const float* wr = Wih + (size_t)o * H2D;
#pragma unroll 4
    for (int d = 0; d < H2D; ++d) acc += wr[d] * p_s[d];
    gi_all[t * 768 + o] = acc;
}

// ---------------------------------------------------------------------------
// GRU: 8 cooperating blocks, Whh register-resident, per-block flag sync.
// ---------------------------------------------------------------------------
__global__ __launch_bounds__(768) void gru_reg_kernel(const float* __restrict__ Whh,
                                                      const float* __restrict__ bhh,
                                                      const float* __restrict__ gi_all,
                                                      const float* __restrict__ hx0,
                                                      float* hx_all,
                                                      unsigned int* flags) {
    __shared__ float4 hx_pad[72];                 // padded: idx (g,i) -> g*9+i
    __shared__ __align__(16) float hx_lin[GD];    // linear copy for hx_old
    __shared__ float gh_s[96];
    int b   = blockIdx.x;
    int tid = threadIdx.x;
    int row_local = tid >> 3;      // 0..95
    int sub       = tid & 7;       // 0..7
    int chunk     = row_local >> 5;
    int r_in      = row_local & 31;
    int grow      = chunk * GD + b * 32 + r_in;

    float4 wreg[8];
    const float4* wrow = (const float4*)(Whh + (size_t)grow * GD + sub * 32);
#pragma unroll
    for (int i = 0; i < 8; ++i) wreg[i] = wrow[i];
    float bias = (sub == 0) ? bhh[grow] : 0.f;
    int u = b * 32 + tid;          // hidden unit owned by tid<32

    for (int t = 0; t < T_STEPS; ++t) {
        float gi_r = 0.f, gi_z = 0.f, gi_n = 0.f;
        if (tid < 32) {
            gi_r = gi_all[t * 768 + u];
            gi_z = gi_all[t * 768 + 256 + u];
            gi_n = gi_all[t * 768 + 512 + u];
        }
        if (t > 0) {
            if (tid < GRU_NB) {
                while (__hip_atomic_load(&flags[(t - 1) * GRU_NB + tid],
                                         __ATOMIC_ACQUIRE,
                                         __HIP_MEMORY_SCOPE_AGENT) == 0u)
                    __builtin_amdgcn_s_sleep(1);
            }
            __syncthreads();
        }
        const float* hsrc = (t == 0) ? hx0 : (hx_all + (size_t)(t - 1) * GD);
        if (tid < 64) {
            float4 v;
            v.x = __hip_atomic_load(hsrc + tid * 4 + 0, __ATOMIC_RELAXED, __HIP_MEMORY_SCOPE_AGENT);
            v.y = __hip_atomic_load(hsrc + tid * 4 + 1, __ATOMIC_RELAXED, __HIP_MEMORY_SCOPE_AGENT);
            v.z = __hip_atomic_load(hsrc + tid * 4 + 2, __ATOMIC_RELAXED, __HIP_MEMORY_SCOPE_AGENT);
            v.w = __hip_atomic_load(hsrc + tid * 4 + 3, __ATOMIC_RELAXED, __HIP_MEMORY_SCOPE_AGENT);
            hx_pad[(tid >> 3) * 9 + (tid & 7)] = v;
            ((float4*)hx_lin)[tid] = v;
        }
        __syncthreads();

        float acc = 0.f;
#pragma unroll
        for (int i = 0; i < 8; ++i) {
            float4 hv = hx_pad[sub * 9 + i];
            float4 wv = wreg[i];
            acc += wv.x * hv.x + wv.y * hv.y + wv.z * hv.z + wv.w * hv.w;
        }
        acc += __shfl_xor(acc, 1);
        acc += __shfl_xor(acc, 2);
        acc += __shfl_xor(acc, 4);
        if (sub == 0) gh_s[row_local] = acc + bias;
        __syncthreads();

        if (tid < 32) {
            float r  = 1.f / (1.f + expf(-(gi_r + gh_s[tid])));
            float zg = 1.f / (1.f + expf(-(gi_z + gh_s[32 + tid])));
            float nn = tanhf(gi_n + r * gh_s[64 + tid]);
            float hnew = (1.f - zg) * nn + zg * hx_lin[u];
            __hip_atomic_store(&hx_all[(size_t)t * GD + u], hnew,
                               __ATOMIC_RELAXED, __HIP_MEMORY_SCOPE_AGENT);
        }
        __syncthreads();
        if (tid == 0)
            __hip_atomic_store(&flags[t * GRU_NB + b], 1u,
                               __ATOMIC_RELEASE, __HIP_MEMORY_SCOPE_AGENT);
    }
}

// ---------------------------------------------------------------------------
// res heads + SIR scan. One block per t.
// ---------------------------------------------------------------------------
__global__ __launch_bounds__(128) void res_sir_kernel(const float* __restrict__ hx_all,
                                                      const float* __restrict__ It,
                                                      const float* __restrict__ Rt,
                                                      const float* __restrict__ r1W,
                                                      const float* __restrict__ r1b,
                                                      const float* __restrict__ r2W,
                                                      const float* __restrict__ r2b,
                                                      const float* __restrict__ I,
                                                      const float* __restrict__ R,
                                                      const float* __restrict__ S,
                                                      const float* __restrict__ Npop,
                                                      float* __restrict__ out) {
    __shared__ float nhx[258];
    __shared__ float ab_s[2];
    int t = blockIdx.x, tid = threadIdx.x;
    for (int i = tid; i < GD; i += 128) nhx[i] = hx_all[t * GD + i];
    if (tid == 0) { nhx[256] = It[t]; nhx[257] = Rt[t]; }
    __syncthreads();
    if (tid < 120) {
        float acc = r1b[tid];
        const float* wr = r1W + tid * 258;
        for (int d = 0; d < 258; ++d) acc += wr[d] * nhx[d];
        int idx = t * 60 + (tid >> 1);
        if (tid & 1) out[3840 + idx] = acc;
        else         out[idx] = acc;
    }
    if (tid == 120 || tid == 121) {
        int q = tid - 120;
        float acc = r2b[q];
        const float* wr = r2W + q * 258;
        for (int d = 0; d < 258; ++d) acc += wr[d] * nhx[d];
        ab_s[q] = acc;
    }
    __syncthreads();
    if (tid == 0) {
        float a_s = 1.f / (1.f + expf(-ab_s[0]));
        float b_s = 1.f / (1.f + expf(-ab_s[1]));
        float Np = Npop[0];
        float lI = I[t], lR = R[t], lS = S[t];
        for (int p = 0; p < PD; ++p) {
            float dI = a_s * lI * (lS / Np) - b_s * lI;
            float dR = b_s * lI;
            lI += dI;
            lR += dR;
            lS = Np - lI - lR;
            out[7680  + t * 60 + p] = dI;
            out[11520 + t * 60 + p] = dR;
        }
    }
}

// ---------------------------------------------------------------------------
extern "C" void kernel_launch(void* const* d_in, const int* in_sizes, int n_in,
                              void* d_out, int out_size, void* d_ws, size_t ws_size,
                              hipStream_t stream) {
    const float* h    = (const float*)d_in[0];
    const int*   ng   = (const int*)  d_in[1];
    const float* Npop = (const float*)d_in[2];
    const float* I_   = (const float*)d_in[3];
    const float* R_   = (const float*)d_in[4];
    const float* S_   = (const float*)d_in[5];
    const float* It   = (const float*)d_in[6];
    const float* Rt   = (const float*)d_in[7];
    const float* fc1  = (const float*)d_in[8];
    const float* fc2  = (const float*)d_in[9];
    const float* gWih = (const float*)d_in[10];
    const float* gWhh = (const float*)d_in[11];
    const float* gbih = (const float*)d_in[12];
    const float* gbhh = (const float*)d_in[13];
    const float* r1W  = (const float*)d_in[14];
    const float* r1b  = (const float*)d_in[15];
    const float* r2W  = (const float*)d_in[16];
    const float* r2b  = (const float*)d_in[17];
    const float* hx0  = (const float*)d_in[18];
    float* out = (float*)d_out;

    // ---- workspace carve-up (all region sizes 16B-aligned) ----
    char* w = (char*)d_ws;
    float* pooled = (float*)w; w += (size_t)T_STEPS * H2D * 4;      // 32 KB
    float* hx_all = (float*)w; w += (size_t)T_STEPS * GD * 4;       // 64 KB
    float* gi_all = (float*)w; w += (size_t)T_STEPS * 768 * 4;      // 192 KB
    float* ppart  = (float*)w; w += (size_t)16 * 512 * H2D * 4;     // 4 MB (Tc<=16)
    __hip_bfloat16* W1Thi = (__hip_bfloat16*)w; w += (size_t)384 * 256 * 2; // 192 KB
    __hip_bfloat16* W1Tlo = (__hip_bfloat16*)w; w += (size_t)384 * 256 * 2;
    __hip_bfloat16* f2Thi = (__hip_bfloat16*)w; w += (size_t)128 * 384 * 2; // 96 KB
    __hip_bfloat16* f2Tlo = (__hip_bfloat16*)w; w += (size_t)128 * 384 * 2;
    unsigned int* flags = (unsigned int*)w; w += (size_t)T_STEPS * GRU_NB * 4; // 2 KB
    size_t fixed = (size_t)(w - (char*)d_ws);

    // per-Tc bytes: norms 8KB + pairA 2MB (ihHi/ihLo; later z2) +
    //               z1 3MB + pairC 3MB (cHi/cLo)
    const size_t perTc = 8192 + 2097152 + 3145728 + 3145728;
    int Tc = 16;
    while (Tc > 1) {
        if (fixed + (size_t)Tc * perTc <= ws_size) break;
        Tc >>= 1;
    }
    float* norms = (float*)w;             w += (size_t)Tc * NN * 4;
    char*  pairA = w;                     w += (size_t)Tc * NN * 256 * 2 * 2;
    float* z1    = (float*)w;             w += (size_t)Tc * NN * C1D * 4;
    __hip_bfloat16* cHi = (__hip_bfloat16*)w; w += (size_t)Tc * NN * C1D * 2;
    __hip_bfloat16* cLo = (__hip_bfloat16*)w;

    __hip_bfloat16* ihHi = (__hip_bfloat16*)pairA;
    __hip_bfloat16* ihLo = ihHi + (size_t)Tc * NN * 256;
    // z2 overlays pairA after GEMM1 consumed ihHi/ihLo
    float* z2 = (float*)pairA;

    prep_kernel<<<(384 * 256 + 255) / 256, 256, 0, stream>>>(fc1, fc2, W1Thi, W1Tlo,
                                                             f2Thi, f2Tlo, flags);

    for (int t0 = 0; t0 < T_STEPS; t0 += Tc) {
        int M = Tc * NN;
        norms_kernel      <<<Tc * NN / 4, 256, 0, stream>>>(h, norms, t0);
        input_attn_kernel <<<Tc * NN / 2, 256, 0, stream>>>(h, ng, norms, ihHi, ihLo, t0);
        // z1 = ih @ W1  (M x 256) @ (256 x 384), bf16x3 MFMA, 128^2 tile
        gemm_bf16x3<<<dim3(384 / 128, M / 128), 256, 0, stream>>>(ihHi, ihLo, W1Thi, W1Tlo,
                                                                  z1, M, 384, 256);
        gat_heads_kernel  <<<Tc * NN, 192, 0, stream>>>(z1, ng, cHi, cLo);
        // z2 = c @ fc2  (M x 384) @ (384 x 128), bf16x3 MFMA, 128^2 tile
        gemm_bf16x3<<<dim3(128 / 128, M / 128), 256, 0, stream>>>(cHi, cLo, f2Thi, f2Tlo,
                                                                  z2, M, 128, 384);
        gat_final_kernel  <<<Tc * NN / 4, 256, 0, stream>>>(z2, ng, ppart);
        pool_reduce_kernel<<<Tc, 128, 0, stream>>>(ppart, pooled, t0);
    }

    gi_all_kernel<<<T_STEPS * 3, 256, 0, stream>>>(gWih, gbih, pooled, gi_all);
    gru_reg_kernel<<<GRU_NB, 768, 0, stream>>>(gWhh, gbhh, gi_all, hx0, hx_all, flags);
    res_sir_kernel<<<T_STEPS, 128, 0, stream>>>(hx_all, It, Rt, r1W, r1b, r2W, r2b,
                                                I_, R_, S_, Npop, out);
}

// Round 17
// 1440.637 us; speedup vs baseline: 1.2337x; 1.0009x over previous
//
#include <hip/hip_runtime.h>
#include <hip/hip_bf16.h>
#include <math.h>

// Problem constants
#define T_STEPS 64
#define NN      2048
#define KN      32
#define IND     256
#define H1D     128
#define C1D     384   // HEADS*H1
#define H2D     128
#define GD      256
#define PD      60
#define GRU_NB  8     // cooperating blocks for the GRU

typedef __attribute__((ext_vector_type(8))) short bf16x8v;  // 8 bf16 = 4 VGPR
typedef __attribute__((ext_vector_type(4))) float f32x4v;

// bit-reversed 5-bit order (involution)
#define BITREV5_INIT {0,16,8,24,4,20,12,28,2,18,10,26,6,22,14,30, \
                      1,17,9,25,5,21,13,29,3,19,11,27,7,23,15,31}

__device__ __forceinline__ float bcast_lane(float v, int lane_imm) {
    return __uint_as_float(__builtin_amdgcn_readlane(__float_as_uint(v), lane_imm));
}

__device__ __forceinline__ void bf16_split(float v, __hip_bfloat16* hi, __hip_bfloat16* lo) {
    __hip_bfloat16 h = __float2bfloat16(v);
    *hi = h;
    *lo = __float2bfloat16(v - __bfloat162float(h));
}

// Butterfly stages 2..6 on 16 stage-1-combined partials.
__device__ __forceinline__ float xpose_reduce16(float part[16], int lane) {
#pragma unroll
    for (int i = 0; i < 8; ++i) {
        float send = (lane & 2) ? part[i] : part[i + 8];
        float keep = (lane & 2) ? part[i + 8] : part[i];
        part[i] = keep + __shfl_xor(send, 2);
    }
#pragma unroll
    for (int i = 0; i < 4; ++i) {
        float send = (lane & 4) ? part[i] : part[i + 4];
        float keep = (lane & 4) ? part[i + 4] : part[i];
        part[i] = keep + __shfl_xor(send, 4);
    }
#pragma unroll
    for (int i = 0; i < 2; ++i) {
        float send = (lane & 8) ? part[i] : part[i + 2];
        float keep = (lane & 8) ? part[i + 2] : part[i];
        part[i] = keep + __shfl_xor(send, 8);
    }
    {
        float send = (lane & 16) ? part[0] : part[1];
        float keep = (lane & 16) ? part[1] : part[0];
        part[0] = keep + __shfl_xor(send, 16);
    }
    return part[0] + __shfl_xor(part[0], 32);
}

// ---------------------------------------------------------------------------
// K1: row norms of h[t]  (one wave per node, single float4 load)
// ---------------------------------------------------------------------------
__global__ __launch_bounds__(256) void norms_kernel(const float* __restrict__ h,
                                                    float* __restrict__ norms,
                                                    int t_base) {
    int gw   = (int)((blockIdx.x * blockDim.x + threadIdx.x) >> 6);
    int lane = threadIdx.x & 63;
    int n    = gw & (NN - 1);
    int tloc = gw >> 11;
    const float4* row = (const float4*)(h + ((size_t)(t_base + tloc) * NN + n) * IND);
    float4 v = row[lane];
    float s = v.x * v.x + v.y * v.y + v.z * v.z + v.w * v.w;
#pragma unroll
    for (int off = 32; off > 0; off >>= 1) s += __shfl_xor(s, off);
    if (lane == 0) norms[(size_t)tloc * NN + n] = sqrtf(s);
}

// ---------------------------------------------------------------------------
// K2: input attention. 2 waves per (t,n); rows in VGPRs (keep-alive),
// scalar SGPR row bases. Output: bf16 hi/lo pair (feeds MFMA GEMM).
// ---------------------------------------------------------------------------
__global__ __launch_bounds__(256, 5) void input_attn_kernel(const float* __restrict__ h,
                                                            const int* __restrict__ neigh,
                                                            const float* __restrict__ norms,
                                                            __hip_bfloat16* __restrict__ ihHi,
                                                            __hip_bfloat16* __restrict__ ihLo,
                                                            int t_base) {
    const int BR[32] = BITREV5_INIT;
    __shared__ float hd_s[2][2][32];
    int wave    = threadIdx.x >> 6;   // 0..3
    int nodeloc = wave >> 1;          // 0..1
    int half    = wave & 1;           // which 128-dim half
    int lane    = threadIdx.x & 63;
    int gw   = (int)((blockIdx.x << 1) | nodeloc);
    int n    = gw & (NN - 1);
    int tloc = gw >> 11;
    const float* hT  = h + (size_t)(t_base + tloc) * NN * IND;
    const float* nrm = norms + (size_t)tloc * NN;

    const float* dst = hT + (size_t)n * IND + half * 128;
    float d0 = dst[lane], d1 = dst[lane + 64];

    int   jreg = neigh[n * KN + (lane & 31)];
    float nj   = nrm[jreg];
    float ndst = nrm[n];

    float r0[32], r1[32], comb[16];
#pragma unroll
    for (int i = 0; i < 16; ++i) {
        int sja = __builtin_amdgcn_readlane(jreg, BR[i]);
        int sjb = __builtin_amdgcn_readlane(jreg, BR[i + 16]);
        const float* sa = hT + (size_t)sja * IND + half * 128;
        const float* sb = hT + (size_t)sjb * IND + half * 128;
        r0[i]      = sa[lane]; r1[i]      = sa[lane + 64];
        r0[i + 16] = sb[lane]; r1[i + 16] = sb[lane + 64];
        float pa = r0[i] * d0 + r1[i] * d1;
        float pb = r0[i + 16] * d0 + r1[i + 16] * d1;
        float send = (lane & 1) ? pa : pb;
        float keep = (lane & 1) ? pb : pa;
        comb[i] = keep + __shfl_xor(send, 1);
    }
#pragma unroll
    for (int i = 0; i < 32; ++i) asm volatile("" : "+v"(r0[i]), "+v"(r1[i]));
    float hdot = xpose_reduce16(comb, lane);   // half-dot of neighbor (lane&31)
    if (lane < 32) hd_s[nodeloc][half][lane] = hdot;
    __syncthreads();
    float dot = hdot + hd_s[nodeloc][half ^ 1][lane & 31];

    float r  = dot / (nj * ndst);
    float r2 = r * r;
    float e  = r2 * r2;

    float a0 = 0.f, a1 = 0.f;
#pragma unroll
    for (int i = 0; i < 32; ++i) {
        float ek = bcast_lane(e, BR[i]);
        a0 += ek * r0[i];
        a1 += ek * r1[i];
    }
    size_t base = (size_t)gw * IND + half * 128;
    __hip_bfloat16 hi, lo;
    bf16_split(a0, &hi, &lo);
    ihHi[base + lane] = hi;       ihLo[base + lane] = lo;
    bf16_split(a1, &hi, &lo);
    ihHi[base + lane + 64] = hi;  ihLo[base + lane + 64] = lo;
}

// ---------------------------------------------------------------------------
// MFMA GEMM, bf16x3 error-compensated split, LDS-staged, 128x128 tile.
// A: [M][K] bf16 pairs. BT: [N][K] bf16 pairs. C: fp32.
// BM=BN=128, BK=32, 256 thr = 4 waves in 2x2; each wave owns 64x64
// (4x4 fragments of 16x16). LDS rows padded to 40 shorts (80 B -> 2-way
// bank aliasing, free per m136). Fragment mapping identical to verified
// 64^2 version (only row bases changed).
// ---------------------------------------------------------------------------
__global__ __launch_bounds__(256) void gemm_bf16x3(const __hip_bfloat16* __restrict__ Ahi,
                                                   const __hip_bfloat16* __restrict__ Alo,
                                                   const __hip_bfloat16* __restrict__ BThi,
                                                   const __hip_bfloat16* __restrict__ BTlo,
                                                   float* __restrict__ C,
                                                   int M, int N, int K) {
    __shared__ short Ah[128][40], Al[128][40], Bh[128][40], Bl[128][40];
    int tid  = threadIdx.x;
    int lane = tid & 63;
    int w    = tid >> 6;
    int wr   = (w >> 1) * 64;    // wave row base within tile
    int wc   = (w & 1) * 64;     // wave col base within tile
    int mb   = blockIdx.y * 128;
    int n0   = blockIdx.x * 128;
    int r    = lane & 15;        // row within fragment
    int g    = lane >> 4;        // k-group: k = g*8 .. g*8+7

    f32x4v acc[4][4] = {};
    for (int k0 = 0; k0 < K; k0 += 32) {
        __syncthreads();
        // stage 128x32 tiles of all four matrices (2 slots per thread each)
#pragma unroll
        for (int sl = 0; sl < 2; ++sl) {
            int s   = tid + sl * 256;     // 0..511
            int row = s >> 2;             // 0..127
            int seg = s & 3;              // 0..3 (8 bf16 each)
            size_t ga = (size_t)(mb + row) * K + k0 + seg * 8;
            size_t gb = (size_t)(n0 + row) * K + k0 + seg * 8;
            *(bf16x8v*)&Ah[row][seg * 8] = *(const bf16x8v*)(Ahi + ga);
            *(bf16x8v*)&Al[row][seg * 8] = *(const bf16x8v*)(Alo + ga);
            *(bf16x8v*)&Bh[row][seg * 8] = *(const bf16x8v*)(BThi + gb);
            *(bf16x8v*)&Bl[row][seg * 8] = *(const bf16x8v*)(BTlo + gb);
        }
        __syncthreads();
        bf16x8v ah[4], al[4];
#pragma unroll
        for (int m = 0; m < 4; ++m) {
            ah[m] = *(const bf16x8v*)&Ah[wr + m * 16 + r][g * 8];
            al[m] = *(const bf16x8v*)&Al[wr + m * 16 + r][g * 8];
        }
#pragma unroll
        for (int nt = 0; nt < 4; ++nt) {
            bf16x8v bh = *(const bf16x8v*)&Bh[wc + nt * 16 + r][g * 8];
            bf16x8v bl = *(const bf16x8v*)&Bl[wc + nt * 16 + r][g * 8];
#pragma unroll
            for (int m = 0; m < 4; ++m) {
                acc[m][nt] = __builtin_amdgcn_mfma_f32_16x16x32_bf16(ah[m], bh, acc[m][nt], 0, 0, 0);
                acc[m][nt] = __builtin_amdgcn_mfma_f32_16x16x32_bf16(ah[m], bl, acc[m][nt], 0, 0, 0);
                acc[m][nt] = __builtin_amdgcn_mfma_f32_16x16x32_bf16(al[m], bh, acc[m][nt], 0, 0, 0);
            }
        }
    }
    // C/D layout: col = lane&15, row = (lane>>4)*4 + reg   [m89-verified]
#pragma unroll
    for (int m = 0; m < 4; ++m)
#pragma unroll
        for (int nt = 0; nt < 4; ++nt)
#pragma unroll
            for (int q = 0; q < 4; ++q)
                C[(size_t)(mb + wr + m * 16 + g * 4 + q) * N + n0 + wc + nt * 16 + r] = acc[m][nt][q];
}

// ---------------------------------------------------------------------------
// K4: 3-head GAT + relu. One block (192 thr, wave=head) per (t,n).
// ---------------------------------------------------------------------------
__global__ __launch_bounds__(192, 5) void gat_heads_kernel(const float* __restrict__ z1,
                                                           const int* __restrict__ neigh,
                                                           __hip_bfloat16* __restrict__ cHi,
                                                           __hip_bfloat16* __restrict__ cLo) {
    const int BR[32] = BITREV5_INIT;
    int n    = blockIdx.x & (NN - 1);
    const float* ztbl = z1 + (size_t)(blockIdx.x >> 11) * NN * C1D;
    int head = threadIdx.x >> 6;
    int lane = threadIdx.x & 63;

    const float* dst = ztbl + (size_t)n * C1D + head * H1D;
    float d0 = dst[lane], d1 = dst[lane + 64];
    int jreg = neigh[n * KN + (lane & 31)];

    float r0[32], r1[32], comb[16];
#pragma unroll
    for (int i = 0; i < 16; ++i) {
        int sja = __builtin_amdgcn_readlane(jreg, BR[i]);
        int sjb = __builtin_amdgcn_readlane(jreg, BR[i + 16]);
        const float* sa = ztbl + (size_t)sja * C1D + head * H1D;
        const float* sb = ztbl + (size_t)sjb * C1D + head * H1D;
        r0[i]      = sa[lane]; r1[i]      = sa[lane + 64];
        r0[i + 16] = sb[lane]; r1[i + 16] = sb[lane + 64];
        float pa = r0[i] * d0 + r1[i] * d1;
        float pb = r0[i + 16] * d0 + r1[i + 16] * d1;
        float send = (lane & 1) ? pa : pb;
        float keep = (lane & 1) ? pb : pa;
        comb[i] = keep + __shfl_xor(send, 1);
    }
#pragma unroll
    for (int i = 0; i < 32; ++i) asm volatile("" : "+v"(r0[i]), "+v"(r1[i]));
    float dot = xpose_reduce16(comb, lane);

    float m = dot;
#pragma unroll
    for (int off = 16; off > 0; off >>= 1) m = fmaxf(m, __shfl_xor(m, off));
    float p = __expf(dot - m);
    float s = p;
#pragma unroll
    for (int off = 16; off > 0; off >>= 1) s += __shfl_xor(s, off);
    p /= s;

    float a0 = 0.f, a1 = 0.f;
#pragma unroll
    for (int i = 0; i < 32; ++i) {
        float pk = bcast_lane(p, BR[i]);
        a0 += pk * r0[i];
        a1 += pk * r1[i];
    }
    size_t base = (size_t)blockIdx.x * C1D + (size_t)head * H1D;
    __hip_bfloat16 hi, lo;
    bf16_split(fmaxf(a0, 0.f), &hi, &lo);
    cHi[base + lane] = hi;       cLo[base + lane] = lo;
    bf16_split(fmaxf(a1, 0.f), &hi, &lo);
    cHi[base + lane + 64] = hi;  cLo[base + lane + 64] = lo;
}

// ---------------------------------------------------------------------------
// K7: final GAT on z2 (d=128) + relu + FUSED partial max-pool.
// ---------------------------------------------------------------------------
__global__ __launch_bounds__(256, 5) void gat_final_kernel(const float* __restrict__ z2,
                                                           const int* __restrict__ neigh,
                                                           float* __restrict__ ppart) {
    const int BR[32] = BITREV5_INIT;
    __shared__ float red_s[4][128];
    int wave = threadIdx.x >> 6;
    int gw   = (int)((blockIdx.x << 2) | wave);
    int n    = gw & (NN - 1);
    const float* ztbl = z2 + (size_t)(gw >> 11) * NN * H2D;
    int lane = threadIdx.x & 63;

    const float* dst = ztbl + (size_t)n * H2D;
    float d0 = dst[lane], d1 = dst[lane + 64];
    int jreg = neigh[n * KN + (lane & 31)];

    float r0[32], r1[32], comb[16];
#pragma unroll
    for (int i = 0; i < 16; ++i) {
        int sja = __builtin_amdgcn_readlane(jreg, BR[i]);
        int sjb = __builtin_amdgcn_readlane(jreg, BR[i + 16]);
        const float* sa = ztbl + (size_t)sja * H2D;
        const float* sb = ztbl + (size_t)sjb * H2D;
        r0[i]      = sa[lane]; r1[i]      = sa[lane + 64];
        r0[i + 16] = sb[lane]; r1[i + 16] = sb[lane + 64];
        float pa = r0[i] * d0 + r1[i] * d1;
        float pb = r0[i + 16] * d0 + r1[i + 16] * d1;
        float send = (lane & 1) ? pa : pb;
        float keep = (lane & 1) ? pb : pa;
        comb[i] = keep + __shfl_xor(send, 1);
    }
#pragma unroll
    for (int i = 0; i < 32; ++i) asm volatile("" : "+v"(r0[i]), "+v"(r1[i]));
    float dot = xpose_reduce16(comb, lane);

    float m = dot;
#pragma unroll
    for (int off = 16; off > 0; off >>= 1) m = fmaxf(m, __shfl_xor(m, off));
    float p = __expf(dot - m);
    float s = p;
#pragma unroll
    for (int off = 16; off > 0; off >>= 1) s += __shfl_xor(s, off);
    p /= s;

    float a0 = 0.f, a1 = 0.f;
#pragma unroll
    for (int i = 0; i < 32; ++i) {
        float pk = bcast_lane(p, BR[i]);
        a0 += pk * r0[i];
        a1 += pk * r1[i];
    }
    red_s[wave][lane]      = fmaxf(a0, 0.f);
    red_s[wave][lane + 64] = fmaxf(a1, 0.f);
    __syncthreads();
    int tid = threadIdx.x;
    if (tid < 128) {
        float mx = fmaxf(fmaxf(red_s[0][tid], red_s[1][tid]),
                         fmaxf(red_s[2][tid], red_s[3][tid]));
        ppart[(size_t)blockIdx.x * H2D + tid] = mx;
    }
}

// ---------------------------------------------------------------------------
// K8: pooled[t][j] = max over NN/4 = 512 block-partials
// ---------------------------------------------------------------------------
__global__ __launch_bounds__(128) void pool_reduce_kernel(const float* __restrict__ ppart,
                                                          float* __restrict__ pooled,
                                                          int t_base) {
    int j = threadIdx.x;
    const float* base = ppart + (size_t)blockIdx.x * 512 * H2D;
    float mx = 0.f;
#pragma unroll 8
    for (int q = 0; q < 512; ++q) mx = fmaxf(mx, base[(size_t)q * H2D + j]);
    pooled[(t_base + blockIdx.x) * H2D + j] = mx;
}

// ---------------------------------------------------------------------------
// prep: weights -> transposed bf16 hi/lo pairs; zero GRU step flags.
// ---------------------------------------------------------------------------
__global__ void prep_kernel(const float* __restrict__ fc1, const float* __restrict__ fc2,
                            __hip_bfloat16* __restrict__ W1Thi, __hip_bfloat16* __restrict__ W1Tlo,
                            __hip_bfloat16* __restrict__ f2Thi, __hip_bfloat16* __restrict__ f2Tlo,
                            unsigned int* __restrict__ flags) {
    int i = blockIdx.x * 256 + threadIdx.x;
    if (i < 384 * 256) {
        int cf = i / 256, d = i % 256;
        int hd = cf >> 7, j = cf & 127;
        float v = fc1[(size_t)hd * 256 * 128 + (size_t)d * 128 + j];
        __hip_bfloat16 hi, lo;
        bf16_split(v, &hi, &lo);
        W1Thi[i] = hi; W1Tlo[i] = lo;
    }
    if (i < 128 * 384) {
        int n = i / 384, k = i % 384;
        float v = fc2[(size_t)k * 128 + n];
        __hip_bfloat16 hi, lo;
        bf16_split(v, &hi, &lo);
        f2Thi[i] = hi; f2Tlo[i] = lo;
    }
    if (i < T_STEPS * GRU_NB) flags[i] = 0u;
}

// ---------------------------------------------------------------------------
// gi_all[t][o] = Wih[o,:] . pooled[t,:] + bih[o]   (parallel over t)
// ---------------------------------------------------------------------------
__global__ __launch_bounds__(256) void gi_all_kernel(const float* __restrict__ Wih,
                                                     const float* __restrict__ bih,
                                                     const float* __restrict__ pooled,
                                                     float* __restrict__ gi_all) {
    __shared__ float p_s[H2D];
    int t  = blockIdx.x / 3;
    int ob = (blockIdx.x % 3) * 256;
    if (threadIdx.x < H2D) p_s[threadIdx.x] = pooled[t * H2D + threadIdx.x];
    __syncthreads();
    int o = ob + threadIdx.x;
    float acc = bih[o];
    const float* wr = Wih + (size_t)o * H2D;
#pragma unroll 4
    for (int d = 0; d < H2D; ++d) acc += wr[d] * p_s[d];
    gi_all[t * 768 + o] = acc;
}

// ---------------------------------------------------------------------------
// GRU: 8 cooperating blocks, Whh register-resident, per-block flag sync.
// ---------------------------------------------------------------------------
__global__ __launch_bounds__(768) void gru_reg_kernel(const float* __restrict__ Whh,
                                                      const float* __restrict__ bhh,
                                                      const float* __restrict__ gi_all,
                                                      const float* __restrict__ hx0,
                                                      float* hx_all,
                                                      unsigned int* flags) {
    __shared__ float4 hx_pad[72];                 // padded: idx (g,i) -> g*9+i
    __shared__ __align__(16) float hx_lin[GD];    // linear copy for hx_old
    __shared__ float gh_s[96];
    int b   = blockIdx.x;
    int tid = threadIdx.x;
    int row_local = tid >> 3;      // 0..95
    int sub       = tid & 7;       // 0..7
    int chunk     = row_local >> 5;
    int r_in      = row_local & 31;
    int grow      = chunk * GD + b * 32 + r_in;

    float4 wreg[8];
    const float4* wrow = (const float4*)(Whh + (size_t)grow * GD + sub * 32);
#pragma unroll
    for (int i = 0; i < 8; ++i) wreg[i] = wrow[i];
    float bias = (sub == 0) ? bhh[grow] : 0.f;
    int u = b * 32 + tid;          // hidden unit owned by tid<32

    for (int t = 0; t < T_STEPS; ++t) {
        float gi_r = 0.f, gi_z = 0.f, gi_n = 0.f;
        if (tid < 32) {
            gi_r = gi_all[t * 768 + u];
            gi_z = gi_all[t * 768 + 256 + u];
            gi_n = gi_all[t * 768 + 512 + u];
        }
        if (t > 0) {
            if (tid < GRU_NB) {
                while (__hip_atomic_load(&flags[(t - 1) * GRU_NB + tid],
                                         __ATOMIC_ACQUIRE,
                                         __HIP_MEMORY_SCOPE_AGENT) == 0u)
                    __builtin_amdgcn_s_sleep(1);
            }
            __syncthreads();
        }
        const float* hsrc = (t == 0) ? hx0 : (hx_all + (size_t)(t - 1) * GD);
        if (tid < 64) {
            float4 v;
            v.x = __hip_atomic_load(hsrc + tid * 4 + 0, __ATOMIC_RELAXED, __HIP_MEMORY_SCOPE_AGENT);
            v.y = __hip_atomic_load(hsrc + tid * 4 + 1, __ATOMIC_RELAXED, __HIP_MEMORY_SCOPE_AGENT);
            v.z = __hip_atomic_load(hsrc + tid * 4 + 2, __ATOMIC_RELAXED, __HIP_MEMORY_SCOPE_AGENT);
            v.w = __hip_atomic_load(hsrc + tid * 4 + 3, __ATOMIC_RELAXED, __HIP_MEMORY_SCOPE_AGENT);
            hx_pad[(tid >> 3) * 9 + (tid & 7)] = v;
            ((float4*)hx_lin)[tid] = v;
        }
        __syncthreads();

        float acc = 0.f;
#pragma unroll
        for (int i = 0; i < 8; ++i) {
            float4 hv = hx_pad[sub * 9 + i];
            float4 wv = wreg[i];
            acc += wv.x * hv.x + wv.y * hv.y + wv.z * hv.z + wv.w * hv.w;
        }
        acc += __shfl_xor(acc, 1);
        acc += __shfl_xor(acc, 2);
        acc += __shfl_xor(acc, 4);
        if (sub == 0) gh_s[row_local] = acc + bias;
        __syncthreads();

        if (tid < 32) {
            float r  = 1.f / (1.f + expf(-(gi_r + gh_s[tid])));
            float zg = 1.f / (1.f + expf(-(gi_z + gh_s[32 + tid])));
            float nn = tanhf(gi_n + r * gh_s[64 + tid]);
            float hnew = (1.f - zg) * nn + zg * hx_lin[u];
            __hip_atomic_store(&hx_all[(size_t)t * GD + u], hnew,
                               __ATOMIC_RELAXED, __HIP_MEMORY_SCOPE_AGENT);
        }
        __syncthreads();
        if (tid == 0)
            __hip_atomic_store(&flags[t * GRU_NB + b], 1u,
                               __ATOMIC_RELEASE, __HIP_MEMORY_SCOPE_AGENT);
    }
}

// ---------------------------------------------------------------------------
// res heads + SIR scan. One block per t.
// ---------------------------------------------------------------------------
__global__ __launch_bounds__(128) void res_sir_kernel(const float* __restrict__ hx_all,
                                                      const float* __restrict__ It,
                                                      const float* __restrict__ Rt,
                                                      const float* __restrict__ r1W,
                                                      const float* __restrict__ r1b,
                                                      const float* __restrict__ r2W,
                                                      const float* __restrict__ r2b,
                                                      const float* __restrict__ I,
                                                      const float* __restrict__ R,
                                                      const float* __restrict__ S,
                                                      const float* __restrict__ Npop,
                                                      float* __restrict__ out) {
    __shared__ float nhx[258];
    __shared__ float ab_s[2];
    int t = blockIdx.x, tid = threadIdx.x;
    for (int i = tid; i < GD; i += 128) nhx[i] = hx_all[t * GD + i];
    if (tid == 0) { nhx[256] = It[t]; nhx[257] = Rt[t]; }
    __syncthreads();
    if (tid < 120) {
        float acc = r1b[tid];
        const float* wr = r1W + tid * 258;
        for (int d = 0; d < 258; ++d) acc += wr[d] * nhx[d];
        int idx = t * 60 + (tid >> 1);
        if (tid & 1) out[3840 + idx] = acc;
        else         out[idx] = acc;
    }
    if (tid == 120 || tid == 121) {
        int q = tid - 120;
        float acc = r2b[q];
        const float* wr = r2W + q * 258;
        for (int d = 0; d < 258; ++d) acc += wr[d] * nhx[d];
        ab_s[q] = acc;
    }
    __syncthreads();
    if (tid == 0) {
        float a_s = 1.f / (1.f + expf(-ab_s[0]));
        float b_s = 1.f / (1.f + expf(-ab_s[1]));
        float Np = Npop[0];
        float lI = I[t], lR = R[t], lS = S[t];
        for (int p = 0; p < PD; ++p) {
            float dI = a_s * lI * (lS / Np) - b_s * lI;
            float dR = b_s * lI;
            lI += dI;
            lR += dR;
            lS = Np - lI - lR;
            out[7680  + t * 60 + p] = dI;
            out[11520 + t * 60 + p] = dR;
        }
    }
}

// ---------------------------------------------------------------------------
extern "C" void kernel_launch(void* const* d_in, const int* in_sizes, int n_in,
                              void* d_out, int out_size, void* d_ws, size_t ws_size,
                              hipStream_t stream) {
    const float* h    = (const float*)d_in[0];
    const int*   ng   = (const int*)  d_in[1];
    const float* Npop = (const float*)d_in[2];
    const float* I_   = (const float*)d_in[3];
    const float* R_   = (const float*)d_in[4];
    const float* S_   = (const float*)d_in[5];
    const float* It   = (const float*)d_in[6];
    const float* Rt   = (const float*)d_in[7];
    const float* fc1  = (const float*)d_in[8];
    const float* fc2  = (const float*)d_in[9];
    const float* gWih = (const float*)d_in[10];
    const float* gWhh = (const float*)d_in[11];
    const float* gbih = (const float*)d_in[12];
    const float* gbhh = (const float*)d_in[13];
    const float* r1W  = (const float*)d_in[14];
    const float* r1b  = (const float*)d_in[15];
    const float* r2W  = (const float*)d_in[16];
    const float* r2b  = (const float*)d_in[17];
    const float* hx0  = (const float*)d_in[18];
    float* out = (float*)d_out;

    // ---- workspace carve-up (all region sizes 16B-aligned) ----
    char* w = (char*)d_ws;
    float* pooled = (float*)w; w += (size_t)T_STEPS * H2D * 4;      // 32 KB
    float* hx_all = (float*)w; w += (size_t)T_STEPS * GD * 4;       // 64 KB
    float* gi_all = (float*)w; w += (size_t)T_STEPS * 768 * 4;      // 192 KB
    float* ppart  = (float*)w; w += (size_t)16 * 512 * H2D * 4;     // 4 MB (Tc<=16)
    __hip_bfloat16* W1Thi = (__hip_bfloat16*)w; w += (size_t)384 * 256 * 2; // 192 KB
    __hip_bfloat16* W1Tlo = (__hip_bfloat16*)w; w += (size_t)384 * 256 * 2;
    __hip_bfloat16* f2Thi = (__hip_bfloat16*)w; w += (size_t)128 * 384 * 2; // 96 KB
    __hip_bfloat16* f2Tlo = (__hip_bfloat16*)w; w += (size_t)128 * 384 * 2;
    unsigned int* flags = (unsigned int*)w; w += (size_t)T_STEPS * GRU_NB * 4; // 2 KB
    size_t fixed = (size_t)(w - (char*)d_ws);

    // per-Tc bytes: norms 8KB + pairA 2MB (ihHi/ihLo; later z2) +
    //               z1 3MB + pairC 3MB (cHi/cLo)
    const size_t perTc = 8192 + 2097152 + 3145728 + 3145728;
    int Tc = 16;
    while (Tc > 1) {
        if (fixed + (size_t)Tc * perTc <= ws_size) break;
        Tc >>= 1;
    }
    float* norms = (float*)w;             w += (size_t)Tc * NN * 4;
    char*  pairA = w;                     w += (size_t)Tc * NN * 256 * 2 * 2;
    float* z1    = (float*)w;             w += (size_t)Tc * NN * C1D * 4;
    __hip_bfloat16* cHi = (__hip_bfloat16*)w; w += (size_t)Tc * NN * C1D * 2;
    __hip_bfloat16* cLo = (__hip_bfloat16*)w;

    __hip_bfloat16* ihHi = (__hip_bfloat16*)pairA;
    __hip_bfloat16* ihLo = ihHi + (size_t)Tc * NN * 256;
    // z2 overlays pairA after GEMM1 consumed ihHi/ihLo
    float* z2 = (float*)pairA;

    prep_kernel<<<(384 * 256 + 255) / 256, 256, 0, stream>>>(fc1, fc2, W1Thi, W1Tlo,
                                                             f2Thi, f2Tlo, flags);

    for (int t0 = 0; t0 < T_STEPS; t0 += Tc) {
        int M = Tc * NN;
        norms_kernel      <<<Tc * NN / 4, 256, 0, stream>>>(h, norms, t0);
        input_attn_kernel <<<Tc * NN / 2, 256, 0, stream>>>(h, ng, norms, ihHi, ihLo, t0);
        // z1 = ih @ W1  (M x 256) @ (256 x 384), bf16x3 MFMA, 128^2 tile
        gemm_bf16x3<<<dim3(384 / 128, M / 128), 256, 0, stream>>>(ihHi, ihLo, W1Thi, W1Tlo,
                                                                  z1, M, 384, 256);
        gat_heads_kernel  <<<Tc * NN, 192, 0, stream>>>(z1, ng, cHi, cLo);
        // z2 = c @ fc2  (M x 384) @ (384 x 128), bf16x3 MFMA, 128^2 tile
        gemm_bf16x3<<<dim3(128 / 128, M / 128), 256, 0, stream>>>(cHi, cLo, f2Thi, f2Tlo,
                                                                  z2, M, 128, 384);
        gat_final_kernel  <<<Tc * NN / 4, 256, 0, stream>>>(z2, ng, ppart);
        pool_reduce_kernel<<<Tc, 128, 0, stream>>>(ppart, pooled, t0);
    }

    gi_all_kernel<<<T_STEPS * 3, 256, 0, stream>>>(gWih, gbih, pooled, gi_all);
    gru_reg_kernel<<<GRU_NB, 768, 0, stream>>>(gWhh, gbhh, gi_all, hx0, hx_all, flags);
    res_sir_kernel<<<T_STEPS, 128, 0, stream>>>(hx_all, It, Rt, r1W, r1b, r2W, r2b,
                                                I_, R_, S_, Npop, out);
}

// Round 18
// 1440.320 us; speedup vs baseline: 1.2340x; 1.0002x over previous
//
#include <hip/hip_runtime.h>
#include <hip/hip_bf16.h>
#include <math.h>

// Problem constants
#define T_STEPS 64
#define NN      2048
#define KN      32
#define IND     256
#define H1D     128
#define C1D     384   // HEADS*H1
#define H2D     128
#define GD      256
#define PD      60
#define GRU_NB  8     // cooperating blocks for the GRU

typedef __attribute__((ext_vector_type(8))) short bf16x8v;  // 8 bf16 = 4 VGPR
typedef __attribute__((ext_vector_type(4))) float f32x4v;

// bit-reversed 5-bit order (involution)
#define BITREV5_INIT {0,16,8,24,4,20,12,28,2,18,10,26,6,22,14,30, \
                      1,17,9,25,5,21,13,29,3,19,11,27,7,23,15,31}

__device__ __forceinline__ float bcast_lane(float v, int lane_imm) {
    return __uint_as_float(__builtin_amdgcn_readlane(__float_as_uint(v), lane_imm));
}

__device__ __forceinline__ void bf16_split(float v, __hip_bfloat16* hi, __hip_bfloat16* lo) {
    __hip_bfloat16 h = __float2bfloat16(v);
    *hi = h;
    *lo = __float2bfloat16(v - __bfloat162float(h));
}

// Butterfly stages 2..6 on 16 stage-1-combined partials.
__device__ __forceinline__ float xpose_reduce16(float part[16], int lane) {
#pragma unroll
    for (int i = 0; i < 8; ++i) {
        float send = (lane & 2) ? part[i] : part[i + 8];
        float keep = (lane & 2) ? part[i + 8] : part[i];
        part[i] = keep + __shfl_xor(send, 2);
    }
#pragma unroll
    for (int i = 0; i < 4; ++i) {
        float send = (lane & 4) ? part[i] : part[i + 4];
        float keep = (lane & 4) ? part[i + 4] : part[i];
        part[i] = keep + __shfl_xor(send, 4);
    }
#pragma unroll
    for (int i = 0; i < 2; ++i) {
        float send = (lane & 8) ? part[i] : part[i + 2];
        float keep = (lane & 8) ? part[i + 2] : part[i];
        part[i] = keep + __shfl_xor(send, 8);
    }
    {
        float send = (lane & 16) ? part[0] : part[1];
        float keep = (lane & 16) ? part[1] : part[0];
        part[0] = keep + __shfl_xor(send, 16);
    }
    return part[0] + __shfl_xor(part[0], 32);
}

// ---------------------------------------------------------------------------
// K1: row norms of h[t]  (one wave per node, single float4 load)
// ---------------------------------------------------------------------------
__global__ __launch_bounds__(256) void norms_kernel(const float* __restrict__ h,
                                                    float* __restrict__ norms,
                                                    int t_base) {
    int gw   = (int)((blockIdx.x * blockDim.x + threadIdx.x) >> 6);
    int lane = threadIdx.x & 63;
    int n    = gw & (NN - 1);
    int tloc = gw >> 11;
    const float4* row = (const float4*)(h + ((size_t)(t_base + tloc) * NN + n) * IND);
    float4 v = row[lane];
    float s = v.x * v.x + v.y * v.y + v.z * v.z + v.w * v.w;
#pragma unroll
    for (int off = 32; off > 0; off >>= 1) s += __shfl_xor(s, off);
    if (lane == 0) norms[(size_t)tloc * NN + n] = sqrtf(s);
}

// ---------------------------------------------------------------------------
// K2: input attention. 2 waves per (t,n); rows in VGPRs (keep-alive),
// scalar SGPR row bases. Output: bf16 hi/lo pair (feeds MFMA GEMM).
// ---------------------------------------------------------------------------
__global__ __launch_bounds__(256, 5) void input_attn_kernel(const float* __restrict__ h,
                                                            const int* __restrict__ neigh,
                                                            const float* __restrict__ norms,
                                                            __hip_bfloat16* __restrict__ ihHi,
                                                            __hip_bfloat16* __restrict__ ihLo,
                                                            int t_base) {
    const int BR[32] = BITREV5_INIT;
    __shared__ float hd_s[2][2][32];
    int wave    = threadIdx.x >> 6;   // 0..3
    int nodeloc = wave >> 1;          // 0..1
    int half    = wave & 1;           // which 128-dim half
    int lane    = threadIdx.x & 63;
    int gw   = (int)((blockIdx.x << 1) | nodeloc);
    int n    = gw & (NN - 1);
    int tloc = gw >> 11;
    const float* hT  = h + (size_t)(t_base + tloc) * NN * IND;
    const float* nrm = norms + (size_t)tloc * NN;

    const float* dst = hT + (size_t)n * IND + half * 128;
    float d0 = dst[lane], d1 = dst[lane + 64];

    int   jreg = neigh[n * KN + (lane & 31)];
    float nj   = nrm[jreg];
    float ndst = nrm[n];

    float r0[32], r1[32], comb[16];
#pragma unroll
    for (int i = 0; i < 16; ++i) {
        int sja = __builtin_amdgcn_readlane(jreg, BR[i]);
        int sjb = __builtin_amdgcn_readlane(jreg, BR[i + 16]);
        const float* sa = hT + (size_t)sja * IND + half * 128;
        const float* sb = hT + (size_t)sjb * IND + half * 128;
        r0[i]      = sa[lane]; r1[i]      = sa[lane + 64];
        r0[i + 16] = sb[lane]; r1[i + 16] = sb[lane + 64];
        float pa = r0[i] * d0 + r1[i] * d1;
        float pb = r0[i + 16] * d0 + r1[i + 16] * d1;
        float send = (lane & 1) ? pa : pb;
        float keep = (lane & 1) ? pb : pa;
        comb[i] = keep + __shfl_xor(send, 1);
    }
#pragma unroll
    for (int i = 0; i < 32; ++i) asm volatile("" : "+v"(r0[i]), "+v"(r1[i]));
    float hdot = xpose_reduce16(comb, lane);   // half-dot of neighbor (lane&31)
    if (lane < 32) hd_s[nodeloc][half][lane] = hdot;
    __syncthreads();
    float dot = hdot + hd_s[nodeloc][half ^ 1][lane & 31];

    float r  = dot / (nj * ndst);
    float r2 = r * r;
    float e  = r2 * r2;

    float a0 = 0.f, a1 = 0.f;
#pragma unroll
    for (int i = 0; i < 32; ++i) {
        float ek = bcast_lane(e, BR[i]);
        a0 += ek * r0[i];
        a1 += ek * r1[i];
    }
    size_t base = (size_t)gw * IND + half * 128;
    __hip_bfloat16 hi, lo;
    bf16_split(a0, &hi, &lo);
    ihHi[base + lane] = hi;       ihLo[base + lane] = lo;
    bf16_split(a1, &hi, &lo);
    ihHi[base + lane + 64] = hi;  ihLo[base + lane + 64] = lo;
}

// ---------------------------------------------------------------------------
// MFMA GEMM, bf16x3 error-compensated split, LDS-staged, 128x128 tile.
// A: [M][K] bf16 pairs. BT: [N][K] bf16 pairs. C: fp32.
// BM=BN=128, BK=32, 256 thr = 4 waves in 2x2; each wave owns 64x64
// (4x4 fragments of 16x16). LDS rows padded to 40 shorts (80 B -> 2-way
// bank aliasing, free per m136). Fragment mapping identical to verified
// 64^2 version (only row bases changed).
// ---------------------------------------------------------------------------
__global__ __launch_bounds__(256) void gemm_bf16x3(const __hip_bfloat16* __restrict__ Ahi,
                                                   const __hip_bfloat16* __restrict__ Alo,
                                                   const __hip_bfloat16* __restrict__ BThi,
                                                   const __hip_bfloat16* __restrict__ BTlo,
                                                   float* __restrict__ C,
                                                   int M, int N, int K) {
    __shared__ short Ah[128][40], Al[128][40], Bh[128][40], Bl[128][40];
    int tid  = threadIdx.x;
    int lane = tid & 63;
    int w    = tid >> 6;
    int wr   = (w >> 1) * 64;    // wave row base within tile
    int wc   = (w & 1) * 64;     // wave col base within tile
    int mb   = blockIdx.y * 128;
    int n0   = blockIdx.x * 128;
    int r    = lane & 15;        // row within fragment
    int g    = lane >> 4;        // k-group: k = g*8 .. g*8+7

    f32x4v acc[4][4] = {};
    for (int k0 = 0; k0 < K; k0 += 32) {
        __syncthreads();
        // stage 128x32 tiles of all four matrices (2 slots per thread each)
#pragma unroll
        for (int sl = 0; sl < 2; ++sl) {
            int s   = tid + sl * 256;     // 0..511
            int row = s >> 2;             // 0..127
            int seg = s & 3;              // 0..3 (8 bf16 each)
            size_t ga = (size_t)(mb + row) * K + k0 + seg * 8;
            size_t gb = (size_t)(n0 + row) * K + k0 + seg * 8;
            *(bf16x8v*)&Ah[row][seg * 8] = *(const bf16x8v*)(Ahi + ga);
            *(bf16x8v*)&Al[row][seg * 8] = *(const bf16x8v*)(Alo + ga);
            *(bf16x8v*)&Bh[row][seg * 8] = *(const bf16x8v*)(BThi + gb);
            *(bf16x8v*)&Bl[row][seg * 8] = *(const bf16x8v*)(BTlo + gb);
        }
        __syncthreads();
        bf16x8v ah[4], al[4];
#pragma unroll
        for (int m = 0; m < 4; ++m) {
            ah[m] = *(const bf16x8v*)&Ah[wr + m * 16 + r][g * 8];
            al[m] = *(const bf16x8v*)&Al[wr + m * 16 + r][g * 8];
        }
#pragma unroll
        for (int nt = 0; nt < 4; ++nt) {
            bf16x8v bh = *(const bf16x8v*)&Bh[wc + nt * 16 + r][g * 8];
            bf16x8v bl = *(const bf16x8v*)&Bl[wc + nt * 16 + r][g * 8];
#pragma unroll
            for (int m = 0; m < 4; ++m) {
                acc[m][nt] = __builtin_amdgcn_mfma_f32_16x16x32_bf16(ah[m], bh, acc[m][nt], 0, 0, 0);
                acc[m][nt] = __builtin_amdgcn_mfma_f32_16x16x32_bf16(ah[m], bl, acc[m][nt], 0, 0, 0);
                acc[m][nt] = __builtin_amdgcn_mfma_f32_16x16x32_bf16(al[m], bh, acc[m][nt], 0, 0, 0);
            }
        }
    }
    // C/D layout: col = lane&15, row = (lane>>4)*4 + reg   [m89-verified]
#pragma unroll
    for (int m = 0; m < 4; ++m)
#pragma unroll
        for (int nt = 0; nt < 4; ++nt)
#pragma unroll
            for (int q = 0; q < 4; ++q)
                C[(size_t)(mb + wr + m * 16 + g * 4 + q) * N + n0 + wc + nt * 16 + r] = acc[m][nt][q];
}

// ---------------------------------------------------------------------------
// K4: 3-head GAT + relu. One block (192 thr, wave=head) per (t,n).
// ---------------------------------------------------------------------------
__global__ __launch_bounds__(192, 5) void gat_heads_kernel(const float* __restrict__ z1,
                                                           const int* __restrict__ neigh,
                                                           __hip_bfloat16* __restrict__ cHi,
                                                           __hip_bfloat16* __restrict__ cLo) {
    const int BR[32] = BITREV5_INIT;
    int n    = blockIdx.x & (NN - 1);
    const float* ztbl = z1 + (size_t)(blockIdx.x >> 11) * NN * C1D;
    int head = threadIdx.x >> 6;
    int lane = threadIdx.x & 63;

    const float* dst = ztbl + (size_t)n * C1D + head * H1D;
    float d0 = dst[lane], d1 = dst[lane + 64];
    int jreg = neigh[n * KN + (lane & 31)];

    float r0[32], r1[32], comb[16];
#pragma unroll
    for (int i = 0; i < 16; ++i) {
        int sja = __builtin_amdgcn_readlane(jreg, BR[i]);
        int sjb = __builtin_amdgcn_readlane(jreg, BR[i + 16]);
        const float* sa = ztbl + (size_t)sja * C1D + head * H1D;
        const float* sb = ztbl + (size_t)sjb * C1D + head * H1D;
        r0[i]      = sa[lane]; r1[i]      = sa[lane + 64];
        r0[i + 16] = sb[lane]; r1[i + 16] = sb[lane + 64];
        float pa = r0[i] * d0 + r1[i] * d1;
        float pb = r0[i + 16] * d0 + r1[i + 16] * d1;
        float send = (lane & 1) ? pa : pb;
        float keep = (lane & 1) ? pb : pa;
        comb[i] = keep + __shfl_xor(send, 1);
    }
#pragma unroll
    for (int i = 0; i < 32; ++i) asm volatile("" : "+v"(r0[i]), "+v"(r1[i]));
    float dot = xpose_reduce16(comb, lane);

    float m = dot;
#pragma unroll
    for (int off = 16; off > 0; off >>= 1) m = fmaxf(m, __shfl_xor(m, off));
    float p = __expf(dot - m);
    float s = p;
#pragma unroll
    for (int off = 16; off > 0; off >>= 1) s += __shfl_xor(s, off);
    p /= s;

    float a0 = 0.f, a1 = 0.f;
#pragma unroll
    for (int i = 0; i < 32; ++i) {
        float pk = bcast_lane(p, BR[i]);
        a0 += pk * r0[i];
        a1 += pk * r1[i];
    }
    size_t base = (size_t)blockIdx.x * C1D + (size_t)head * H1D;
    __hip_bfloat16 hi, lo;
    bf16_split(fmaxf(a0, 0.f), &hi, &lo);
    cHi[base + lane] = hi;       cLo[base + lane] = lo;
    bf16_split(fmaxf(a1, 0.f), &hi, &lo);
    cHi[base + lane + 64] = hi;  cLo[base + lane + 64] = lo;
}

// ---------------------------------------------------------------------------
// K7: final GAT on z2 (d=128) + relu + FUSED partial max-pool.
// ---------------------------------------------------------------------------
__global__ __launch_bounds__(256, 5) void gat_final_kernel(const float* __restrict__ z2,
                                                           const int* __restrict__ neigh,
                                                           float* __restrict__ ppart) {
    const int BR[32] = BITREV5_INIT;
    __shared__ float red_s[4][128];
    int wave = threadIdx.x >> 6;
    int gw   = (int)((blockIdx.x << 2) | wave);
    int n    = gw & (NN - 1);
    const float* ztbl = z2 + (size_t)(gw >> 11) * NN * H2D;
    int lane = threadIdx.x & 63;

    const float* dst = ztbl + (size_t)n * H2D;
    float d0 = dst[lane], d1 = dst[lane + 64];
    int jreg = neigh[n * KN + (lane & 31)];

    float r0[32], r1[32], comb[16];
#pragma unroll
    for (int i = 0; i < 16; ++i) {
        int sja = __builtin_amdgcn_readlane(jreg, BR[i]);
        int sjb = __builtin_amdgcn_readlane(jreg, BR[i + 16]);
        const float* sa = ztbl + (size_t)sja * H2D;
        const float* sb = ztbl + (size_t)sjb * H2D;
        r0[i]      = sa[lane]; r1[i]      = sa[lane + 64];
        r0[i + 16] = sb[lane]; r1[i + 16] = sb[lane + 64];
        float pa = r0[i] * d0 + r1[i] * d1;
        float pb = r0[i + 16] * d0 + r1[i + 16] * d1;
        float send = (lane & 1) ? pa : pb;
        float keep = (lane & 1) ? pb : pa;
        comb[i] = keep + __shfl_xor(send, 1);
    }
#pragma unroll
    for (int i = 0; i < 32; ++i) asm volatile("" : "+v"(r0[i]), "+v"(r1[i]));
    float dot = xpose_reduce16(comb, lane);

    float m = dot;
#pragma unroll
    for (int off = 16; off > 0; off >>= 1) m = fmaxf(m, __shfl_xor(m, off));
    float p = __expf(dot - m);
    float s = p;
#pragma unroll
    for (int off = 16; off > 0; off >>= 1) s += __shfl_xor(s, off);
    p /= s;

    float a0 = 0.f, a1 = 0.f;
#pragma unroll
    for (int i = 0; i < 32; ++i) {
        float pk = bcast_lane(p, BR[i]);
        a0 += pk * r0[i];
        a1 += pk * r1[i];
    }
    red_s[wave][lane]      = fmaxf(a0, 0.f);
    red_s[wave][lane + 64] = fmaxf(a1, 0.f);
    __syncthreads();
    int tid = threadIdx.x;
    if (tid < 128) {
        float mx = fmaxf(fmaxf(red_s[0][tid], red_s[1][tid]),
                         fmaxf(red_s[2][tid], red_s[3][tid]));
        ppart[(size_t)blockIdx.x * H2D + tid] = mx;
    }
}

// ---------------------------------------------------------------------------
// K8: pooled[t][j] = max over NN/4 = 512 block-partials
// ---------------------------------------------------------------------------
__global__ __launch_bounds__(128) void pool_reduce_kernel(const float* __restrict__ ppart,
                                                          float* __restrict__ pooled,
                                                          int t_base) {
    int j = threadIdx.x;
    const float* base = ppart + (size_t)blockIdx.x * 512 * H2D;
    float mx = 0.f;
#pragma unroll 8
    for (int q = 0; q < 512; ++q) mx = fmaxf(mx, base[(size_t)q * H2D + j]);
    pooled[(t_base + blockIdx.x) * H2D + j] = mx;
}

// ---------------------------------------------------------------------------
// prep: weights -> transposed bf16 hi/lo pairs; zero GRU step flags.
// ---------------------------------------------------------------------------
__global__ void prep_kernel(const float* __restrict__ fc1, const float* __restrict__ fc2,
                            __hip_bfloat16* __restrict__ W1Thi, __hip_bfloat16* __restrict__ W1Tlo,
                            __hip_bfloat16* __restrict__ f2Thi, __hip_bfloat16* __restrict__ f2Tlo,
                            unsigned int* __restrict__ flags) {
    int i = blockIdx.x * 256 + threadIdx.x;
    if (i < 384 * 256) {
        int cf = i / 256, d = i % 256;
        int hd = cf >> 7, j = cf & 127;
        float v = fc1[(size_t)hd * 256 * 128 + (size_t)d * 128 + j];
        __hip_bfloat16 hi, lo;
        bf16_split(v, &hi, &lo);
        W1Thi[i] = hi; W1Tlo[i] = lo;
    }
    if (i < 128 * 384) {
        int n = i / 384, k = i % 384;
        float v = fc2[(size_t)k * 128 + n];
        __hip_bfloat16 hi, lo;
        bf16_split(v, &hi, &lo);
        f2Thi[i] = hi; f2Tlo[i] = lo;
    }
    if (i < T_STEPS * GRU_NB) flags[i] = 0u;
}

// ---------------------------------------------------------------------------
// gi_all[t][o] = Wih[o,:] . pooled[t,:] + bih[o]   (parallel over t)
// ---------------------------------------------------------------------------
__global__ __launch_bounds__(256) void gi_all_kernel(const float* __restrict__ Wih,
                                                     const float* __restrict__ bih,
                                                     const float* __restrict__ pooled,
                                                     float* __restrict__ gi_all) {
    __shared__ float p_s[H2D];
    int t  = blockIdx.x / 3;
    int ob = (blockIdx.x % 3) * 256;
    if (threadIdx.x < H2D) p_s[threadIdx.x] = pooled[t * H2D + threadIdx.x];
    __syncthreads();
    int o = ob + threadIdx.x;
    float acc = bih[o];
    const float* wr = Wih + (size_t)o * H2D;
#pragma unroll 4
    for (int d = 0; d < H2D; ++d) acc += wr[d] * p_s[d];
    gi_all[t * 768 + o] = acc;
}

// ---------------------------------------------------------------------------
// GRU: 8 cooperating blocks, Whh register-resident, per-block flag sync.
// ---------------------------------------------------------------------------
__global__ __launch_bounds__(768) void gru_reg_kernel(const float* __restrict__ Whh,
                                                      const float* __restrict__ bhh,
                                                      const float* __restrict__ gi_all,
                                                      const float* __restrict__ hx0,
                                                      float* hx_all,
                                                      unsigned int* flags) {
    __shared__ float4 hx_pad[72];                 // padded: idx (g,i) -> g*9+i
    __shared__ __align__(16) float hx_lin[GD];    // linear copy for hx_old
    __shared__ float gh_s[96];
    int b   = blockIdx.x;
    int tid = threadIdx.x;
    int row_local = tid >> 3;      // 0..95
    int sub       = tid & 7;       // 0..7
    int chunk     = row_local >> 5;
    int r_in      = row_local & 31;
    int grow      = chunk * GD + b * 32 + r_in;

    float4 wreg[8];
    const float4* wrow = (const float4*)(Whh + (size_t)grow * GD + sub * 32);
#pragma unroll
    for (int i = 0; i < 8; ++i) wreg[i] = wrow[i];
    float bias = (sub == 0) ? bhh[grow] : 0.f;
    int u = b * 32 + tid;          // hidden unit owned by tid<32

    for (int t = 0; t < T_STEPS; ++t) {
        float gi_r = 0.f, gi_z = 0.f, gi_n = 0.f;
        if (tid < 32) {
            gi_r = gi_all[t * 768 + u];
            gi_z = gi_all[t * 768 + 256 + u];
            gi_n = gi_all[t * 768 + 512 + u];
        }
        if (t > 0) {
            if (tid < GRU_NB) {
                while (__hip_atomic_load(&flags[(t - 1) * GRU_NB + tid],
                                         __ATOMIC_ACQUIRE,
                                         __HIP_MEMORY_SCOPE_AGENT) == 0u)
                    __builtin_amdgcn_s_sleep(1);
            }
            __syncthreads();
        }
        const float* hsrc = (t == 0) ? hx0 : (hx_all + (size_t)(t - 1) * GD);
        if (tid < 64) {
            float4 v;
            v.x = __hip_atomic_load(hsrc + tid * 4 + 0, __ATOMIC_RELAXED, __HIP_MEMORY_SCOPE_AGENT);
            v.y = __hip_atomic_load(hsrc + tid * 4 + 1, __ATOMIC_RELAXED, __HIP_MEMORY_SCOPE_AGENT);
            v.z = __hip_atomic_load(hsrc + tid * 4 + 2, __ATOMIC_RELAXED, __HIP_MEMORY_SCOPE_AGENT);
            v.w = __hip_atomic_load(hsrc + tid * 4 + 3, __ATOMIC_RELAXED, __HIP_MEMORY_SCOPE_AGENT);
            hx_pad[(tid >> 3) * 9 + (tid & 7)] = v;
            ((float4*)hx_lin)[tid] = v;
        }
        __syncthreads();

        float acc = 0.f;
#pragma unroll
        for (int i = 0; i < 8; ++i) {
            float4 hv = hx_pad[sub * 9 + i];
            float4 wv = wreg[i];
            acc += wv.x * hv.x + wv.y * hv.y + wv.z * hv.z + wv.w * hv.w;
        }
        acc += __shfl_xor(acc, 1);
        acc += __shfl_xor(acc, 2);
        acc += __shfl_xor(acc, 4);
        if (sub == 0) gh_s[row_local] = acc + bias;
        __syncthreads();

        if (tid < 32) {
            float r  = 1.f / (1.f + expf(-(gi_r + gh_s[tid])));
            float zg = 1.f / (1.f + expf(-(gi_z + gh_s[32 + tid])));
            float nn = tanhf(gi_n + r * gh_s[64 + tid]);
            float hnew = (1.f - zg) * nn + zg * hx_lin[u];
            __hip_atomic_store(&hx_all[(size_t)t * GD + u], hnew,
                               __ATOMIC_RELAXED, __HIP_MEMORY_SCOPE_AGENT);
        }
        __syncthreads();
        if (tid == 0)
            __hip_atomic_store(&flags[t * GRU_NB + b], 1u,
                               __ATOMIC_RELEASE, __HIP_MEMORY_SCOPE_AGENT);
    }
}

// ---------------------------------------------------------------------------
// res heads + SIR scan. One block per t.
// ---------------------------------------------------------------------------
__global__ __launch_bounds__(128) void res_sir_kernel(const float* __restrict__ hx_all,
                                                      const float* __restrict__ It,
                                                      const float* __restrict__ Rt,
                                                      const float* __restrict__ r1W,
                                                      const float* __restrict__ r1b,
                                                      const float* __restrict__ r2W,
                                                      const float* __restrict__ r2b,
                                                      const float* __restrict__ I,
                                                      const float* __restrict__ R,
                                                      const float* __restrict__ S,
                                                      const float* __restrict__ Npop,
                                                      float* __restrict__ out) {
    __shared__ float nhx[258];
    __shared__ float ab_s[2];
    int t = blockIdx.x, tid = threadIdx.x;
    for (int i = tid; i < GD; i += 128) nhx[i] = hx_all[t * GD + i];
    if (tid == 0) { nhx[256] = It[t]; nhx[257] = Rt[t]; }
    __syncthreads();
    if (tid < 120) {
        float acc = r1b[tid];
        const float* wr = r1W + tid * 258;
        for (int d = 0; d < 258; ++d) acc += wr[d] * nhx[d];
        int idx = t * 60 + (tid >> 1);
        if (tid & 1) out[3840 + idx] = acc;
        else         out[idx] = acc;
    }
    if (tid == 120 || tid == 121) {
        int q = tid - 120;
        float acc = r2b[q];
        const float* wr = r2W + q * 258;
        for (int d = 0; d < 258; ++d) acc += wr[d] * nhx[d];
        ab_s[q] = acc;
    }
    __syncthreads();
    if (tid == 0) {
        float a_s = 1.f / (1.f + expf(-ab_s[0]));
        float b_s = 1.f / (1.f + expf(-ab_s[1]));
        float Np = Npop[0];
        float lI = I[t], lR = R[t], lS = S[t];
        for (int p = 0; p < PD; ++p) {
            float dI = a_s * lI * (lS / Np) - b_s * lI;
            float dR = b_s * lI;
            lI += dI;
            lR += dR;
            lS = Np - lI - lR;
            out[7680  + t * 60 + p] = dI;
            out[11520 + t * 60 + p] = dR;
        }
    }
}

// ---------------------------------------------------------------------------
extern "C" void kernel_launch(void* const* d_in, const int* in_sizes, int n_in,
                              void* d_out, int out_size, void* d_ws, size_t ws_size,
                              hipStream_t stream) {
    const float* h    = (const float*)d_in[0];
    const int*   ng   = (const int*)  d_in[1];
    const float* Npop = (const float*)d_in[2];
    const float* I_   = (const float*)d_in[3];
    const float* R_   = (const float*)d_in[4];
    const float* S_   = (const float*)d_in[5];
    const float* It   = (const float*)d_in[6];
    const float* Rt   = (const float*)d_in[7];
    const float* fc1  = (const float*)d_in[8];
    const float* fc2  = (const float*)d_in[9];
    const float* gWih = (const float*)d_in[10];
    const float* gWhh = (const float*)d_in[11];
    const float* gbih = (const float*)d_in[12];
    const float* gbhh = (const float*)d_in[13];
    const float* r1W  = (const float*)d_in[14];
    const float* r1b  = (const float*)d_in[15];
    const float* r2W  = (const float*)d_in[16];
    const float* r2b  = (const float*)d_in[17];
    const float* hx0  = (const float*)d_in[18];
    float* out = (float*)d_out;

    // ---- workspace carve-up (all region sizes 16B-aligned) ----
    char* w = (char*)d_ws;
    float* pooled = (float*)w; w += (size_t)T_STEPS * H2D * 4;      // 32 KB
    float* hx_all = (float*)w; w += (size_t)T_STEPS * GD * 4;       // 64 KB
    float* gi_all = (float*)w; w += (size_t)T_STEPS * 768 * 4;      // 192 KB
    float* ppart  = (float*)w; w += (size_t)16 * 512 * H2D * 4;     // 4 MB (Tc<=16)
    __hip_bfloat16* W1Thi = (__hip_bfloat16*)w; w += (size_t)384 * 256 * 2; // 192 KB
    __hip_bfloat16* W1Tlo = (__hip_bfloat16*)w; w += (size_t)384 * 256 * 2;
    __hip_bfloat16* f2Thi = (__hip_bfloat16*)w; w += (size_t)128 * 384 * 2; // 96 KB
    __hip_bfloat16* f2Tlo = (__hip_bfloat16*)w; w += (size_t)128 * 384 * 2;
    unsigned int* flags = (unsigned int*)w; w += (size_t)T_STEPS * GRU_NB * 4; // 2 KB
    size_t fixed = (size_t)(w - (char*)d_ws);

    // per-Tc bytes: norms 8KB + pairA 2MB (ihHi/ihLo; later z2) +
    //               z1 3MB + pairC 3MB (cHi/cLo)
    const size_t perTc = 8192 + 2097152 + 3145728 + 3145728;
    int Tc = 16;
    while (Tc > 1) {
        if (fixed + (size_t)Tc * perTc <= ws_size) break;
        Tc >>= 1;
    }
    float* norms = (float*)w;             w += (size_t)Tc * NN * 4;
    char*  pairA = w;                     w += (size_t)Tc * NN * 256 * 2 * 2;
    float* z1    = (float*)w;             w += (size_t)Tc * NN * C1D * 4;
    __hip_bfloat16* cHi = (__hip_bfloat16*)w; w += (size_t)Tc * NN * C1D * 2;
    __hip_bfloat16* cLo = (__hip_bfloat16*)w;

    __hip_bfloat16* ihHi = (__hip_bfloat16*)pairA;
    __hip_bfloat16* ihLo = ihHi + (size_t)Tc * NN * 256;
    // z2 overlays pairA after GEMM1 consumed ihHi/ihLo
    float* z2 = (float*)pairA;

    prep_kernel<<<(384 * 256 + 255) / 256, 256, 0, stream>>>(fc1, fc2, W1Thi, W1Tlo,
                                                             f2Thi, f2Tlo, flags);

    for (int t0 = 0; t0 < T_STEPS; t0 += Tc) {
        int M = Tc * NN;
        norms_kernel      <<<Tc * NN / 4, 256, 0, stream>>>(h, norms, t0);
        input_attn_kernel <<<Tc * NN / 2, 256, 0, stream>>>(h, ng, norms, ihHi, ihLo, t0);
        // z1 = ih @ W1  (M x 256) @ (256 x 384), bf16x3 MFMA, 128^2 tile
        gemm_bf16x3<<<dim3(384 / 128, M / 128), 256, 0, stream>>>(ihHi, ihLo, W1Thi, W1Tlo,
                                                                  z1, M, 384, 256);
        gat_heads_kernel  <<<Tc * NN, 192, 0, stream>>>(z1, ng, cHi, cLo);
        // z2 = c @ fc2  (M x 384) @ (384 x 128), bf16x3 MFMA, 128^2 tile
        gemm_bf16x3<<<dim3(128 / 128, M / 128), 256, 0, stream>>>(cHi, cLo, f2Thi, f2Tlo,
                                                                  z2, M, 128, 384);
        gat_final_kernel  <<<Tc * NN / 4, 256, 0, stream>>>(z2, ng, ppart);
        pool_reduce_kernel<<<Tc, 128, 0, stream>>>(ppart, pooled, t0);
    }

    gi_all_kernel<<<T_STEPS * 3, 256, 0, stream>>>(gWih, gbih, pooled, gi_all);
    gru_reg_kernel<<<GRU_NB, 768, 0, stream>>>(gWhh, gbhh, gi_all, hx0, hx_all, flags);
    res_sir_kernel<<<T_STEPS, 128, 0, stream>>>(hx_all, It, Rt, r1W, r1b, r2W, r2b,
                                                I_, R_, S_, Npop, out);
}

// Round 19
// 1438.602 us; speedup vs baseline: 1.2354x; 1.0012x over previous
//
#include <hip/hip_runtime.h>
#include <hip/hip_bf16.h>
#include <math.h>

// Problem constants
#define T_STEPS 64
#define NN      2048
#define KN      32
#define IND     256
#define H1D     128
#define C1D     384   // HEADS*H1
#define H2D     128
#define GD      256
#define PD      60
#define GRU_NB  8     // cooperating blocks for the GRU

typedef __attribute__((ext_vector_type(8))) short bf16x8v;  // 8 bf16 = 4 VGPR
typedef __attribute__((ext_vector_type(4))) float f32x4v;

// bit-reversed 5-bit order (involution)
#define BITREV5_INIT {0,16,8,24,4,20,12,28,2,18,10,26,6,22,14,30, \
                      1,17,9,25,5,21,13,29,3,19,11,27,7,23,15,31}

__device__ __forceinline__ float bcast_lane(float v, int lane_imm) {
    return __uint_as_float(__builtin_amdgcn_readlane(__float_as_uint(v), lane_imm));
}

__device__ __forceinline__ void bf16_split(float v, __hip_bfloat16* hi, __hip_bfloat16* lo) {
    __hip_bfloat16 h = __float2bfloat16(v);
    *hi = h;
    *lo = __float2bfloat16(v - __bfloat162float(h));
}

// Butterfly stages 2..6 on 16 stage-1-combined partials.
__device__ __forceinline__ float xpose_reduce16(float part[16], int lane) {
#pragma unroll
    for (int i = 0; i < 8; ++i) {
        float send = (lane & 2) ? part[i] : part[i + 8];
        float keep = (lane & 2) ? part[i + 8] : part[i];
        part[i] = keep + __shfl_xor(send, 2);
    }
#pragma unroll
    for (int i = 0; i < 4; ++i) {
        float send = (lane & 4) ? part[i] : part[i + 4];
        float keep = (lane & 4) ? part[i + 4] : part[i];
        part[i] = keep + __shfl_xor(send, 4);
    }
#pragma unroll
    for (int i = 0; i < 2; ++i) {
        float send = (lane & 8) ? part[i] : part[i + 2];
        float keep = (lane & 8) ? part[i + 2] : part[i];
        part[i] = keep + __shfl_xor(send, 8);
    }
    {
        float send = (lane & 16) ? part[0] : part[1];
        float keep = (lane & 16) ? part[1] : part[0];
        part[0] = keep + __shfl_xor(send, 16);
    }
    return part[0] + __shfl_xor(part[0], 32);
}

// ---------------------------------------------------------------------------
// K1: row norms of h[t]  (one wave per node, single float4 load)
// ---------------------------------------------------------------------------
__global__ __launch_bounds__(256) void norms_kernel(const float* __restrict__ h,
                                                    float* __restrict__ norms,
                                                    int t_base) {
    int gw   = (int)((blockIdx.x * blockDim.x + threadIdx.x) >> 6);
    int lane = threadIdx.x & 63;
    int n    = gw & (NN - 1);
    int tloc = gw >> 11;
    const float4* row = (const float4*)(h + ((size_t)(t_base + tloc) * NN + n) * IND);
    float4 v = row[lane];
    float s = v.x * v.x + v.y * v.y + v.z * v.z + v.w * v.w;
#pragma unroll
    for (int off = 32; off > 0; off >>= 1) s += __shfl_xor(s, off);
    if (lane == 0) norms[(size_t)tloc * NN + n] = sqrtf(s);
}

// ---------------------------------------------------------------------------
// K2: input attention. 2 waves per (t,n); rows in VGPRs (keep-alive),
// scalar SGPR row bases. Output: bf16 hi/lo pair (feeds MFMA GEMM).
// ---------------------------------------------------------------------------
__global__ __launch_bounds__(256, 5) void input_attn_kernel(const float* __restrict__ h,
                                                            const int* __restrict__ neigh,
                                                            const float* __restrict__ norms,
                                                            __hip_bfloat16* __restrict__ ihHi,
                                                            __hip_bfloat16* __restrict__ ihLo,
                                                            int t_base) {
    const int BR[32] = BITREV5_INIT;
    __shared__ float hd_s[2][2][32];
    int wave    = threadIdx.x >> 6;   // 0..3
    int nodeloc = wave >> 1;          // 0..1
    int half    = wave & 1;           // which 128-dim half
    int lane    = threadIdx.x & 63;
    int gw   = (int)((blockIdx.x << 1) | nodeloc);
    int n    = gw & (NN - 1);
    int tloc = gw >> 11;
    const float* hT  = h + (size_t)(t_base + tloc) * NN * IND;
    const float* nrm = norms + (size_t)tloc * NN;

    const float* dst = hT + (size_t)n * IND + half * 128;
    float d0 = dst[lane], d1 = dst[lane + 64];

    int   jreg = neigh[n * KN + (lane & 31)];
    float nj   = nrm[jreg];
    float ndst = nrm[n];

    float r0[32], r1[32], comb[16];
#pragma unroll
    for (int i = 0; i < 16; ++i) {
        int sja = __builtin_amdgcn_readlane(jreg, BR[i]);
        int sjb = __builtin_amdgcn_readlane(jreg, BR[i + 16]);
        const float* sa = hT + (size_t)sja * IND + half * 128;
        const float* sb = hT + (size_t)sjb * IND + half * 128;
        r0[i]      = sa[lane]; r1[i]      = sa[lane + 64];
        r0[i + 16] = sb[lane]; r1[i + 16] = sb[lane + 64];
        float pa = r0[i] * d0 + r1[i] * d1;
        float pb = r0[i + 16] * d0 + r1[i + 16] * d1;
        float send = (lane & 1) ? pa : pb;
        float keep = (lane & 1) ? pb : pa;
        comb[i] = keep + __shfl_xor(send, 1);
    }
#pragma unroll
    for (int i = 0; i < 32; ++i) asm volatile("" : "+v"(r0[i]), "+v"(r1[i]));
    float hdot = xpose_reduce16(comb, lane);   // half-dot of neighbor (lane&31)
    if (lane < 32) hd_s[nodeloc][half][lane] = hdot;
    __syncthreads();
    float dot = hdot + hd_s[nodeloc][half ^ 1][lane & 31];

    float r  = dot / (nj * ndst);
    float r2 = r * r;
    float e  = r2 * r2;

    float a0 = 0.f, a1 = 0.f;
#pragma unroll
    for (int i = 0; i < 32; ++i) {
        float ek = bcast_lane(e, BR[i]);
        a0 += ek * r0[i];
        a1 += ek * r1[i];
    }
    size_t base = (size_t)gw * IND + half * 128;
    __hip_bfloat16 hi, lo;
    bf16_split(a0, &hi, &lo);
    ihHi[base + lane] = hi;       ihLo[base + lane] = lo;
    bf16_split(a1, &hi, &lo);
    ihHi[base + lane + 64] = hi;  ihLo[base + lane + 64] = lo;
}

// ---------------------------------------------------------------------------
// MFMA GEMM, bf16x3 error-compensated split, LDS-staged, 128x128 tile.
// A: [M][K] bf16 pairs. BT: [N][K] bf16 pairs. C: fp32.
// BM=BN=128, BK=32, 256 thr = 4 waves in 2x2; each wave owns 64x64
// (4x4 fragments of 16x16). LDS rows padded to 40 shorts (80 B -> 2-way
// bank aliasing, free per m136). Fragment mapping identical to verified
// 64^2 version (only row bases changed).
// ---------------------------------------------------------------------------
__global__ __launch_bounds__(256) void gemm_bf16x3(const __hip_bfloat16* __restrict__ Ahi,
                                                   const __hip_bfloat16* __restrict__ Alo,
                                                   const __hip_bfloat16* __restrict__ BThi,
                                                   const __hip_bfloat16* __restrict__ BTlo,
                                                   float* __restrict__ C,
                                                   int M, int N, int K) {
    __shared__ short Ah[128][40], Al[128][40], Bh[128][40], Bl[128][40];
    int tid  = threadIdx.x;
    int lane = tid & 63;
    int w    = tid >> 6;
    int wr   = (w >> 1) * 64;    // wave row base within tile
    int wc   = (w & 1) * 64;     // wave col base within tile
    int mb   = blockIdx.y * 128;
    int n0   = blockIdx.x * 128;
    int r    = lane & 15;        // row within fragment
    int g    = lane >> 4;        // k-group: k = g*8 .. g*8+7

    f32x4v acc[4][4] = {};
    for (int k0 = 0; k0 < K; k0 += 32) {
        __syncthreads();
        // stage 128x32 tiles of all four matrices (2 slots per thread each)
#pragma unroll
        for (int sl = 0; sl < 2; ++sl) {
            int s   = tid + sl * 256;     // 0..511
            int row = s >> 2;             // 0..127
            int seg = s & 3;              // 0..3 (8 bf16 each)
            size_t ga = (size_t)(mb + row) * K + k0 + seg * 8;
            size_t gb = (size_t)(n0 + row) * K + k0 + seg * 8;
            *(bf16x8v*)&Ah[row][seg * 8] = *(const bf16x8v*)(Ahi + ga);
            *(bf16x8v*)&Al[row][seg * 8] = *(const bf16x8v*)(Alo + ga);
            *(bf16x8v*)&Bh[row][seg * 8] = *(const bf16x8v*)(BThi + gb);
            *(bf16x8v*)&Bl[row][seg * 8] = *(const bf16x8v*)(BTlo + gb);
        }
        __syncthreads();
        bf16x8v ah[4], al[4];
#pragma unroll
        for (int m = 0; m < 4; ++m) {
            ah[m] = *(const bf16x8v*)&Ah[wr + m * 16 + r][g * 8];
            al[m] = *(const bf16x8v*)&Al[wr + m * 16 + r][g * 8];
        }
#pragma unroll
        for (int nt = 0; nt < 4; ++nt) {
            bf16x8v bh = *(const bf16x8v*)&Bh[wc + nt * 16 + r][g * 8];
            bf16x8v bl = *(const bf16x8v*)&Bl[wc + nt * 16 + r][g * 8];
#pragma unroll
            for (int m = 0; m < 4; ++m) {
                acc[m][nt] = __builtin_amdgcn_mfma_f32_16x16x32_bf16(ah[m], bh, acc[m][nt], 0, 0, 0);
                acc[m][nt] = __builtin_amdgcn_mfma_f32_16x16x32_bf16(ah[m], bl, acc[m][nt], 0, 0, 0);
                acc[m][nt] = __builtin_amdgcn_mfma_f32_16x16x32_bf16(al[m], bh, acc[m][nt], 0, 0, 0);
            }
        }
    }
    // C/D layout: col = lane&15, row = (lane>>4)*4 + reg   [m89-verified]
#pragma unroll
    for (int m = 0; m < 4; ++m)
#pragma unroll
        for (int nt = 0; nt < 4; ++nt)
#pragma unroll
            for (int q = 0; q < 4; ++q)
                C[(size_t)(mb + wr + m * 16 + g * 4 + q) * N + n0 + wc + nt * 16 + r] = acc[m][nt][q];
}

// ---------------------------------------------------------------------------
// K4: 3-head GAT + relu. One block (192 thr, wave=head) per (t,n).
// ---------------------------------------------------------------------------
__global__ __launch_bounds__(192, 5) void gat_heads_kernel(const float* __restrict__ z1,
                                                           const int* __restrict__ neigh,
                                                           __hip_bfloat16* __restrict__ cHi,
                                                           __hip_bfloat16* __restrict__ cLo) {
    const int BR[32] = BITREV5_INIT;
    int n    = blockIdx.x & (NN - 1);
    const float* ztbl = z1 + (size_t)(blockIdx.x >> 11) * NN * C1D;
    int head = threadIdx.x >> 6;
    int lane = threadIdx.x & 63;

    const float* dst = ztbl + (size_t)n * C1D + head * H1D;
    float d0 = dst[lane], d1 = dst[lane + 64];
    int jreg = neigh[n * KN + (lane & 31)];

    float r0[32], r1[32], comb[16];
#pragma unroll
    for (int i = 0; i < 16; ++i) {
        int sja = __builtin_amdgcn_readlane(jreg, BR[i]);
        int sjb = __builtin_amdgcn_readlane(jreg, BR[i + 16]);
        const float* sa = ztbl + (size_t)sja * C1D + head * H1D;
        const float* sb = ztbl + (size_t)sjb * C1D + head * H1D;
        r0[i]      = sa[lane]; r1[i]      = sa[lane + 64];
        r0[i + 16] = sb[lane]; r1[i + 16] = sb[lane + 64];
        float pa = r0[i] * d0 + r1[i] * d1;
        float pb = r0[i + 16] * d0 + r1[i + 16] * d1;
        float send = (lane & 1) ? pa : pb;
        float keep = (lane & 1) ? pb : pa;
        comb[i] = keep + __shfl_xor(send, 1);
    }
#pragma unroll
    for (int i = 0; i < 32; ++i) asm volatile("" : "+v"(r0[i]), "+v"(r1[i]));
    float dot = xpose_reduce16(comb, lane);

    float m = dot;
#pragma unroll
    for (int off = 16; off > 0; off >>= 1) m = fmaxf(m, __shfl_xor(m, off));
    float p = __expf(dot - m);
    float s = p;
#pragma unroll
    for (int off = 16; off > 0; off >>= 1) s += __shfl_xor(s, off);
    p /= s;

    float a0 = 0.f, a1 = 0.f;
#pragma unroll
    for (int i = 0; i < 32; ++i) {
        float pk = bcast_lane(p, BR[i]);
        a0 += pk * r0[i];
        a1 += pk * r1[i];
    }
    size_t base = (size_t)blockIdx.x * C1D + (size_t)head * H1D;
    __hip_bfloat16 hi, lo;
    bf16_split(fmaxf(a0, 0.f), &hi, &lo);
    cHi[base + lane] = hi;       cLo[base + lane] = lo;
    bf16_split(fmaxf(a1, 0.f), &hi, &lo);
    cHi[base + lane + 64] = hi;  cLo[base + lane + 64] = lo;
}

// ---------------------------------------------------------------------------
// K7: final GAT on z2 (d=128) + relu + FUSED partial max-pool.
// ---------------------------------------------------------------------------
__global__ __launch_bounds__(256, 5) void gat_final_kernel(const float* __restrict__ z2,
                                                           const int* __restrict__ neigh,
                                                           float* __restrict__ ppart) {
    const int BR[32] = BITREV5_INIT;
    __shared__ float red_s[4][128];
    int wave = threadIdx.x >> 6;
    int gw   = (int)((blockIdx.x << 2) | wave);
    int n    = gw & (NN - 1);
    const float* ztbl = z2 + (size_t)(gw >> 11) * NN * H2D;
    int lane = threadIdx.x & 63;

    const float* dst = ztbl + (size_t)n * H2D;
    float d0 = dst[lane], d1 = dst[lane + 64];
    int jreg = neigh[n * KN + (lane & 31)];

    float r0[32], r1[32], comb[16];
#pragma unroll
    for (int i = 0; i < 16; ++i) {
        int sja = __builtin_amdgcn_readlane(jreg, BR[i]);
        int sjb = __builtin_amdgcn_readlane(jreg, BR[i + 16]);
        const float* sa = ztbl + (size_t)sja * H2D;
        const float* sb = ztbl + (size_t)sjb * H2D;
        r0[i]      = sa[lane]; r1[i]      = sa[lane + 64];
        r0[i + 16] = sb[lane]; r1[i + 16] = sb[lane + 64];
        float pa = r0[i] * d0 + r1[i] * d1;
        float pb = r0[i + 16] * d0 + r1[i + 16] * d1;
        float send = (lane & 1) ? pa : pb;
        float keep = (lane & 1) ? pb : pa;
        comb[i] = keep + __shfl_xor(send, 1);
    }
#pragma unroll
    for (int i = 0; i < 32; ++i) asm volatile("" : "+v"(r0[i]), "+v"(r1[i]));
    float dot = xpose_reduce16(comb, lane);

    float m = dot;
#pragma unroll
    for (int off = 16; off > 0; off >>= 1) m = fmaxf(m, __shfl_xor(m, off));
    float p = __expf(dot - m);
    float s = p;
#pragma unroll
    for (int off = 16; off > 0; off >>= 1) s += __shfl_xor(s, off);
    p /= s;

    float a0 = 0.f, a1 = 0.f;
#pragma unroll
    for (int i = 0; i < 32; ++i) {
        float pk = bcast_lane(p, BR[i]);
        a0 += pk * r0[i];
        a1 += pk * r1[i];
    }
    red_s[wave][lane]      = fmaxf(a0, 0.f);
    red_s[wave][lane + 64] = fmaxf(a1, 0.f);
    __syncthreads();
    int tid = threadIdx.x;
    if (tid < 128) {
        float mx = fmaxf(fmaxf(red_s[0][tid], red_s[1][tid]),
                         fmaxf(red_s[2][tid], red_s[3][tid]));
        ppart[(size_t)blockIdx.x * H2D + tid] = mx;
    }
}

// ---------------------------------------------------------------------------
// K8: pooled[t][j] = max over NN/4 = 512 block-partials
// ---------------------------------------------------------------------------
__global__ __launch_bounds__(128) void pool_reduce_kernel(const float* __restrict__ ppart,
                                                          float* __restrict__ pooled,
                                                          int t_base) {
    int j = threadIdx.x;
    const float* base = ppart + (size_t)blockIdx.x * 512 * H2D;
    float mx = 0.f;
#pragma unroll 8
    for (int q = 0; q < 512; ++q) mx = fmaxf(mx, base[(size_t)q * H2D + j]);
    pooled[(t_base + blockIdx.x) * H2D + j] = mx;
}

// ---------------------------------------------------------------------------
// prep: weights -> transposed bf16 hi/lo pairs; zero GRU step flags.
// ---------------------------------------------------------------------------
__global__ void prep_kernel(const float* __restrict__ fc1, const float* __restrict__ fc2,
                            __hip_bfloat16* __restrict__ W1Thi, __hip_bfloat16* __restrict__ W1Tlo,
                            __hip_bfloat16* __restrict__ f2Thi, __hip_bfloat16* __restrict__ f2Tlo,
                            unsigned int* __restrict__ flags) {
    int i = blockIdx.x * 256 + threadIdx.x;
    if (i < 384 * 256) {
        int cf = i / 256, d = i % 256;
        int hd = cf >> 7, j = cf & 127;
        float v = fc1[(size_t)hd * 256 * 128 + (size_t)d * 128 + j];
        __hip_bfloat16 hi, lo;
        bf16_split(v, &hi, &lo);
        W1Thi[i] = hi; W1Tlo[i] = lo;
    }
    if (i < 128 * 384) {
        int n = i / 384, k = i % 384;
        float v = fc2[(size_t)k * 128 + n];
        __hip_bfloat16 hi, lo;
        bf16_split(v, &hi, &lo);
        f2Thi[i] = hi; f2Tlo[i] = lo;
    }
    if (i < T_STEPS * GRU_NB) flags[i] = 0u;
}

// ---------------------------------------------------------------------------
// gi_all[t][o] = Wih[o,:] . pooled[t,:] + bih[o]   (parallel over t)
// ---------------------------------------------------------------------------
__global__ __launch_bounds__(256) void gi_all_kernel(const float* __restrict__ Wih,
                                                     const float* __restrict__ bih,
                                                     const float* __restrict__ pooled,
                                                     float* __restrict__ gi_all) {
    __shared__ float p_s[H2D];
    int t  = blockIdx.x / 3;
    int ob = (blockIdx.x % 3) * 256;
    if (threadIdx.x < H2D) p_s[threadIdx.x] = pooled[t * H2D + threadIdx.x];
    __syncthreads();
    int o = ob + threadIdx.x;
    float acc = bih[o];
    const float* wr = Wih + (size_t)o * H2D;
#pragma unroll 4
    for (int d = 0; d < H2D; ++d) acc += wr[d] * p_s[d];
    gi_all[t * 768 + o] = acc;
}

// ---------------------------------------------------------------------------
// GRU: 8 cooperating blocks, Whh register-resident, per-block flag sync.
// ---------------------------------------------------------------------------
__global__ __launch_bounds__(768) void gru_reg_kernel(const float* __restrict__ Whh,
                                                      const float* __restrict__ bhh,
                                                      const float* __restrict__ gi_all,
                                                      const float* __restrict__ hx0,
                                                      float* hx_all,
                                                      unsigned int* flags) {
    __shared__ float4 hx_pad[72];                 // padded: idx (g,i) -> g*9+i
    __shared__ __align__(16) float hx_lin[GD];    // linear copy for hx_old
    __shared__ float gh_s[96];
    int b   = blockIdx.x;
    int tid = threadIdx.x;
    int row_local = tid >> 3;      // 0..95
    int sub       = tid & 7;       // 0..7
    int chunk     = row_local >> 5;
    int r_in      = row_local & 31;
    int grow      = chunk * GD + b * 32 + r_in;

    float4 wreg[8];
    const float4* wrow = (const float4*)(Whh + (size_t)grow * GD + sub * 32);
#pragma unroll
    for (int i = 0; i < 8; ++i) wreg[i] = wrow[i];
    float bias = (sub == 0) ? bhh[grow] : 0.f;
    int u = b * 32 + tid;          // hidden unit owned by tid<32

    for (int t = 0; t < T_STEPS; ++t) {
        float gi_r = 0.f, gi_z = 0.f, gi_n = 0.f;
        if (tid < 32) {
            gi_r = gi_all[t * 768 + u];
            gi_z = gi_all[t * 768 + 256 + u];
            gi_n = gi_all[t * 768 + 512 + u];
        }
        if (t > 0) {
            if (tid < GRU_NB) {
                while (__hip_atomic_load(&flags[(t - 1) * GRU_NB + tid],
                                         __ATOMIC_ACQUIRE,
                                         __HIP_MEMORY_SCOPE_AGENT) == 0u)
                    __builtin_amdgcn_s_sleep(1);
            }
            __syncthreads();
        }
        const float* hsrc = (t == 0) ? hx0 : (hx_all + (size_t)(t - 1) * GD);
        if (tid < 64) {
            float4 v;
            v.x = __hip_atomic_load(hsrc + tid * 4 + 0, __ATOMIC_RELAXED, __HIP_MEMORY_SCOPE_AGENT);
            v.y = __hip_atomic_load(hsrc + tid * 4 + 1, __ATOMIC_RELAXED, __HIP_MEMORY_SCOPE_AGENT);
            v.z = __hip_atomic_load(hsrc + tid * 4 + 2, __ATOMIC_RELAXED, __HIP_MEMORY_SCOPE_AGENT);
            v.w = __hip_atomic_load(hsrc + tid * 4 + 3, __ATOMIC_RELAXED, __HIP_MEMORY_SCOPE_AGENT);
            hx_pad[(tid >> 3) * 9 + (tid & 7)] = v;
            ((float4*)hx_lin)[tid] = v;
        }
        __syncthreads();

        float acc = 0.f;
#pragma unroll
        for (int i = 0; i < 8; ++i) {
            float4 hv = hx_pad[sub * 9 + i];
            float4 wv = wreg[i];
            acc += wv.x * hv.x + wv.y * hv.y + wv.z * hv.z + wv.w * hv.w;
        }
        acc += __shfl_xor(acc, 1);
        acc += __shfl_xor(acc, 2);
        acc += __shfl_xor(acc, 4);
        if (sub == 0) gh_s[row_local] = acc + bias;
        __syncthreads();

        if (tid < 32) {
            float r  = 1.f / (1.f + expf(-(gi_r + gh_s[tid])));
            float zg = 1.f / (1.f + expf(-(gi_z + gh_s[32 + tid])));
            float nn = tanhf(gi_n + r * gh_s[64 + tid]);
            float hnew = (1.f - zg) * nn + zg * hx_lin[u];
            __hip_atomic_store(&hx_all[(size_t)t * GD + u], hnew,
                               __ATOMIC_RELAXED, __HIP_MEMORY_SCOPE_AGENT);
        }
        __syncthreads();
        if (tid == 0)
            __hip_atomic_store(&flags[t * GRU_NB + b], 1u,
                               __ATOMIC_RELEASE, __HIP_MEMORY_SCOPE_AGENT);
    }
}

// ---------------------------------------------------------------------------
// res heads + SIR scan. One block per t.
// ---------------------------------------------------------------------------
__global__ __launch_bounds__(128) void res_sir_kernel(const float* __restrict__ hx_all,
                                                      const float* __restrict__ It,
                                                      const float* __restrict__ Rt,
                                                      const float* __restrict__ r1W,
                                                      const float* __restrict__ r1b,
                                                      const float* __restrict__ r2W,
                                                      const float* __restrict__ r2b,
                                                      const float* __restrict__ I,
                                                      const float* __restrict__ R,
                                                      const float* __restrict__ S,
                                                      const float* __restrict__ Npop,
                                                      float* __restrict__ out) {
    __shared__ float nhx[258];
    __shared__ float ab_s[2];
    int t = blockIdx.x, tid = threadIdx.x;
    for (int i = tid; i < GD; i += 128) nhx[i] = hx_all[t * GD + i];
    if (tid == 0) { nhx[256] = It[t]; nhx[257] = Rt[t]; }
    __syncthreads();
    if (tid < 120) {
        float acc = r1b[tid];
        const float* wr = r1W + tid * 258;
        for (int d = 0; d < 258; ++d) acc += wr[d] * nhx[d];
        int idx = t * 60 + (tid >> 1);
        if (tid & 1) out[3840 + idx] = acc;
        else         out[idx] = acc;
    }
    if (tid == 120 || tid == 121) {
        int q = tid - 120;
        float acc = r2b[q];
        const float* wr = r2W + q * 258;
        for (int d = 0; d < 258; ++d) acc += wr[d] * nhx[d];
        ab_s[q] = acc;
    }
    __syncthreads();
    if (tid == 0) {
        float a_s = 1.f / (1.f + expf(-ab_s[0]));
        float b_s = 1.f / (1.f + expf(-ab_s[1]));
        float Np = Npop[0];
        float lI = I[t], lR = R[t], lS = S[t];
        for (int p = 0; p < PD; ++p) {
            float dI = a_s * lI * (lS / Np) - b_s * lI;
            float dR = b_s * lI;
            lI += dI;
            lR += dR;
            lS = Np - lI - lR;
            out[7680  + t * 60 + p] = dI;
            out[11520 + t * 60 + p] = dR;
        }
    }
}

// ---------------------------------------------------------------------------
extern "C" void kernel_launch(void* const* d_in, const int* in_sizes, int n_in,
                              void* d_out, int out_size, void* d_ws, size_t ws_size,
                              hipStream_t stream) {
    const float* h    = (const float*)d_in[0];
    const int*   ng   = (const int*)  d_in[1];
    const float* Npop = (const float*)d_in[2];
    const float* I_   = (const float*)d_in[3];
    const float* R_   = (const float*)d_in[4];
    const float* S_   = (const float*)d_in[5];
    const float* It   = (const float*)d_in[6];
    const float* Rt   = (const float*)d_in[7];
    const float* fc1  = (const float*)d_in[8];
    const float* fc2  = (const float*)d_in[9];
    const float* gWih = (const float*)d_in[10];
    const float* gWhh = (const float*)d_in[11];
    const float* gbih = (const float*)d_in[12];
    const float* gbhh = (const float*)d_in[13];
    const float* r1W  = (const float*)d_in[14];
    const float* r1b  = (const float*)d_in[15];
    const float* r2W  = (const float*)d_in[16];
    const float* r2b  = (const float*)d_in[17];
    const float* hx0  = (const float*)d_in[18];
    float* out = (float*)d_out;

    // ---- workspace carve-up (all region sizes 16B-aligned) ----
    char* w = (char*)d_ws;
    float* pooled = (float*)w; w += (size_t)T_STEPS * H2D * 4;      // 32 KB
    float* hx_all = (float*)w; w += (size_t)T_STEPS * GD * 4;       // 64 KB
    float* gi_all = (float*)w; w += (size_t)T_STEPS * 768 * 4;      // 192 KB
    float* ppart  = (float*)w; w += (size_t)16 * 512 * H2D * 4;     // 4 MB (Tc<=16)
    __hip_bfloat16* W1Thi = (__hip_bfloat16*)w; w += (size_t)384 * 256 * 2; // 192 KB
    __hip_bfloat16* W1Tlo = (__hip_bfloat16*)w; w += (size_t)384 * 256 * 2;
    __hip_bfloat16* f2Thi = (__hip_bfloat16*)w; w += (size_t)128 * 384 * 2; // 96 KB
    __hip_bfloat16* f2Tlo = (__hip_bfloat16*)w; w += (size_t)128 * 384 * 2;
    unsigned int* flags = (unsigned int*)w; w += (size_t)T_STEPS * GRU_NB * 4; // 2 KB
    size_t fixed = (size_t)(w - (char*)d_ws);

    // per-Tc bytes: norms 8KB + pairA 2MB (ihHi/ihLo; later z2) +
    //               z1 3MB + pairC 3MB (cHi/cLo)
    const size_t perTc = 8192 + 2097152 + 3145728 + 3145728;
    int Tc = 16;
    while (Tc > 1) {
        if (fixed + (size_t)Tc * perTc <= ws_size) break;
        Tc >>= 1;
    }
    float* norms = (float*)w;             w += (size_t)Tc * NN * 4;
    char*  pairA = w;                     w += (size_t)Tc * NN * 256 * 2 * 2;
    float* z1    = (float*)w;             w += (size_t)Tc * NN * C1D * 4;
    __hip_bfloat16* cHi = (__hip_bfloat16*)w; w += (size_t)Tc * NN * C1D * 2;
    __hip_bfloat16* cLo = (__hip_bfloat16*)w;

    __hip_bfloat16* ihHi = (__hip_bfloat16*)pairA;
    __hip_bfloat16* ihLo = ihHi + (size_t)Tc * NN * 256;
    // z2 overlays pairA after GEMM1 consumed ihHi/ihLo
    float* z2 = (float*)pairA;

    prep_kernel<<<(384 * 256 + 255) / 256, 256, 0, stream>>>(fc1, fc2, W1Thi, W1Tlo,
                                                             f2Thi, f2Tlo, flags);

    for (int t0 = 0; t0 < T_STEPS; t0 += Tc) {
        int M = Tc * NN;
        norms_kernel      <<<Tc * NN / 4, 256, 0, stream>>>(h, norms, t0);
        input_attn_kernel <<<Tc * NN / 2, 256, 0, stream>>>(h, ng, norms, ihHi, ihLo, t0);
        // z1 = ih @ W1  (M x 256) @ (256 x 384), bf16x3 MFMA, 128^2 tile
        gemm_bf16x3<<<dim3(384 / 128, M / 128), 256, 0, stream>>>(ihHi, ihLo, W1Thi, W1Tlo,
                                                                  z1, M, 384, 256);
        gat_heads_kernel  <<<Tc * NN, 192, 0, stream>>>(z1, ng, cHi, cLo);
        // z2 = c @ fc2  (M x 384) @ (384 x 128), bf16x3 MFMA, 128^2 tile
        gemm_bf16x3<<<dim3(128 / 128, M / 128), 256, 0, stream>>>(cHi, cLo, f2Thi, f2Tlo,
                                                                  z2, M, 128, 384);
        gat_final_kernel  <<<Tc * NN / 4, 256, 0, stream>>>(z2, ng, ppart);
        pool_reduce_kernel<<<Tc, 128, 0, stream>>>(ppart, pooled, t0);
    }

    gi_all_kernel<<<T_STEPS * 3, 256, 0, stream>>>(gWih, gbih, pooled, gi_all);
    gru_reg_kernel<<<GRU_NB, 768, 0, stream>>>(gWhh, gbhh, gi_all, hx0, hx_all, flags);
    res_sir_kernel<<<T_STEPS, 128, 0, stream>>>(hx_all, It, Rt, r1W, r1b, r2W, r2b,
                                                I_, R_, S_, Npop, out);
}